// Round 4
// baseline (610.963 us; speedup 1.0000x reference)
//
#include <hip/hip_runtime.h>
#include <math.h>

#define HW 6400

__device__ __forceinline__ float wredsum(float v){
  #pragma unroll
  for (int o = 32; o; o >>= 1) v += __shfl_xor(v, o);
  return v;
}

// ---------------- K1: depthwise dilated convs + GN partial stats ----------------
__global__ __launch_bounds__(256) void k_dw(
    const float* __restrict__ z,
    const float* __restrict__ w0, const float* __restrict__ b0,
    const float* __restrict__ w1, const float* __restrict__ b1,
    const float* __restrict__ w2, const float* __restrict__ b2,
    const float* __restrict__ w3, const float* __restrict__ b3,
    float* __restrict__ zc, float* __restrict__ gnpart){
  int tid = threadIdx.x;
  int c = blockIdx.y, b = blockIdx.z;
  int pix = blockIdx.x * 256 + tid;
  int h = pix / 80, w = pix % 80;
  int part = c >> 6, cl = c & 63;
  const float* wp; const float* bp; int d;
  if (part == 0)      { wp = w0; bp = b0; d = 7; }
  else if (part == 1) { wp = w1; bp = b1; d = 5; }
  else if (part == 2) { wp = w2; bp = b2; d = 2; }
  else                { wp = w3; bp = b3; d = 1; }
  wp += cl * 9;
  const float* zin = z + (b * 256 + c) * HW;
  float acc = bp[cl];
  #pragma unroll
  for (int kh = 0; kh < 3; kh++){
    int hh = h + (kh - 1) * d;
    if ((unsigned)hh < 80u){
      #pragma unroll
      for (int kw = 0; kw < 3; kw++){
        int ww = w + (kw - 1) * d;
        if ((unsigned)ww < 80u) acc += wp[kh * 3 + kw] * zin[hh * 80 + ww];
      }
    }
  }
  zc[(b * 256 + c) * HW + pix] = acc;
  float S = wredsum(acc), Q = wredsum(acc * acc);
  __shared__ float l[8];
  int lane = tid & 63, wid = tid >> 6;
  if (lane == 0){ l[wid] = S; l[4 + wid] = Q; }
  __syncthreads();
  if (tid == 0){
    float SS = l[0] + l[1] + l[2] + l[3];
    float QQ = l[4] + l[5] + l[6] + l[7];
    int blkid = (b * 256 + c) * 25 + blockIdx.x;
    gnpart[blkid * 2] = SS; gnpart[blkid * 2 + 1] = QQ;
  }
}

// ---------------- K2: GN stats finalize -> per (b,c) scale/shift ----------------
__global__ __launch_bounds__(256) void k_gnfin(
    const float* __restrict__ gnpart, const float* __restrict__ gn_w,
    const float* __restrict__ gn_b, float* __restrict__ gn_sc){
  int tid = threadIdx.x; int bg = blockIdx.x; // b*4+g
  float S = 0.f, Q = 0.f;
  for (int i = tid; i < 1600; i += 256){
    S += gnpart[(bg * 1600 + i) * 2];
    Q += gnpart[(bg * 1600 + i) * 2 + 1];
  }
  S = wredsum(S); Q = wredsum(Q);
  __shared__ float l[8];
  int lane = tid & 63, wid = tid >> 6;
  if (lane == 0){ l[wid] = S; l[4 + wid] = Q; }
  __syncthreads();
  float SS = l[0] + l[1] + l[2] + l[3];
  float QQ = l[4] + l[5] + l[6] + l[7];
  float M = 64.f * HW;
  float mean = SS / M;
  float var = QQ / M - mean * mean;
  float rstd = rsqrtf(var + 1e-5f);
  if (tid < 64){
    int b = bg >> 2, g = bg & 3;
    int c = g * 64 + tid;
    float sc = gn_w[c] * rstd;
    float sh = gn_b[c] - mean * sc;
    gn_sc[(b * 256 + c) * 2] = sc;
    gn_sc[(b * 256 + c) * 2 + 1] = sh;
  }
}

// ---------------- K3: GN-apply + 1x1 conv (256->256) + bias + GELU ----------------
// grid (25, 16, 2), block 256: 16 outputs/thread, ping-pong channel prefetch
__global__ __launch_bounds__(256) void k_conv1(
    const float* __restrict__ zc, const float* __restrict__ gn_sc,
    const float* __restrict__ cw, const float* __restrict__ cb,
    float* __restrict__ zc2){
  int tid = threadIdx.x;
  int pix = blockIdx.x * 256 + tid;
  int ot = blockIdx.y * 16;
  int b = blockIdx.z;
  const float* zbase = zc + (size_t)b * 256 * HW + pix;
  const float* gbase = gn_sc + b * 512;
  float acc[16];
  #pragma unroll
  for (int o = 0; o < 16; o++) acc[o] = 0.f;
  float xa[16], xb[16];
  #pragma unroll
  for (int cc = 0; cc < 16; cc++)
    xa[cc] = zbase[(size_t)cc * HW] * gbase[cc * 2] + gbase[cc * 2 + 1];
  for (int c0 = 0; c0 < 256; c0 += 32){
    #pragma unroll
    for (int cc = 0; cc < 16; cc++){
      int c = c0 + 16 + cc;
      xb[cc] = zbase[(size_t)c * HW] * gbase[c * 2] + gbase[c * 2 + 1];
    }
    #pragma unroll
    for (int o = 0; o < 16; o++){
      const float* wr = cw + (ot + o) * 256 + c0;
      float a = acc[o];
      #pragma unroll
      for (int cc = 0; cc < 16; cc++) a += wr[cc] * xa[cc];
      acc[o] = a;
    }
    if (c0 + 32 < 256){
      #pragma unroll
      for (int cc = 0; cc < 16; cc++){
        int c = c0 + 32 + cc;
        xa[cc] = zbase[(size_t)c * HW] * gbase[c * 2] + gbase[c * 2 + 1];
      }
    }
    #pragma unroll
    for (int o = 0; o < 16; o++){
      const float* wr = cw + (ot + o) * 256 + c0 + 16;
      float a = acc[o];
      #pragma unroll
      for (int cc = 0; cc < 16; cc++) a += wr[cc] * xb[cc];
      acc[o] = a;
    }
  }
  #pragma unroll
  for (int o = 0; o < 16; o++){
    float v = acc[o] + cb[ot + o];
    v = 0.5f * v * (1.f + erff(v * 0.70710678118f));
    zc2[(b * 256 + ot + o) * HW + pix] = v;
  }
}

// ---------------- K4a: 3x3 conv 256->16x2, split-K + oc-split partials ----------------
// grid (100, 16, 2), block 64: one pixel/thread, 32 input channels, 16 outputs.
__global__ __launch_bounds__(64) void k_conv5ac_part(
    const float* __restrict__ zc2, const float* __restrict__ wa,
    const float* __restrict__ wc, float* __restrict__ partial){
  int tid = threadIdx.x;
  int pix = blockIdx.x * 64 + tid;
  int yy = blockIdx.y;
  int icc = yy >> 1, osel = yy & 1;
  int b = blockIdx.z;
  int h = pix / 80, w = pix % 80;
  int off[9]; float msk[9];
  #pragma unroll
  for (int dy = 0; dy < 3; dy++){
    #pragma unroll
    for (int dx = 0; dx < 3; dx++){
      int hh = h + dy - 1, ww = w + dx - 1;
      bool ok = ((unsigned)hh < 80u) && ((unsigned)ww < 80u);
      off[dy * 3 + dx] = ok ? hh * 80 + ww : 0;
      msk[dy * 3 + dx] = ok ? 1.f : 0.f;
    }
  }
  const float* wsel = osel ? wc : wa;
  float acc[16];
  #pragma unroll
  for (int o = 0; o < 16; o++) acc[o] = 0.f;
  int ic0 = icc * 32;
  const float* xbase = zc2 + (size_t)(b * 256 + ic0) * HW;
  float xr[4][9];
  #pragma unroll
  for (int j = 0; j < 4; j++){
    const float* xin = xbase + (size_t)j * HW;
    #pragma unroll
    for (int k = 0; k < 9; k++) xr[j][k] = xin[off[k]] * msk[k];
  }
  #pragma unroll
  for (int ic = 0; ic < 32; ic += 4){
    #pragma unroll
    for (int j = 0; j < 4; j++){
      #pragma unroll
      for (int o = 0; o < 16; o++){
        const float* wro = wsel + (o * 256 + ic0 + ic + j) * 9;  // uniform -> s_load
        float a = acc[o];
        #pragma unroll
        for (int k = 0; k < 9; k++) a += wro[k] * xr[j][k];
        acc[o] = a;
      }
      if (ic + j + 4 < 32){
        const float* xin = xbase + (size_t)(ic + j + 4) * HW;
        #pragma unroll
        for (int k = 0; k < 9; k++) xr[j][k] = xin[off[k]] * msk[k];
      }
    }
  }
  float* pp = partial + ((size_t)(icc * 2 + b) * 32 + osel * 16) * HW + pix;
  #pragma unroll
  for (int o = 0; o < 16; o++) pp[(size_t)o * HW] = acc[o];
}

// ---------------- K4b: reduce split-K partials -> fpre + BN partial stats ----------------
__global__ __launch_bounds__(256) void k_conv5ac_red(
    const float* __restrict__ partial, float* __restrict__ fpre,
    float* __restrict__ bnpart){
  int tid = threadIdx.x; int oc = blockIdx.y, b = blockIdx.z;
  int pix = blockIdx.x * 256 + tid;
  float s = 0.f;
  #pragma unroll
  for (int icc = 0; icc < 8; icc++)
    s += partial[((size_t)(icc * 2 + b) * 32 + oc) * HW + pix];
  fpre[(b * 32 + oc) * HW + pix] = s;
  float S = wredsum(s), Q = wredsum(s * s);
  __shared__ float l[8];
  int lane = tid & 63, wid = tid >> 6;
  if (lane == 0){ l[wid] = S; l[4 + wid] = Q; }
  __syncthreads();
  if (tid == 0){
    bnpart[oc * 100 + (b * 25 + blockIdx.x) * 2]     = l[0] + l[1] + l[2] + l[3];
    bnpart[oc * 100 + (b * 25 + blockIdx.x) * 2 + 1] = l[4] + l[5] + l[6] + l[7];
  }
}

// ---------------- K5/K12: BN finalize (32 channels), parallel reduce ----------------
__global__ __launch_bounds__(256) void k_bnfin(
    const float* __restrict__ part, int nent,
    const float* __restrict__ w1, const float* __restrict__ b1,
    const float* __restrict__ w2, const float* __restrict__ b2,
    float* __restrict__ sc_out){
  __shared__ float lS[8][32], lQ[8][32];
  int tid = threadIdx.x;
  int oc = tid & 31, sl = tid >> 5;
  float S = 0.f, Q = 0.f;
  for (int i = sl; i < nent; i += 8){
    S += part[oc * 2 * nent + i * 2];
    Q += part[oc * 2 * nent + i * 2 + 1];
  }
  lS[sl][oc] = S; lQ[sl][oc] = Q;
  __syncthreads();
  if (tid < 32){
    float SS = 0.f, QQ = 0.f;
    #pragma unroll
    for (int s = 0; s < 8; s++){ SS += lS[s][oc]; QQ += lQ[s][oc]; }
    float M = 2.f * HW;
    float mean = SS / M, var = QQ / M - mean * mean;
    float rstd = rsqrtf(var + 1e-3f);
    float w  = (oc < 16) ? w1[oc] : w2[oc - 16];
    float bb = (oc < 16) ? b1[oc] : b2[oc - 16];
    float sc = w * rstd, sh = bb - mean * sc;
    sc_out[oc * 2] = sc; sc_out[oc * 2 + 1] = sh;
  }
}

// ---------------- K6: BN+relu apply -> feat1/feat2, and q,k,v 1x1 convs ----------------
__global__ __launch_bounds__(256) void k_featqkv(
    const float* __restrict__ fpre, const float* __restrict__ bnsc,
    const float* __restrict__ pqw, const float* __restrict__ pqb,
    const float* __restrict__ pkw, const float* __restrict__ pkb,
    const float* __restrict__ pvw, const float* __restrict__ pvb,
    float* __restrict__ feat, float* __restrict__ qkvT){
  int tid = threadIdx.x; int b = blockIdx.y;
  int n = blockIdx.x * 256 + tid;
  float f1[16], f2[16];
  #pragma unroll
  for (int c = 0; c < 16; c++){
    float v1 = fpre[(b * 32 + c) * HW + n] * bnsc[c * 2] + bnsc[c * 2 + 1];
    f1[c] = fmaxf(v1, 0.f);
    float v2 = fpre[(b * 32 + 16 + c) * HW + n] * bnsc[(16 + c) * 2] + bnsc[(16 + c) * 2 + 1];
    f2[c] = fmaxf(v2, 0.f);
    feat[(b * 32 + c) * HW + n] = f1[c];
    feat[(b * 32 + 16 + c) * HW + n] = f2[c];
  }
  float* o = qkvT + ((size_t)b * HW + n) * 20;
  #pragma unroll
  for (int j = 0; j < 2; j++){
    float q = pqb[j], k = pkb[j];
    #pragma unroll
    for (int c = 0; c < 16; c++){ q += pqw[j * 16 + c] * f1[c]; k += pkw[j * 16 + c] * f1[c]; }
    o[j] = q; o[2 + j] = k;
  }
  #pragma unroll
  for (int j = 0; j < 16; j++){
    float v = pvb[j];
    #pragma unroll
    for (int c = 0; c < 16; c++) v += pvw[j * 16 + c] * f1[c];
    o[4 + j] = v;
  }
}

// ---------------- K7a: PAM flash partials, 25 m-chunks, deferred-max ----------------
__global__ __launch_bounds__(256) void k_pam_a(
    const float* __restrict__ qkvT, float* __restrict__ part){
  int tid = threadIdx.x;
  int n = blockIdx.x * 256 + tid;
  int mc = blockIdx.y, b = blockIdx.z;
  const float* qp = qkvT + ((size_t)b * HW + n) * 20;
  float q0 = qp[0], q1 = qp[1];
  float mx = -1e30f, Z = 0.f;
  float acc[16];
  #pragma unroll
  for (int c = 0; c < 16; c++) acc[c] = 0.f;
  const float* kvbase = qkvT + ((size_t)b * HW + mc * 256) * 20;
  #pragma unroll 2
  for (int mi = 0; mi < 256; mi++){
    const float* kv = kvbase + mi * 20;          // uniform across block -> scalar loads
    float k0 = kv[2], k1 = kv[3];
    float s = q0 * k0 + q1 * k1;
    if (__any(s > mx + 8.f)){                    // rare after warm-up
      float nmx = fmaxf(mx, s);
      float r = __expf(mx - nmx);
      mx = nmx;
      Z *= r;
      #pragma unroll
      for (int c = 0; c < 16; c++) acc[c] *= r;
    }
    float p = __expf(s - mx);                    // bounded by e^8
    Z += p;
    #pragma unroll
    for (int c = 0; c < 16; c++) acc[c] += p * kv[4 + c];
  }
  float* pp = part + ((size_t)(b * 25 + mc) * 18) * HW + n;
  pp[0] = mx; pp[HW] = Z;
  #pragma unroll
  for (int c = 0; c < 16; c++) pp[(size_t)(2 + c) * HW] = acc[c];
}

// ---------------- K7b: merge PAM partials (2 channels/block), residual ----------------
// grid (25, 8, 2), block 256
__global__ __launch_bounds__(256) void k_pam_b(
    const float* __restrict__ part, const float* __restrict__ feat,
    const float* __restrict__ gammap, float* __restrict__ pam_in){
  int tid = threadIdx.x; int cg = blockIdx.y, b = blockIdx.z;
  int n = blockIdx.x * 256 + tid;
  float gamma = gammap[0];
  float mxs[25]; float mx = -1e30f;
  #pragma unroll
  for (int mc = 0; mc < 25; mc++){
    mxs[mc] = part[((size_t)(b * 25 + mc) * 18) * HW + n];
    mx = fmaxf(mx, mxs[mc]);
  }
  float Z = 0.f, a0 = 0.f, a1 = 0.f;
  #pragma unroll
  for (int mc = 0; mc < 25; mc++){
    const float* pp = part + ((size_t)(b * 25 + mc) * 18) * HW + n;
    float r = __expf(mxs[mc] - mx);
    Z += pp[HW] * r;
    a0 += pp[(size_t)(2 + cg * 2) * HW] * r;
    a1 += pp[(size_t)(3 + cg * 2) * HW] * r;
  }
  float inv = gamma / Z;
  int c0 = cg * 2;
  pam_in[(b * 16 + c0) * HW + n]     = a0 * inv + feat[(b * 32 + c0) * HW + n];
  pam_in[(b * 16 + c0 + 1) * HW + n] = a1 * inv + feat[(b * 32 + c0 + 1) * HW + n];
}

// ---------------- K8: CAM gram matrix e[b,c,d] ----------------
__global__ __launch_bounds__(256) void k_cam_gram(
    const float* __restrict__ feat, float* __restrict__ e){
  int tid = threadIdx.x;
  int dd = blockIdx.x, c = blockIdx.y, b = blockIdx.z;
  const float* fc = feat + (b * 32 + 16 + c) * HW;
  const float* fd = feat + (b * 32 + 16 + dd) * HW;
  float S = 0.f;
  for (int i = tid; i < HW; i += 256) S += fc[i] * fd[i];
  S = wredsum(S);
  __shared__ float l[4];
  int lane = tid & 63, wid = tid >> 6;
  if (lane == 0) l[wid] = S;
  __syncthreads();
  if (tid == 0) e[(b * 16 + c) * 16 + dd] = l[0] + l[1] + l[2] + l[3];
}

// ---------------- K9: CAM softmax of (max - e) rows ----------------
__global__ void k_cam_soft(const float* __restrict__ e, float* __restrict__ att){
  int tid = threadIdx.x; if (tid >= 32) return;
  int b = tid >> 4, c = tid & 15;
  const float* row = e + (b * 16 + c) * 16;
  float r[16]; float mn = 1e30f;
  #pragma unroll
  for (int d = 0; d < 16; d++){ r[d] = row[d]; mn = fminf(mn, r[d]); }
  float p[16]; float s = 0.f;
  #pragma unroll
  for (int d = 0; d < 16; d++){ p[d] = __expf(mn - r[d]); s += p[d]; }
  float inv = 1.f / s;
  #pragma unroll
  for (int d = 0; d < 16; d++) att[(b * 16 + c) * 16 + d] = p[d] * inv;
}

// ---------------- K10: CAM apply + residual ----------------
__global__ __launch_bounds__(256) void k_cam_apply(
    const float* __restrict__ att, const float* __restrict__ feat,
    const float* __restrict__ gammap, float* __restrict__ cam_in){
  int tid = threadIdx.x; int c = blockIdx.y, b = blockIdx.z;
  int n = blockIdx.x * 256 + tid;
  const float* arow = att + (b * 16 + c) * 16;
  float s = 0.f;
  #pragma unroll
  for (int d = 0; d < 16; d++) s += arow[d] * feat[(b * 32 + 16 + d) * HW + n];
  cam_in[(b * 16 + c) * HW + n] = gammap[0] * s + feat[(b * 32 + 16 + c) * HW + n];
}

// ---------------- K11: 3x3 conv 16->32 (c5b|c5d), 4 outputs/thread + BN stats ----------------
// grid (100, 8, 2), block 64
__global__ __launch_bounds__(64) void k_conv5bd2(
    const float* __restrict__ pam_in, const float* __restrict__ cam_in,
    const float* __restrict__ wb, const float* __restrict__ wd,
    float* __restrict__ bdpre, float* __restrict__ bnpart){
  int tid = threadIdx.x;
  int pix = blockIdx.x * 64 + tid;
  int ocg = blockIdx.y, b = blockIdx.z;
  int half = ocg >> 2, oq = (ocg & 3) * 4;
  int h = pix / 80, w = pix % 80;
  int off[9]; float msk[9];
  #pragma unroll
  for (int dy = 0; dy < 3; dy++){
    #pragma unroll
    for (int dx = 0; dx < 3; dx++){
      int hh = h + dy - 1, ww = w + dx - 1;
      bool ok = ((unsigned)hh < 80u) && ((unsigned)ww < 80u);
      off[dy * 3 + dx] = ok ? hh * 80 + ww : 0;
      msk[dy * 3 + dx] = ok ? 1.f : 0.f;
    }
  }
  const float* in = (half ? cam_in : pam_in) + (size_t)b * 16 * HW;
  const float* wsel = (half ? wd : wb) + oq * 16 * 9;
  float acc[4];
  #pragma unroll
  for (int o = 0; o < 4; o++) acc[o] = 0.f;
  float xa[9], xb[9];
  #pragma unroll
  for (int k = 0; k < 9; k++) xa[k] = in[off[k]] * msk[k];
  #pragma unroll
  for (int ic = 0; ic < 16; ic += 2){
    const float* xin1 = in + (size_t)(ic + 1) * HW;
    #pragma unroll
    for (int k = 0; k < 9; k++) xb[k] = xin1[off[k]] * msk[k];
    #pragma unroll
    for (int o = 0; o < 4; o++){
      const float* wr = wsel + (o * 16 + ic) * 9;
      float a = acc[o];
      #pragma unroll
      for (int k = 0; k < 9; k++) a += wr[k] * xa[k];
      acc[o] = a;
    }
    if (ic + 2 < 16){
      const float* xin2 = in + (size_t)(ic + 2) * HW;
      #pragma unroll
      for (int k = 0; k < 9; k++) xa[k] = xin2[off[k]] * msk[k];
    }
    #pragma unroll
    for (int o = 0; o < 4; o++){
      const float* wr = wsel + (o * 16 + ic + 1) * 9;
      float a = acc[o];
      #pragma unroll
      for (int k = 0; k < 9; k++) a += wr[k] * xb[k];
      acc[o] = a;
    }
  }
  int oc0 = half * 16 + oq;
  #pragma unroll
  for (int o = 0; o < 4; o++){
    float v = acc[o];
    bdpre[(b * 32 + oc0 + o) * HW + pix] = v;
    float S = wredsum(v), Q = wredsum(v * v);
    if (tid == 0){
      bnpart[(oc0 + o) * 400 + (b * 100 + blockIdx.x) * 2]     = S;
      bnpart[(oc0 + o) * 400 + (b * 100 + blockIdx.x) * 2 + 1] = Q;
    }
  }
}

// ---------------- K13: fused BN+relu+sum + 1x1 conv 16->256 + relu -> out ----------------
// grid (25, 8, 2), block 256: 32 outputs/thread
__global__ __launch_bounds__(256) void k_c6(
    const float* __restrict__ bdpre, const float* __restrict__ bnsc,
    const float* __restrict__ w6, const float* __restrict__ b6,
    float* __restrict__ out){
  int tid = threadIdx.x; int og = blockIdx.y * 32, b = blockIdx.z;
  int n = blockIdx.x * 256 + tid;
  float x[16];
  #pragma unroll
  for (int c = 0; c < 16; c++){
    float v1 = bdpre[(b * 32 + c) * HW + n] * bnsc[c * 2] + bnsc[c * 2 + 1];
    float v2 = bdpre[(b * 32 + 16 + c) * HW + n] * bnsc[(16 + c) * 2] + bnsc[(16 + c) * 2 + 1];
    x[c] = fmaxf(v1, 0.f) + fmaxf(v2, 0.f);
  }
  #pragma unroll
  for (int o = 0; o < 32; o++){
    float a = b6[og + o];
    #pragma unroll
    for (int c = 0; c < 16; c++) a += w6[(og + o) * 16 + c] * x[c];
    out[(b * 256 + og + o) * HW + n] = fmaxf(a, 0.f);
  }
}

extern "C" void kernel_launch(void* const* d_in, const int* in_sizes, int n_in,
                              void* d_out, int out_size, void* d_ws, size_t ws_size,
                              hipStream_t stream){
  const float* z      = (const float*)d_in[0];
  const float* w_at0  = (const float*)d_in[1];
  const float* b_at0  = (const float*)d_in[2];
  const float* w_at1  = (const float*)d_in[3];
  const float* b_at1  = (const float*)d_in[4];
  const float* w_at2  = (const float*)d_in[5];
  const float* b_at2  = (const float*)d_in[6];
  const float* w_at3  = (const float*)d_in[7];
  const float* b_at3  = (const float*)d_in[8];
  const float* gn_w   = (const float*)d_in[9];
  const float* gn_b   = (const float*)d_in[10];
  const float* conv_w = (const float*)d_in[11];
  const float* conv_b = (const float*)d_in[12];
  const float* c5a_w  = (const float*)d_in[13];
  const float* bn5a_w = (const float*)d_in[14];
  const float* bn5a_b = (const float*)d_in[15];
  const float* c5c_w  = (const float*)d_in[16];
  const float* bn5c_w = (const float*)d_in[17];
  const float* bn5c_b = (const float*)d_in[18];
  const float* pq_w   = (const float*)d_in[19];
  const float* pq_b   = (const float*)d_in[20];
  const float* pk_w   = (const float*)d_in[21];
  const float* pk_b   = (const float*)d_in[22];
  const float* pv_w   = (const float*)d_in[23];
  const float* pv_b   = (const float*)d_in[24];
  const float* pa_g   = (const float*)d_in[25];
  const float* ca_g   = (const float*)d_in[26];
  const float* c5b_w  = (const float*)d_in[27];
  const float* bn5b_w = (const float*)d_in[28];
  const float* bn5b_b = (const float*)d_in[29];
  const float* c5d_w  = (const float*)d_in[30];
  const float* bn5d_w = (const float*)d_in[31];
  const float* bn5d_b = (const float*)d_in[32];
  const float* c6_w   = (const float*)d_in[33];
  const float* c6_b   = (const float*)d_in[34];

  float* ws = (float*)d_ws;
  float* ZC      = ws;                    // 3,276,800
  float* ZC2     = ZC + 3276800;          // 3,276,800
  float* FPRE    = ZC2 + 3276800;         // 409,600
  float* FEAT    = FPRE + 409600;         // 409,600
  float* QKVT    = FEAT + 409600;         // 256,000
  float* PAM_IN  = QKVT + 256000;         // 204,800
  float* CAM_IN  = PAM_IN + 204800;       // 204,800
  float* BDPRE   = CAM_IN + 204800;       // 409,600
  float* ST      = BDPRE + 409600;
  float* GN_SC    = ST;                   // 1024
  float* BNA_SC   = ST + 1024;            // 64
  float* BNB_SC   = ST + 1088;            // 64
  float* CAM_ATT  = ST + 1152;            // 512
  float* CAM_E    = ST + 1664;            // 512
  float* GN_PART  = ST + 2176;            // 25,600
  float* BNA_PART = ST + 27776;           // 3,200
  float* BNB_PART = ST + 30976;           // 12,800
  // Aliases into the ZC/ZC2 region:
  //  - PARTIAL (conv5ac split-K, 3,276,800 floats) = ZC; ZC dead after k_conv1,
  //    read by k_conv5ac_red, dead after.
  //  - PART (PAM partials, 25 chunks * 18 planes * 2b * HW = 5,760,000 floats)
  //    spans ZC..into ZC2; both dead before k_pam_a runs.
  float* PARTIAL = ZC;
  float* PART    = ZC;

  k_dw<<<dim3(25, 256, 2), 256, 0, stream>>>(z, w_at0, b_at0, w_at1, b_at1,
                                             w_at2, b_at2, w_at3, b_at3, ZC, GN_PART);
  k_gnfin<<<8, 256, 0, stream>>>(GN_PART, gn_w, gn_b, GN_SC);
  k_conv1<<<dim3(25, 16, 2), 256, 0, stream>>>(ZC, GN_SC, conv_w, conv_b, ZC2);
  k_conv5ac_part<<<dim3(100, 16, 2), 64, 0, stream>>>(ZC2, c5a_w, c5c_w, PARTIAL);
  k_conv5ac_red<<<dim3(25, 32, 2), 256, 0, stream>>>(PARTIAL, FPRE, BNA_PART);
  k_bnfin<<<1, 256, 0, stream>>>(BNA_PART, 50, bn5a_w, bn5a_b, bn5c_w, bn5c_b, BNA_SC);
  k_featqkv<<<dim3(25, 2), 256, 0, stream>>>(FPRE, BNA_SC, pq_w, pq_b, pk_w, pk_b,
                                             pv_w, pv_b, FEAT, QKVT);
  k_pam_a<<<dim3(25, 25, 2), 256, 0, stream>>>(QKVT, PART);
  k_pam_b<<<dim3(25, 8, 2), 256, 0, stream>>>(PART, FEAT, pa_g, PAM_IN);
  k_cam_gram<<<dim3(16, 16, 2), 256, 0, stream>>>(FEAT, CAM_E);
  k_cam_soft<<<1, 64, 0, stream>>>(CAM_E, CAM_ATT);
  k_cam_apply<<<dim3(25, 16, 2), 256, 0, stream>>>(CAM_ATT, FEAT, ca_g, CAM_IN);
  k_conv5bd2<<<dim3(100, 8, 2), 64, 0, stream>>>(PAM_IN, CAM_IN, c5b_w, c5d_w, BDPRE, BNB_PART);
  k_bnfin<<<1, 256, 0, stream>>>(BNB_PART, 200, bn5b_w, bn5b_b, bn5d_w, bn5d_b, BNB_SC);
  k_c6<<<dim3(25, 8, 2), 256, 0, stream>>>(BDPRE, BNB_SC, c6_w, c6_b, (float*)d_out);
}

// Round 5
// 406.442 us; speedup vs baseline: 1.5032x; 1.5032x over previous
//
#include <hip/hip_runtime.h>
#include <math.h>

#define HW 6400

__device__ __forceinline__ float wredsum(float v){
  #pragma unroll
  for (int o = 32; o; o >>= 1) v += __shfl_xor(v, o);
  return v;
}

// ---------------- K0: weight transpose prep ----------------
// WT[ic][o*9+k]  (o<16 -> c5a, o>=16 -> c5c), 256*288
// WT2[ic][o*9+k] (o<16 -> c5b, o>=16 -> c5d), 16*288
__global__ __launch_bounds__(256) void k_wprep(
    const float* __restrict__ wa, const float* __restrict__ wc,
    const float* __restrict__ wb, const float* __restrict__ wd,
    float* __restrict__ wt, float* __restrict__ wt2){
  int i = blockIdx.x * 256 + threadIdx.x;
  if (i < 256 * 288){
    int ic = i / 288, r = i - ic * 288;
    int o = r / 9, k = r - o * 9;
    float v = (o < 16) ? wa[(o * 256 + ic) * 9 + k] : wc[((o - 16) * 256 + ic) * 9 + k];
    wt[i] = v;
  }
  if (i < 16 * 288){
    int ic = i / 288, r = i - ic * 288;
    int o = r / 9, k = r - o * 9;
    float v = (o < 16) ? wb[(o * 16 + ic) * 9 + k] : wd[((o - 16) * 16 + ic) * 9 + k];
    wt2[i] = v;
  }
}

// ---------------- K1: depthwise dilated convs + GN partial stats ----------------
__global__ __launch_bounds__(256) void k_dw(
    const float* __restrict__ z,
    const float* __restrict__ w0, const float* __restrict__ b0,
    const float* __restrict__ w1, const float* __restrict__ b1,
    const float* __restrict__ w2, const float* __restrict__ b2,
    const float* __restrict__ w3, const float* __restrict__ b3,
    float* __restrict__ zc, float* __restrict__ gnpart){
  int tid = threadIdx.x;
  int c = blockIdx.y, b = blockIdx.z;
  int pix = blockIdx.x * 256 + tid;
  int h = pix / 80, w = pix % 80;
  int part = c >> 6, cl = c & 63;
  const float* wp; const float* bp; int d;
  if (part == 0)      { wp = w0; bp = b0; d = 7; }
  else if (part == 1) { wp = w1; bp = b1; d = 5; }
  else if (part == 2) { wp = w2; bp = b2; d = 2; }
  else                { wp = w3; bp = b3; d = 1; }
  wp += cl * 9;
  const float* zin = z + (b * 256 + c) * HW;
  float acc = bp[cl];
  #pragma unroll
  for (int kh = 0; kh < 3; kh++){
    int hh = h + (kh - 1) * d;
    if ((unsigned)hh < 80u){
      #pragma unroll
      for (int kw = 0; kw < 3; kw++){
        int ww = w + (kw - 1) * d;
        if ((unsigned)ww < 80u) acc += wp[kh * 3 + kw] * zin[hh * 80 + ww];
      }
    }
  }
  zc[(b * 256 + c) * HW + pix] = acc;
  float S = wredsum(acc), Q = wredsum(acc * acc);
  __shared__ float l[8];
  int lane = tid & 63, wid = tid >> 6;
  if (lane == 0){ l[wid] = S; l[4 + wid] = Q; }
  __syncthreads();
  if (tid == 0){
    float SS = l[0] + l[1] + l[2] + l[3];
    float QQ = l[4] + l[5] + l[6] + l[7];
    int blkid = (b * 256 + c) * 25 + blockIdx.x;
    gnpart[blkid * 2] = SS; gnpart[blkid * 2 + 1] = QQ;
  }
}

// ---------------- K2: GN stats finalize -> per (b,c) scale/shift ----------------
__global__ __launch_bounds__(256) void k_gnfin(
    const float* __restrict__ gnpart, const float* __restrict__ gn_w,
    const float* __restrict__ gn_b, float* __restrict__ gn_sc){
  int tid = threadIdx.x; int bg = blockIdx.x; // b*4+g
  float S = 0.f, Q = 0.f;
  for (int i = tid; i < 1600; i += 256){
    S += gnpart[(bg * 1600 + i) * 2];
    Q += gnpart[(bg * 1600 + i) * 2 + 1];
  }
  S = wredsum(S); Q = wredsum(Q);
  __shared__ float l[8];
  int lane = tid & 63, wid = tid >> 6;
  if (lane == 0){ l[wid] = S; l[4 + wid] = Q; }
  __syncthreads();
  float SS = l[0] + l[1] + l[2] + l[3];
  float QQ = l[4] + l[5] + l[6] + l[7];
  float M = 64.f * HW;
  float mean = SS / M;
  float var = QQ / M - mean * mean;
  float rstd = rsqrtf(var + 1e-5f);
  if (tid < 64){
    int b = bg >> 2, g = bg & 3;
    int c = g * 64 + tid;
    float sc = gn_w[c] * rstd;
    float sh = gn_b[c] - mean * sc;
    gn_sc[(b * 256 + c) * 2] = sc;
    gn_sc[(b * 256 + c) * 2 + 1] = sh;
  }
}

// ---------------- K3: GN-apply + 1x1 conv (256->256) + bias + GELU ----------------
// grid (25, 16, 2), block 256: 16 outputs/thread, ping-pong channel prefetch
__global__ __launch_bounds__(256) void k_conv1(
    const float* __restrict__ zc, const float* __restrict__ gn_sc,
    const float* __restrict__ cw, const float* __restrict__ cb,
    float* __restrict__ zc2){
  int tid = threadIdx.x;
  int pix = blockIdx.x * 256 + tid;
  int ot = blockIdx.y * 16;
  int b = blockIdx.z;
  const float* zbase = zc + (size_t)b * 256 * HW + pix;
  const float* gbase = gn_sc + b * 512;
  float acc[16];
  #pragma unroll
  for (int o = 0; o < 16; o++) acc[o] = 0.f;
  float xa[16], xb[16];
  #pragma unroll
  for (int cc = 0; cc < 16; cc++)
    xa[cc] = zbase[(size_t)cc * HW] * gbase[cc * 2] + gbase[cc * 2 + 1];
  for (int c0 = 0; c0 < 256; c0 += 32){
    #pragma unroll
    for (int cc = 0; cc < 16; cc++){
      int c = c0 + 16 + cc;
      xb[cc] = zbase[(size_t)c * HW] * gbase[c * 2] + gbase[c * 2 + 1];
    }
    #pragma unroll
    for (int o = 0; o < 16; o++){
      const float* wr = cw + (ot + o) * 256 + c0;
      float a = acc[o];
      #pragma unroll
      for (int cc = 0; cc < 16; cc++) a += wr[cc] * xa[cc];
      acc[o] = a;
    }
    if (c0 + 32 < 256){
      #pragma unroll
      for (int cc = 0; cc < 16; cc++){
        int c = c0 + 32 + cc;
        xa[cc] = zbase[(size_t)c * HW] * gbase[c * 2] + gbase[c * 2 + 1];
      }
    }
    #pragma unroll
    for (int o = 0; o < 16; o++){
      const float* wr = cw + (ot + o) * 256 + c0 + 16;
      float a = acc[o];
      #pragma unroll
      for (int cc = 0; cc < 16; cc++) a += wr[cc] * xb[cc];
      acc[o] = a;
    }
  }
  #pragma unroll
  for (int o = 0; o < 16; o++){
    float v = acc[o] + cb[ot + o];
    v = 0.5f * v * (1.f + erff(v * 0.70710678118f));
    zc2[(b * 256 + ot + o) * HW + pix] = v;
  }
}

// ---------------- K4a: 3x3 conv 256->32 (c5a|c5c fused), split-K partials ----------------
// grid (100, 8, 2), block 64: one pixel/thread, 32 input channels, 32 outputs.
// Weights from WT[ic][o*9+k]: 288 contiguous floats per ic -> batched s_loads.
__global__ __launch_bounds__(64) void k_conv5ac_part(
    const float* __restrict__ zc2, const float* __restrict__ wt,
    float* __restrict__ partial){
  int tid = threadIdx.x;
  int pix = blockIdx.x * 64 + tid;
  int icc = blockIdx.y, b = blockIdx.z;
  int h = pix / 80, w = pix % 80;
  int off[9]; float msk[9];
  #pragma unroll
  for (int dy = 0; dy < 3; dy++){
    #pragma unroll
    for (int dx = 0; dx < 3; dx++){
      int hh = h + dy - 1, ww = w + dx - 1;
      bool ok = ((unsigned)hh < 80u) && ((unsigned)ww < 80u);
      off[dy * 3 + dx] = ok ? hh * 80 + ww : 0;
      msk[dy * 3 + dx] = ok ? 1.f : 0.f;
    }
  }
  float acc[32];
  #pragma unroll
  for (int o = 0; o < 32; o++) acc[o] = 0.f;
  int ic0 = icc * 32;
  const float* xbase = zc2 + (size_t)(b * 256 + ic0) * HW;
  float xa[9], xb[9];
  #pragma unroll
  for (int k = 0; k < 9; k++) xa[k] = xbase[off[k]] * msk[k];
  for (int ic = 0; ic < 32; ic += 2){
    const float* xin1 = xbase + (size_t)(ic + 1) * HW;
    #pragma unroll
    for (int k = 0; k < 9; k++) xb[k] = xin1[off[k]] * msk[k];
    const float* wr0 = wt + (ic0 + ic) * 288;        // uniform, contiguous
    #pragma unroll
    for (int o = 0; o < 32; o++){
      float a = acc[o];
      #pragma unroll
      for (int k = 0; k < 9; k++) a += wr0[o * 9 + k] * xa[k];
      acc[o] = a;
    }
    if (ic + 2 < 32){
      const float* xin2 = xbase + (size_t)(ic + 2) * HW;
      #pragma unroll
      for (int k = 0; k < 9; k++) xa[k] = xin2[off[k]] * msk[k];
    }
    const float* wr1 = wt + (ic0 + ic + 1) * 288;
    #pragma unroll
    for (int o = 0; o < 32; o++){
      float a = acc[o];
      #pragma unroll
      for (int k = 0; k < 9; k++) a += wr1[o * 9 + k] * xb[k];
      acc[o] = a;
    }
  }
  float* pp = partial + ((size_t)(icc * 2 + b) * 32) * HW + pix;
  #pragma unroll
  for (int o = 0; o < 32; o++) pp[(size_t)o * HW] = acc[o];
}

// ---------------- K4b: reduce split-K partials -> fpre + BN partial stats ----------------
__global__ __launch_bounds__(256) void k_conv5ac_red(
    const float* __restrict__ partial, float* __restrict__ fpre,
    float* __restrict__ bnpart){
  int tid = threadIdx.x; int oc = blockIdx.y, b = blockIdx.z;
  int pix = blockIdx.x * 256 + tid;
  float s = 0.f;
  #pragma unroll
  for (int icc = 0; icc < 8; icc++)
    s += partial[((size_t)(icc * 2 + b) * 32 + oc) * HW + pix];
  fpre[(b * 32 + oc) * HW + pix] = s;
  float S = wredsum(s), Q = wredsum(s * s);
  __shared__ float l[8];
  int lane = tid & 63, wid = tid >> 6;
  if (lane == 0){ l[wid] = S; l[4 + wid] = Q; }
  __syncthreads();
  if (tid == 0){
    bnpart[oc * 100 + (b * 25 + blockIdx.x) * 2]     = l[0] + l[1] + l[2] + l[3];
    bnpart[oc * 100 + (b * 25 + blockIdx.x) * 2 + 1] = l[4] + l[5] + l[6] + l[7];
  }
}

// ---------------- K5/K12: BN finalize (32 channels), parallel reduce ----------------
__global__ __launch_bounds__(256) void k_bnfin(
    const float* __restrict__ part, int nent,
    const float* __restrict__ w1, const float* __restrict__ b1,
    const float* __restrict__ w2, const float* __restrict__ b2,
    float* __restrict__ sc_out){
  __shared__ float lS[8][32], lQ[8][32];
  int tid = threadIdx.x;
  int oc = tid & 31, sl = tid >> 5;
  float S = 0.f, Q = 0.f;
  for (int i = sl; i < nent; i += 8){
    S += part[oc * 2 * nent + i * 2];
    Q += part[oc * 2 * nent + i * 2 + 1];
  }
  lS[sl][oc] = S; lQ[sl][oc] = Q;
  __syncthreads();
  if (tid < 32){
    float SS = 0.f, QQ = 0.f;
    #pragma unroll
    for (int s = 0; s < 8; s++){ SS += lS[s][oc]; QQ += lQ[s][oc]; }
    float M = 2.f * HW;
    float mean = SS / M, var = QQ / M - mean * mean;
    float rstd = rsqrtf(var + 1e-3f);
    float w  = (oc < 16) ? w1[oc] : w2[oc - 16];
    float bb = (oc < 16) ? b1[oc] : b2[oc - 16];
    float sc = w * rstd, sh = bb - mean * sc;
    sc_out[oc * 2] = sc; sc_out[oc * 2 + 1] = sh;
  }
}

// ---------------- K6: BN+relu apply -> feat1/feat2, and q,k,v 1x1 convs ----------------
__global__ __launch_bounds__(256) void k_featqkv(
    const float* __restrict__ fpre, const float* __restrict__ bnsc,
    const float* __restrict__ pqw, const float* __restrict__ pqb,
    const float* __restrict__ pkw, const float* __restrict__ pkb,
    const float* __restrict__ pvw, const float* __restrict__ pvb,
    float* __restrict__ feat, float* __restrict__ qkvT){
  int tid = threadIdx.x; int b = blockIdx.y;
  int n = blockIdx.x * 256 + tid;
  float f1[16], f2[16];
  #pragma unroll
  for (int c = 0; c < 16; c++){
    float v1 = fpre[(b * 32 + c) * HW + n] * bnsc[c * 2] + bnsc[c * 2 + 1];
    f1[c] = fmaxf(v1, 0.f);
    float v2 = fpre[(b * 32 + 16 + c) * HW + n] * bnsc[(16 + c) * 2] + bnsc[(16 + c) * 2 + 1];
    f2[c] = fmaxf(v2, 0.f);
    feat[(b * 32 + c) * HW + n] = f1[c];
    feat[(b * 32 + 16 + c) * HW + n] = f2[c];
  }
  float* o = qkvT + ((size_t)b * HW + n) * 20;
  #pragma unroll
  for (int j = 0; j < 2; j++){
    float q = pqb[j], k = pkb[j];
    #pragma unroll
    for (int c = 0; c < 16; c++){ q += pqw[j * 16 + c] * f1[c]; k += pkw[j * 16 + c] * f1[c]; }
    o[j] = q; o[2 + j] = k;
  }
  #pragma unroll
  for (int j = 0; j < 16; j++){
    float v = pvb[j];
    #pragma unroll
    for (int c = 0; c < 16; c++) v += pvw[j * 16 + c] * f1[c];
    o[4 + j] = v;
  }
}

// ---------------- K7a: PAM flash partials, 25 m-chunks, deferred-max ----------------
__global__ __launch_bounds__(256) void k_pam_a(
    const float* __restrict__ qkvT, float* __restrict__ part){
  int tid = threadIdx.x;
  int n = blockIdx.x * 256 + tid;
  int mc = blockIdx.y, b = blockIdx.z;
  const float* qp = qkvT + ((size_t)b * HW + n) * 20;
  float q0 = qp[0], q1 = qp[1];
  float mx = -1e30f, Z = 0.f;
  float acc[16];
  #pragma unroll
  for (int c = 0; c < 16; c++) acc[c] = 0.f;
  const float* kvbase = qkvT + ((size_t)b * HW + mc * 256) * 20;
  #pragma unroll 2
  for (int mi = 0; mi < 256; mi++){
    const float* kv = kvbase + mi * 20;          // uniform across block -> scalar loads
    float k0 = kv[2], k1 = kv[3];
    float s = q0 * k0 + q1 * k1;
    if (__any(s > mx + 8.f)){                    // rare after warm-up
      float nmx = fmaxf(mx, s);
      float r = __expf(mx - nmx);
      mx = nmx;
      Z *= r;
      #pragma unroll
      for (int c = 0; c < 16; c++) acc[c] *= r;
    }
    float p = __expf(s - mx);                    // bounded by e^8
    Z += p;
    #pragma unroll
    for (int c = 0; c < 16; c++) acc[c] += p * kv[4 + c];
  }
  float* pp = part + ((size_t)(b * 25 + mc) * 18) * HW + n;
  pp[0] = mx; pp[HW] = Z;
  #pragma unroll
  for (int c = 0; c < 16; c++) pp[(size_t)(2 + c) * HW] = acc[c];
}

// ---------------- K7b: merge PAM partials (2 channels/block), residual ----------------
// grid (25, 8, 2), block 256
__global__ __launch_bounds__(256) void k_pam_b(
    const float* __restrict__ part, const float* __restrict__ feat,
    const float* __restrict__ gammap, float* __restrict__ pam_in){
  int tid = threadIdx.x; int cg = blockIdx.y, b = blockIdx.z;
  int n = blockIdx.x * 256 + tid;
  float gamma = gammap[0];
  float mxs[25]; float mx = -1e30f;
  #pragma unroll
  for (int mc = 0; mc < 25; mc++){
    mxs[mc] = part[((size_t)(b * 25 + mc) * 18) * HW + n];
    mx = fmaxf(mx, mxs[mc]);
  }
  float Z = 0.f, a0 = 0.f, a1 = 0.f;
  #pragma unroll
  for (int mc = 0; mc < 25; mc++){
    const float* pp = part + ((size_t)(b * 25 + mc) * 18) * HW + n;
    float r = __expf(mxs[mc] - mx);
    Z += pp[HW] * r;
    a0 += pp[(size_t)(2 + cg * 2) * HW] * r;
    a1 += pp[(size_t)(3 + cg * 2) * HW] * r;
  }
  float inv = gamma / Z;
  int c0 = cg * 2;
  pam_in[(b * 16 + c0) * HW + n]     = a0 * inv + feat[(b * 32 + c0) * HW + n];
  pam_in[(b * 16 + c0 + 1) * HW + n] = a1 * inv + feat[(b * 32 + c0 + 1) * HW + n];
}

// ---------------- K8: CAM gram matrix e[b,c,d] ----------------
__global__ __launch_bounds__(256) void k_cam_gram(
    const float* __restrict__ feat, float* __restrict__ e){
  int tid = threadIdx.x;
  int dd = blockIdx.x, c = blockIdx.y, b = blockIdx.z;
  const float* fc = feat + (b * 32 + 16 + c) * HW;
  const float* fd = feat + (b * 32 + 16 + dd) * HW;
  float S = 0.f;
  for (int i = tid; i < HW; i += 256) S += fc[i] * fd[i];
  S = wredsum(S);
  __shared__ float l[4];
  int lane = tid & 63, wid = tid >> 6;
  if (lane == 0) l[wid] = S;
  __syncthreads();
  if (tid == 0) e[(b * 16 + c) * 16 + dd] = l[0] + l[1] + l[2] + l[3];
}

// ---------------- K9: CAM softmax of (max - e) rows ----------------
__global__ void k_cam_soft(const float* __restrict__ e, float* __restrict__ att){
  int tid = threadIdx.x; if (tid >= 32) return;
  int b = tid >> 4, c = tid & 15;
  const float* row = e + (b * 16 + c) * 16;
  float r[16]; float mn = 1e30f;
  #pragma unroll
  for (int d = 0; d < 16; d++){ r[d] = row[d]; mn = fminf(mn, r[d]); }
  float p[16]; float s = 0.f;
  #pragma unroll
  for (int d = 0; d < 16; d++){ p[d] = __expf(mn - r[d]); s += p[d]; }
  float inv = 1.f / s;
  #pragma unroll
  for (int d = 0; d < 16; d++) att[(b * 16 + c) * 16 + d] = p[d] * inv;
}

// ---------------- K10: CAM apply + residual ----------------
__global__ __launch_bounds__(256) void k_cam_apply(
    const float* __restrict__ att, const float* __restrict__ feat,
    const float* __restrict__ gammap, float* __restrict__ cam_in){
  int tid = threadIdx.x; int c = blockIdx.y, b = blockIdx.z;
  int n = blockIdx.x * 256 + tid;
  const float* arow = att + (b * 16 + c) * 16;
  float s = 0.f;
  #pragma unroll
  for (int d = 0; d < 16; d++) s += arow[d] * feat[(b * 32 + 16 + d) * HW + n];
  cam_in[(b * 16 + c) * HW + n] = gammap[0] * s + feat[(b * 32 + 16 + c) * HW + n];
}

// ---------------- K11: 3x3 conv 16->32 (c5b|c5d), 4 outputs/thread + BN stats ----------------
// grid (100, 8, 2), block 64; weights from WT2[ic][o*9+k] (contiguous per ic)
__global__ __launch_bounds__(64) void k_conv5bd2(
    const float* __restrict__ pam_in, const float* __restrict__ cam_in,
    const float* __restrict__ wt2,
    float* __restrict__ bdpre, float* __restrict__ bnpart){
  int tid = threadIdx.x;
  int pix = blockIdx.x * 64 + tid;
  int ocg = blockIdx.y, b = blockIdx.z;
  int half = ocg >> 2, oq = (ocg & 3) * 4;
  int h = pix / 80, w = pix % 80;
  int off[9]; float msk[9];
  #pragma unroll
  for (int dy = 0; dy < 3; dy++){
    #pragma unroll
    for (int dx = 0; dx < 3; dx++){
      int hh = h + dy - 1, ww = w + dx - 1;
      bool ok = ((unsigned)hh < 80u) && ((unsigned)ww < 80u);
      off[dy * 3 + dx] = ok ? hh * 80 + ww : 0;
      msk[dy * 3 + dx] = ok ? 1.f : 0.f;
    }
  }
  const float* in = (half ? cam_in : pam_in) + (size_t)b * 16 * HW;
  int obase = half * 16 + oq;
  float acc[4];
  #pragma unroll
  for (int o = 0; o < 4; o++) acc[o] = 0.f;
  float xa[9], xb[9];
  #pragma unroll
  for (int k = 0; k < 9; k++) xa[k] = in[off[k]] * msk[k];
  #pragma unroll
  for (int ic = 0; ic < 16; ic += 2){
    const float* xin1 = in + (size_t)(ic + 1) * HW;
    #pragma unroll
    for (int k = 0; k < 9; k++) xb[k] = xin1[off[k]] * msk[k];
    const float* wr0 = wt2 + ic * 288 + obase * 9;        // 36 contiguous floats
    #pragma unroll
    for (int o = 0; o < 4; o++){
      float a = acc[o];
      #pragma unroll
      for (int k = 0; k < 9; k++) a += wr0[o * 9 + k] * xa[k];
      acc[o] = a;
    }
    if (ic + 2 < 16){
      const float* xin2 = in + (size_t)(ic + 2) * HW;
      #pragma unroll
      for (int k = 0; k < 9; k++) xa[k] = xin2[off[k]] * msk[k];
    }
    const float* wr1 = wt2 + (ic + 1) * 288 + obase * 9;
    #pragma unroll
    for (int o = 0; o < 4; o++){
      float a = acc[o];
      #pragma unroll
      for (int k = 0; k < 9; k++) a += wr1[o * 9 + k] * xb[k];
      acc[o] = a;
    }
  }
  #pragma unroll
  for (int o = 0; o < 4; o++){
    float v = acc[o];
    bdpre[(b * 32 + obase + o) * HW + pix] = v;
    float S = wredsum(v), Q = wredsum(v * v);
    if (tid == 0){
      bnpart[(obase + o) * 400 + (b * 100 + blockIdx.x) * 2]     = S;
      bnpart[(obase + o) * 400 + (b * 100 + blockIdx.x) * 2 + 1] = Q;
    }
  }
}

// ---------------- K13: fused BN+relu+sum + 1x1 conv 16->256 + relu -> out ----------------
// grid (25, 8, 2), block 256: 32 outputs/thread
__global__ __launch_bounds__(256) void k_c6(
    const float* __restrict__ bdpre, const float* __restrict__ bnsc,
    const float* __restrict__ w6, const float* __restrict__ b6,
    float* __restrict__ out){
  int tid = threadIdx.x; int og = blockIdx.y * 32, b = blockIdx.z;
  int n = blockIdx.x * 256 + tid;
  float x[16];
  #pragma unroll
  for (int c = 0; c < 16; c++){
    float v1 = bdpre[(b * 32 + c) * HW + n] * bnsc[c * 2] + bnsc[c * 2 + 1];
    float v2 = bdpre[(b * 32 + 16 + c) * HW + n] * bnsc[(16 + c) * 2] + bnsc[(16 + c) * 2 + 1];
    x[c] = fmaxf(v1, 0.f) + fmaxf(v2, 0.f);
  }
  #pragma unroll
  for (int o = 0; o < 32; o++){
    float a = b6[og + o];
    #pragma unroll
    for (int c = 0; c < 16; c++) a += w6[(og + o) * 16 + c] * x[c];
    out[(b * 256 + og + o) * HW + n] = fmaxf(a, 0.f);
  }
}

extern "C" void kernel_launch(void* const* d_in, const int* in_sizes, int n_in,
                              void* d_out, int out_size, void* d_ws, size_t ws_size,
                              hipStream_t stream){
  const float* z      = (const float*)d_in[0];
  const float* w_at0  = (const float*)d_in[1];
  const float* b_at0  = (const float*)d_in[2];
  const float* w_at1  = (const float*)d_in[3];
  const float* b_at1  = (const float*)d_in[4];
  const float* w_at2  = (const float*)d_in[5];
  const float* b_at2  = (const float*)d_in[6];
  const float* w_at3  = (const float*)d_in[7];
  const float* b_at3  = (const float*)d_in[8];
  const float* gn_w   = (const float*)d_in[9];
  const float* gn_b   = (const float*)d_in[10];
  const float* conv_w = (const float*)d_in[11];
  const float* conv_b = (const float*)d_in[12];
  const float* c5a_w  = (const float*)d_in[13];
  const float* bn5a_w = (const float*)d_in[14];
  const float* bn5a_b = (const float*)d_in[15];
  const float* c5c_w  = (const float*)d_in[16];
  const float* bn5c_w = (const float*)d_in[17];
  const float* bn5c_b = (const float*)d_in[18];
  const float* pq_w   = (const float*)d_in[19];
  const float* pq_b   = (const float*)d_in[20];
  const float* pk_w   = (const float*)d_in[21];
  const float* pk_b   = (const float*)d_in[22];
  const float* pv_w   = (const float*)d_in[23];
  const float* pv_b   = (const float*)d_in[24];
  const float* pa_g   = (const float*)d_in[25];
  const float* ca_g   = (const float*)d_in[26];
  const float* c5b_w  = (const float*)d_in[27];
  const float* bn5b_w = (const float*)d_in[28];
  const float* bn5b_b = (const float*)d_in[29];
  const float* c5d_w  = (const float*)d_in[30];
  const float* bn5d_w = (const float*)d_in[31];
  const float* bn5d_b = (const float*)d_in[32];
  const float* c6_w   = (const float*)d_in[33];
  const float* c6_b   = (const float*)d_in[34];

  float* ws = (float*)d_ws;
  float* ZC      = ws;                    // 3,276,800
  float* ZC2     = ZC + 3276800;          // 3,276,800
  float* FPRE    = ZC2 + 3276800;         // 409,600
  float* FEAT    = FPRE + 409600;         // 409,600
  float* QKVT    = FEAT + 409600;         // 256,000
  float* PAM_IN  = QKVT + 256000;         // 204,800
  float* CAM_IN  = PAM_IN + 204800;       // 204,800
  float* BDPRE   = CAM_IN + 204800;       // 409,600
  float* ST      = BDPRE + 409600;
  float* GN_SC    = ST;                   // 1024
  float* BNA_SC   = ST + 1024;            // 64
  float* BNB_SC   = ST + 1088;            // 64
  float* CAM_ATT  = ST + 1152;            // 512
  float* CAM_E    = ST + 1664;            // 512
  float* GN_PART  = ST + 2176;            // 25,600
  float* BNA_PART = ST + 27776;           // 3,200
  float* BNB_PART = ST + 30976;           // 12,800
  float* WT       = ST + 43776;           // 73,728 (256*288)
  float* WT2      = WT + 73728;           // 4,608  (16*288)
  // Aliases into the ZC/ZC2 region:
  //  - PARTIAL (conv5ac split-K, 8*2*32*HW = 3,276,800 floats) = ZC; ZC dead after
  //    k_conv1, PARTIAL dead after k_conv5ac_red.
  //  - PART (PAM partials, 25*18*2*HW = 5,760,000 floats) spans ZC..into ZC2;
  //    both dead before k_pam_a runs.
  float* PARTIAL = ZC;
  float* PART    = ZC;

  k_wprep<<<288, 256, 0, stream>>>(c5a_w, c5c_w, c5b_w, c5d_w, WT, WT2);
  k_dw<<<dim3(25, 256, 2), 256, 0, stream>>>(z, w_at0, b_at0, w_at1, b_at1,
                                             w_at2, b_at2, w_at3, b_at3, ZC, GN_PART);
  k_gnfin<<<8, 256, 0, stream>>>(GN_PART, gn_w, gn_b, GN_SC);
  k_conv1<<<dim3(25, 16, 2), 256, 0, stream>>>(ZC, GN_SC, conv_w, conv_b, ZC2);
  k_conv5ac_part<<<dim3(100, 8, 2), 64, 0, stream>>>(ZC2, WT, PARTIAL);
  k_conv5ac_red<<<dim3(25, 32, 2), 256, 0, stream>>>(PARTIAL, FPRE, BNA_PART);
  k_bnfin<<<1, 256, 0, stream>>>(BNA_PART, 50, bn5a_w, bn5a_b, bn5c_w, bn5c_b, BNA_SC);
  k_featqkv<<<dim3(25, 2), 256, 0, stream>>>(FPRE, BNA_SC, pq_w, pq_b, pk_w, pk_b,
                                             pv_w, pv_b, FEAT, QKVT);
  k_pam_a<<<dim3(25, 25, 2), 256, 0, stream>>>(QKVT, PART);
  k_pam_b<<<dim3(25, 8, 2), 256, 0, stream>>>(PART, FEAT, pa_g, PAM_IN);
  k_cam_gram<<<dim3(16, 16, 2), 256, 0, stream>>>(FEAT, CAM_E);
  k_cam_soft<<<1, 64, 0, stream>>>(CAM_E, CAM_ATT);
  k_cam_apply<<<dim3(25, 16, 2), 256, 0, stream>>>(CAM_ATT, FEAT, ca_g, CAM_IN);
  k_conv5bd2<<<dim3(100, 8, 2), 64, 0, stream>>>(PAM_IN, CAM_IN, WT2, BDPRE, BNB_PART);
  k_bnfin<<<1, 256, 0, stream>>>(BNB_PART, 200, bn5b_w, bn5b_b, bn5d_w, bn5d_b, BNB_SC);
  k_c6<<<dim3(25, 8, 2), 256, 0, stream>>>(BDPRE, BNB_SC, c6_w, c6_b, (float*)d_out);
}

// Round 6
// 346.120 us; speedup vs baseline: 1.7652x; 1.1743x over previous
//
#include <hip/hip_runtime.h>
#include <math.h>

#define HW 6400

__device__ __forceinline__ float wredsum(float v){
  #pragma unroll
  for (int o = 32; o; o >>= 1) v += __shfl_xor(v, o);
  return v;
}

// ---------------- K0: weight re-layout prep ----------------
// WTL[ic][k][o]: wtl[(ic*9+k)*32+o], o<16 -> c5a, o>=16 -> c5c     (73,728)
// CWT[ob][c][oi]: cwt[ob*4096 + c*16 + oi] = cw[(ob*16+oi)*256+c]  (65,536)
// WT2[ic][o*9+k] (o<16 -> c5b, o>=16 -> c5d)                       (4,608)
__global__ __launch_bounds__(256) void k_wprep(
    const float* __restrict__ wa, const float* __restrict__ wc,
    const float* __restrict__ wb, const float* __restrict__ wd,
    const float* __restrict__ cw,
    float* __restrict__ wtl, float* __restrict__ cwt, float* __restrict__ wt2){
  int i = blockIdx.x * 256 + threadIdx.x;
  if (i < 256 * 288){
    int ic = i / 288, r = i - ic * 288;
    int kk = r >> 5, o = r & 31;
    float v = (o < 16) ? wa[(o * 256 + ic) * 9 + kk] : wc[((o - 16) * 256 + ic) * 9 + kk];
    wtl[i] = v;
  }
  if (i < 16 * 4096){
    int ob = i / 4096, r = i - ob * 4096;
    int c = r >> 4, oi = r & 15;
    cwt[i] = cw[(ob * 16 + oi) * 256 + c];
  }
  if (i < 16 * 288){
    int ic = i / 288, r = i - ic * 288;
    int o = r / 9, k = r - o * 9;
    float v = (o < 16) ? wb[(o * 16 + ic) * 9 + k] : wd[((o - 16) * 16 + ic) * 9 + k];
    wt2[i] = v;
  }
}

// ---------------- K1: depthwise dilated convs + GN partial stats ----------------
__global__ __launch_bounds__(256) void k_dw(
    const float* __restrict__ z,
    const float* __restrict__ w0, const float* __restrict__ b0,
    const float* __restrict__ w1, const float* __restrict__ b1,
    const float* __restrict__ w2, const float* __restrict__ b2,
    const float* __restrict__ w3, const float* __restrict__ b3,
    float* __restrict__ zc, float* __restrict__ gnpart){
  int tid = threadIdx.x;
  int c = blockIdx.y, b = blockIdx.z;
  int pix = blockIdx.x * 256 + tid;
  int h = pix / 80, w = pix % 80;
  int part = c >> 6, cl = c & 63;
  const float* wp; const float* bp; int d;
  if (part == 0)      { wp = w0; bp = b0; d = 7; }
  else if (part == 1) { wp = w1; bp = b1; d = 5; }
  else if (part == 2) { wp = w2; bp = b2; d = 2; }
  else                { wp = w3; bp = b3; d = 1; }
  wp += cl * 9;
  const float* zin = z + (b * 256 + c) * HW;
  float acc = bp[cl];
  #pragma unroll
  for (int kh = 0; kh < 3; kh++){
    int hh = h + (kh - 1) * d;
    if ((unsigned)hh < 80u){
      #pragma unroll
      for (int kw = 0; kw < 3; kw++){
        int ww = w + (kw - 1) * d;
        if ((unsigned)ww < 80u) acc += wp[kh * 3 + kw] * zin[hh * 80 + ww];
      }
    }
  }
  zc[(b * 256 + c) * HW + pix] = acc;
  float S = wredsum(acc), Q = wredsum(acc * acc);
  __shared__ float l[8];
  int lane = tid & 63, wid = tid >> 6;
  if (lane == 0){ l[wid] = S; l[4 + wid] = Q; }
  __syncthreads();
  if (tid == 0){
    float SS = l[0] + l[1] + l[2] + l[3];
    float QQ = l[4] + l[5] + l[6] + l[7];
    int blkid = (b * 256 + c) * 25 + blockIdx.x;
    gnpart[blkid * 2] = SS; gnpart[blkid * 2 + 1] = QQ;
  }
}

// ---------------- K2: GN stats finalize -> per (b,c) scale/shift ----------------
__global__ __launch_bounds__(256) void k_gnfin(
    const float* __restrict__ gnpart, const float* __restrict__ gn_w,
    const float* __restrict__ gn_b, float* __restrict__ gn_sc){
  int tid = threadIdx.x; int bg = blockIdx.x; // b*4+g
  float S = 0.f, Q = 0.f;
  for (int i = tid; i < 1600; i += 256){
    S += gnpart[(bg * 1600 + i) * 2];
    Q += gnpart[(bg * 1600 + i) * 2 + 1];
  }
  S = wredsum(S); Q = wredsum(Q);
  __shared__ float l[8];
  int lane = tid & 63, wid = tid >> 6;
  if (lane == 0){ l[wid] = S; l[4 + wid] = Q; }
  __syncthreads();
  float SS = l[0] + l[1] + l[2] + l[3];
  float QQ = l[4] + l[5] + l[6] + l[7];
  float M = 64.f * HW;
  float mean = SS / M;
  float var = QQ / M - mean * mean;
  float rstd = rsqrtf(var + 1e-5f);
  if (tid < 64){
    int b = bg >> 2, g = bg & 3;
    int c = g * 64 + tid;
    float sc = gn_w[c] * rstd;
    float sh = gn_b[c] - mean * sc;
    gn_sc[(b * 256 + c) * 2] = sc;
    gn_sc[(b * 256 + c) * 2 + 1] = sh;
  }
}

// ---------------- K3: GN-apply + 1x1 conv (256->256) + bias + GELU ----------------
// grid (25, 16, 2), block 256: weights staged in LDS [c][o] -> broadcast ds_read_b128
__global__ __launch_bounds__(256) void k_conv1(
    const float* __restrict__ zc, const float* __restrict__ gn_sc,
    const float* __restrict__ cwt, const float* __restrict__ cb,
    float* __restrict__ zc2){
  __shared__ __align__(16) float lw[4096];   // 16KB: [c=256][o=16]
  int tid = threadIdx.x;
  int pix = blockIdx.x * 256 + tid;
  int ot = blockIdx.y * 16;
  int b = blockIdx.z;
  const float* wsrc = cwt + blockIdx.y * 4096;
  #pragma unroll
  for (int j = 0; j < 4; j++){
    float4 v = *(const float4*)(wsrc + j * 1024 + tid * 4);
    *(float4*)&lw[j * 1024 + tid * 4] = v;
  }
  __syncthreads();
  const float* zbase = zc + (size_t)b * 256 * HW + pix;
  const float* gbase = gn_sc + b * 512;
  float acc[16];
  #pragma unroll
  for (int o = 0; o < 16; o++) acc[o] = 0.f;
  float xa[16], xb[16];
  #pragma unroll
  for (int cc = 0; cc < 16; cc++)
    xa[cc] = zbase[(size_t)cc * HW] * gbase[cc * 2] + gbase[cc * 2 + 1];
  for (int c0 = 0; c0 < 256; c0 += 32){
    #pragma unroll
    for (int cc = 0; cc < 16; cc++){
      int c = c0 + 16 + cc;
      xb[cc] = zbase[(size_t)c * HW] * gbase[c * 2] + gbase[c * 2 + 1];
    }
    #pragma unroll
    for (int cc = 0; cc < 16; cc++){
      const float4* wv = (const float4*)&lw[(c0 + cc) * 16];
      float xv = xa[cc];
      #pragma unroll
      for (int q = 0; q < 4; q++){
        float4 w4 = wv[q];
        acc[q * 4 + 0] = fmaf(w4.x, xv, acc[q * 4 + 0]);
        acc[q * 4 + 1] = fmaf(w4.y, xv, acc[q * 4 + 1]);
        acc[q * 4 + 2] = fmaf(w4.z, xv, acc[q * 4 + 2]);
        acc[q * 4 + 3] = fmaf(w4.w, xv, acc[q * 4 + 3]);
      }
    }
    if (c0 + 32 < 256){
      #pragma unroll
      for (int cc = 0; cc < 16; cc++){
        int c = c0 + 32 + cc;
        xa[cc] = zbase[(size_t)c * HW] * gbase[c * 2] + gbase[c * 2 + 1];
      }
    }
    #pragma unroll
    for (int cc = 0; cc < 16; cc++){
      const float4* wv = (const float4*)&lw[(c0 + 16 + cc) * 16];
      float xv = xb[cc];
      #pragma unroll
      for (int q = 0; q < 4; q++){
        float4 w4 = wv[q];
        acc[q * 4 + 0] = fmaf(w4.x, xv, acc[q * 4 + 0]);
        acc[q * 4 + 1] = fmaf(w4.y, xv, acc[q * 4 + 1]);
        acc[q * 4 + 2] = fmaf(w4.z, xv, acc[q * 4 + 2]);
        acc[q * 4 + 3] = fmaf(w4.w, xv, acc[q * 4 + 3]);
      }
    }
  }
  #pragma unroll
  for (int o = 0; o < 16; o++){
    float v = acc[o] + cb[ot + o];
    v = 0.5f * v * (1.f + erff(v * 0.70710678118f));
    zc2[(b * 256 + ot + o) * HW + pix] = v;
  }
}

// ---------------- K4a helpers ----------------
__device__ __forceinline__ void load9(float* x, const float* base,
                                      const int* off, const float* msk){
  #pragma unroll
  for (int k = 0; k < 9; k++) x[k] = base[off[k]] * msk[k];
}

__device__ __forceinline__ void fma288(float* acc, const float* lwrow, const float* x){
  #pragma unroll
  for (int k = 0; k < 9; k++){
    float xv = x[k];
    const float4* wv = (const float4*)(lwrow + k * 32);
    #pragma unroll
    for (int q = 0; q < 8; q++){
      float4 w4 = wv[q];
      acc[q * 4 + 0] = fmaf(w4.x, xv, acc[q * 4 + 0]);
      acc[q * 4 + 1] = fmaf(w4.y, xv, acc[q * 4 + 1]);
      acc[q * 4 + 2] = fmaf(w4.z, xv, acc[q * 4 + 2]);
      acc[q * 4 + 3] = fmaf(w4.w, xv, acc[q * 4 + 3]);
    }
  }
}

// ---------------- K4a: 3x3 conv 256->32 (c5a|c5c fused), split-K partials ----------------
// grid (100, 8, 2), block 64 (1 wave): weights staged in LDS per 8-ic group.
__global__ __launch_bounds__(64) void k_conv5ac_part(
    const float* __restrict__ zc2, const float* __restrict__ wtl,
    float* __restrict__ partial){
  __shared__ __align__(16) float lw[2304];   // 9.2KB: 8 ic x [k=9][o=32]
  int tid = threadIdx.x;
  int pix = blockIdx.x * 64 + tid;
  int icc = blockIdx.y, b = blockIdx.z;
  int h = pix / 80, w = pix % 80;
  int off[9]; float msk[9];
  #pragma unroll
  for (int dy = 0; dy < 3; dy++){
    #pragma unroll
    for (int dx = 0; dx < 3; dx++){
      int hh = h + dy - 1, ww = w + dx - 1;
      bool ok = ((unsigned)hh < 80u) && ((unsigned)ww < 80u);
      off[dy * 3 + dx] = ok ? hh * 80 + ww : 0;
      msk[dy * 3 + dx] = ok ? 1.f : 0.f;
    }
  }
  float acc[32];
  #pragma unroll
  for (int o = 0; o < 32; o++) acc[o] = 0.f;
  int ic0 = icc * 32;
  const float* xbase = zc2 + (size_t)(b * 256 + ic0) * HW;
  float xA[9], xB[9];
  load9(xA, xbase, off, msk);
  #pragma unroll
  for (int g = 0; g < 4; g++){
    // stage weights for this 8-ic group: 2304 contiguous floats (no barrier: 1 wave)
    const float* wg = wtl + (ic0 + g * 8) * 288;
    #pragma unroll
    for (int j = 0; j < 9; j++){
      float4 v = *(const float4*)(wg + j * 256 + tid * 4);
      *(float4*)&lw[j * 256 + tid * 4] = v;
    }
    #pragma unroll
    for (int ici = 0; ici < 8; ici++){
      int ic = g * 8 + ici;
      const float* lwrow = lw + ici * 288;
      if (ici & 1){
        if (ic + 1 < 32) load9(xA, xbase + (size_t)(ic + 1) * HW, off, msk);
        fma288(acc, lwrow, xB);
      } else {
        if (ic + 1 < 32) load9(xB, xbase + (size_t)(ic + 1) * HW, off, msk);
        fma288(acc, lwrow, xA);
      }
    }
  }
  float* pp = partial + ((size_t)(icc * 2 + b) * 32) * HW + pix;
  #pragma unroll
  for (int o = 0; o < 32; o++) pp[(size_t)o * HW] = acc[o];
}

// ---------------- K4b: reduce split-K partials -> fpre + BN partial stats ----------------
__global__ __launch_bounds__(256) void k_conv5ac_red(
    const float* __restrict__ partial, float* __restrict__ fpre,
    float* __restrict__ bnpart){
  int tid = threadIdx.x; int oc = blockIdx.y, b = blockIdx.z;
  int pix = blockIdx.x * 256 + tid;
  float s = 0.f;
  #pragma unroll
  for (int icc = 0; icc < 8; icc++)
    s += partial[((size_t)(icc * 2 + b) * 32 + oc) * HW + pix];
  fpre[(b * 32 + oc) * HW + pix] = s;
  float S = wredsum(s), Q = wredsum(s * s);
  __shared__ float l[8];
  int lane = tid & 63, wid = tid >> 6;
  if (lane == 0){ l[wid] = S; l[4 + wid] = Q; }
  __syncthreads();
  if (tid == 0){
    bnpart[oc * 100 + (b * 25 + blockIdx.x) * 2]     = l[0] + l[1] + l[2] + l[3];
    bnpart[oc * 100 + (b * 25 + blockIdx.x) * 2 + 1] = l[4] + l[5] + l[6] + l[7];
  }
}

// ---------------- K5/K12: BN finalize (32 channels), parallel reduce ----------------
__global__ __launch_bounds__(256) void k_bnfin(
    const float* __restrict__ part, int nent,
    const float* __restrict__ w1, const float* __restrict__ b1,
    const float* __restrict__ w2, const float* __restrict__ b2,
    float* __restrict__ sc_out){
  __shared__ float lS[8][32], lQ[8][32];
  int tid = threadIdx.x;
  int oc = tid & 31, sl = tid >> 5;
  float S = 0.f, Q = 0.f;
  for (int i = sl; i < nent; i += 8){
    S += part[oc * 2 * nent + i * 2];
    Q += part[oc * 2 * nent + i * 2 + 1];
  }
  lS[sl][oc] = S; lQ[sl][oc] = Q;
  __syncthreads();
  if (tid < 32){
    float SS = 0.f, QQ = 0.f;
    #pragma unroll
    for (int s = 0; s < 8; s++){ SS += lS[s][oc]; QQ += lQ[s][oc]; }
    float M = 2.f * HW;
    float mean = SS / M, var = QQ / M - mean * mean;
    float rstd = rsqrtf(var + 1e-3f);
    float w  = (oc < 16) ? w1[oc] : w2[oc - 16];
    float bb = (oc < 16) ? b1[oc] : b2[oc - 16];
    float sc = w * rstd, sh = bb - mean * sc;
    sc_out[oc * 2] = sc; sc_out[oc * 2 + 1] = sh;
  }
}

// ---------------- K6: BN+relu apply -> feat1/feat2, and q,k,v 1x1 convs ----------------
__global__ __launch_bounds__(256) void k_featqkv(
    const float* __restrict__ fpre, const float* __restrict__ bnsc,
    const float* __restrict__ pqw, const float* __restrict__ pqb,
    const float* __restrict__ pkw, const float* __restrict__ pkb,
    const float* __restrict__ pvw, const float* __restrict__ pvb,
    float* __restrict__ feat, float* __restrict__ qkvT){
  int tid = threadIdx.x; int b = blockIdx.y;
  int n = blockIdx.x * 256 + tid;
  float f1[16], f2[16];
  #pragma unroll
  for (int c = 0; c < 16; c++){
    float v1 = fpre[(b * 32 + c) * HW + n] * bnsc[c * 2] + bnsc[c * 2 + 1];
    f1[c] = fmaxf(v1, 0.f);
    float v2 = fpre[(b * 32 + 16 + c) * HW + n] * bnsc[(16 + c) * 2] + bnsc[(16 + c) * 2 + 1];
    f2[c] = fmaxf(v2, 0.f);
    feat[(b * 32 + c) * HW + n] = f1[c];
    feat[(b * 32 + 16 + c) * HW + n] = f2[c];
  }
  float* o = qkvT + ((size_t)b * HW + n) * 20;
  #pragma unroll
  for (int j = 0; j < 2; j++){
    float q = pqb[j], k = pkb[j];
    #pragma unroll
    for (int c = 0; c < 16; c++){ q += pqw[j * 16 + c] * f1[c]; k += pkw[j * 16 + c] * f1[c]; }
    o[j] = q; o[2 + j] = k;
  }
  #pragma unroll
  for (int j = 0; j < 16; j++){
    float v = pvb[j];
    #pragma unroll
    for (int c = 0; c < 16; c++) v += pvw[j * 16 + c] * f1[c];
    o[4 + j] = v;
  }
}

// ---------------- K7a: PAM flash partials, 25 m-chunks, LDS-staged KV ----------------
__global__ __launch_bounds__(256) void k_pam_a(
    const float* __restrict__ qkvT, float* __restrict__ part){
  __shared__ __align__(16) float lkv[256 * 20];   // 20KB
  int tid = threadIdx.x;
  int n = blockIdx.x * 256 + tid;
  int mc = blockIdx.y, b = blockIdx.z;
  const float* kvg = qkvT + ((size_t)b * HW + mc * 256) * 20;
  #pragma unroll
  for (int j = 0; j < 5; j++){
    float4 v = *(const float4*)(kvg + j * 1024 + tid * 4);
    *(float4*)&lkv[j * 1024 + tid * 4] = v;
  }
  __syncthreads();
  const float* qp = qkvT + ((size_t)b * HW + n) * 20;
  float q0 = qp[0], q1 = qp[1];
  float mx = -1e30f, Z = 0.f;
  float acc[16];
  #pragma unroll
  for (int c = 0; c < 16; c++) acc[c] = 0.f;
  #pragma unroll 2
  for (int mi = 0; mi < 256; mi++){
    const float* kv = lkv + mi * 20;             // uniform -> LDS broadcast
    float k0 = kv[2], k1 = kv[3];
    float s = q0 * k0 + q1 * k1;
    if (__any(s > mx + 8.f)){                    // rare after warm-up
      float nmx = fmaxf(mx, s);
      float r = __expf(mx - nmx);
      mx = nmx;
      Z *= r;
      #pragma unroll
      for (int c = 0; c < 16; c++) acc[c] *= r;
    }
    float p = __expf(s - mx);                    // bounded by e^8
    Z += p;
    #pragma unroll
    for (int c = 0; c < 16; c++) acc[c] += p * kv[4 + c];
  }
  float* pp = part + ((size_t)(b * 25 + mc) * 18) * HW + n;
  pp[0] = mx; pp[HW] = Z;
  #pragma unroll
  for (int c = 0; c < 16; c++) pp[(size_t)(2 + c) * HW] = acc[c];
}

// ---------------- K7b: merge PAM partials (2 channels/block), residual ----------------
__global__ __launch_bounds__(256) void k_pam_b(
    const float* __restrict__ part, const float* __restrict__ feat,
    const float* __restrict__ gammap, float* __restrict__ pam_in){
  int tid = threadIdx.x; int cg = blockIdx.y, b = blockIdx.z;
  int n = blockIdx.x * 256 + tid;
  float gamma = gammap[0];
  float mxs[25]; float mx = -1e30f;
  #pragma unroll
  for (int mc = 0; mc < 25; mc++){
    mxs[mc] = part[((size_t)(b * 25 + mc) * 18) * HW + n];
    mx = fmaxf(mx, mxs[mc]);
  }
  float Z = 0.f, a0 = 0.f, a1 = 0.f;
  #pragma unroll
  for (int mc = 0; mc < 25; mc++){
    const float* pp = part + ((size_t)(b * 25 + mc) * 18) * HW + n;
    float r = __expf(mxs[mc] - mx);
    Z += pp[HW] * r;
    a0 += pp[(size_t)(2 + cg * 2) * HW] * r;
    a1 += pp[(size_t)(3 + cg * 2) * HW] * r;
  }
  float inv = gamma / Z;
  int c0 = cg * 2;
  pam_in[(b * 16 + c0) * HW + n]     = a0 * inv + feat[(b * 32 + c0) * HW + n];
  pam_in[(b * 16 + c0 + 1) * HW + n] = a1 * inv + feat[(b * 32 + c0 + 1) * HW + n];
}

// ---------------- K8: CAM gram matrix e[b,c,d] ----------------
__global__ __launch_bounds__(256) void k_cam_gram(
    const float* __restrict__ feat, float* __restrict__ e){
  int tid = threadIdx.x;
  int dd = blockIdx.x, c = blockIdx.y, b = blockIdx.z;
  const float* fc = feat + (b * 32 + 16 + c) * HW;
  const float* fd = feat + (b * 32 + 16 + dd) * HW;
  float S = 0.f;
  for (int i = tid; i < HW; i += 256) S += fc[i] * fd[i];
  S = wredsum(S);
  __shared__ float l[4];
  int lane = tid & 63, wid = tid >> 6;
  if (lane == 0) l[wid] = S;
  __syncthreads();
  if (tid == 0) e[(b * 16 + c) * 16 + dd] = l[0] + l[1] + l[2] + l[3];
}

// ---------------- K9: CAM softmax of (max - e) rows ----------------
__global__ void k_cam_soft(const float* __restrict__ e, float* __restrict__ att){
  int tid = threadIdx.x; if (tid >= 32) return;
  int b = tid >> 4, c = tid & 15;
  const float* row = e + (b * 16 + c) * 16;
  float r[16]; float mn = 1e30f;
  #pragma unroll
  for (int d = 0; d < 16; d++){ r[d] = row[d]; mn = fminf(mn, r[d]); }
  float p[16]; float s = 0.f;
  #pragma unroll
  for (int d = 0; d < 16; d++){ p[d] = __expf(mn - r[d]); s += p[d]; }
  float inv = 1.f / s;
  #pragma unroll
  for (int d = 0; d < 16; d++) att[(b * 16 + c) * 16 + d] = p[d] * inv;
}

// ---------------- K10: CAM apply + residual ----------------
__global__ __launch_bounds__(256) void k_cam_apply(
    const float* __restrict__ att, const float* __restrict__ feat,
    const float* __restrict__ gammap, float* __restrict__ cam_in){
  int tid = threadIdx.x; int c = blockIdx.y, b = blockIdx.z;
  int n = blockIdx.x * 256 + tid;
  const float* arow = att + (b * 16 + c) * 16;
  float s = 0.f;
  #pragma unroll
  for (int d = 0; d < 16; d++) s += arow[d] * feat[(b * 32 + 16 + d) * HW + n];
  cam_in[(b * 16 + c) * HW + n] = gammap[0] * s + feat[(b * 32 + 16 + c) * HW + n];
}

// ---------------- K11: 3x3 conv 16->32 (c5b|c5d), 4 outputs/thread + BN stats ----------------
// grid (100, 8, 2), block 64; weights from WT2[ic][o*9+k] (contiguous per ic)
__global__ __launch_bounds__(64) void k_conv5bd2(
    const float* __restrict__ pam_in, const float* __restrict__ cam_in,
    const float* __restrict__ wt2,
    float* __restrict__ bdpre, float* __restrict__ bnpart){
  int tid = threadIdx.x;
  int pix = blockIdx.x * 64 + tid;
  int ocg = blockIdx.y, b = blockIdx.z;
  int half = ocg >> 2, oq = (ocg & 3) * 4;
  int h = pix / 80, w = pix % 80;
  int off[9]; float msk[9];
  #pragma unroll
  for (int dy = 0; dy < 3; dy++){
    #pragma unroll
    for (int dx = 0; dx < 3; dx++){
      int hh = h + dy - 1, ww = w + dx - 1;
      bool ok = ((unsigned)hh < 80u) && ((unsigned)ww < 80u);
      off[dy * 3 + dx] = ok ? hh * 80 + ww : 0;
      msk[dy * 3 + dx] = ok ? 1.f : 0.f;
    }
  }
  const float* in = (half ? cam_in : pam_in) + (size_t)b * 16 * HW;
  int obase = half * 16 + oq;
  float acc[4];
  #pragma unroll
  for (int o = 0; o < 4; o++) acc[o] = 0.f;
  float xa[9], xb[9];
  #pragma unroll
  for (int k = 0; k < 9; k++) xa[k] = in[off[k]] * msk[k];
  #pragma unroll
  for (int ic = 0; ic < 16; ic += 2){
    const float* xin1 = in + (size_t)(ic + 1) * HW;
    #pragma unroll
    for (int k = 0; k < 9; k++) xb[k] = xin1[off[k]] * msk[k];
    const float* wr0 = wt2 + ic * 288 + obase * 9;
    #pragma unroll
    for (int o = 0; o < 4; o++){
      float a = acc[o];
      #pragma unroll
      for (int k = 0; k < 9; k++) a += wr0[o * 9 + k] * xa[k];
      acc[o] = a;
    }
    if (ic + 2 < 16){
      const float* xin2 = in + (size_t)(ic + 2) * HW;
      #pragma unroll
      for (int k = 0; k < 9; k++) xa[k] = xin2[off[k]] * msk[k];
    }
    const float* wr1 = wt2 + (ic + 1) * 288 + obase * 9;
    #pragma unroll
    for (int o = 0; o < 4; o++){
      float a = acc[o];
      #pragma unroll
      for (int k = 0; k < 9; k++) a += wr1[o * 9 + k] * xb[k];
      acc[o] = a;
    }
  }
  #pragma unroll
  for (int o = 0; o < 4; o++){
    float v = acc[o];
    bdpre[(b * 32 + obase + o) * HW + pix] = v;
    float S = wredsum(v), Q = wredsum(v * v);
    if (tid == 0){
      bnpart[(obase + o) * 400 + (b * 100 + blockIdx.x) * 2]     = S;
      bnpart[(obase + o) * 400 + (b * 100 + blockIdx.x) * 2 + 1] = Q;
    }
  }
}

// ---------------- K13: fused BN+relu+sum + 1x1 conv 16->256 + relu -> out ----------------
__global__ __launch_bounds__(256) void k_c6(
    const float* __restrict__ bdpre, const float* __restrict__ bnsc,
    const float* __restrict__ w6, const float* __restrict__ b6,
    float* __restrict__ out){
  int tid = threadIdx.x; int og = blockIdx.y * 32, b = blockIdx.z;
  int n = blockIdx.x * 256 + tid;
  float x[16];
  #pragma unroll
  for (int c = 0; c < 16; c++){
    float v1 = bdpre[(b * 32 + c) * HW + n] * bnsc[c * 2] + bnsc[c * 2 + 1];
    float v2 = bdpre[(b * 32 + 16 + c) * HW + n] * bnsc[(16 + c) * 2] + bnsc[(16 + c) * 2 + 1];
    x[c] = fmaxf(v1, 0.f) + fmaxf(v2, 0.f);
  }
  #pragma unroll
  for (int o = 0; o < 32; o++){
    float a = b6[og + o];
    #pragma unroll
    for (int c = 0; c < 16; c++) a += w6[(og + o) * 16 + c] * x[c];
    out[(b * 256 + og + o) * HW + n] = fmaxf(a, 0.f);
  }
}

extern "C" void kernel_launch(void* const* d_in, const int* in_sizes, int n_in,
                              void* d_out, int out_size, void* d_ws, size_t ws_size,
                              hipStream_t stream){
  const float* z      = (const float*)d_in[0];
  const float* w_at0  = (const float*)d_in[1];
  const float* b_at0  = (const float*)d_in[2];
  const float* w_at1  = (const float*)d_in[3];
  const float* b_at1  = (const float*)d_in[4];
  const float* w_at2  = (const float*)d_in[5];
  const float* b_at2  = (const float*)d_in[6];
  const float* w_at3  = (const float*)d_in[7];
  const float* b_at3  = (const float*)d_in[8];
  const float* gn_w   = (const float*)d_in[9];
  const float* gn_b   = (const float*)d_in[10];
  const float* conv_w = (const float*)d_in[11];
  const float* conv_b = (const float*)d_in[12];
  const float* c5a_w  = (const float*)d_in[13];
  const float* bn5a_w = (const float*)d_in[14];
  const float* bn5a_b = (const float*)d_in[15];
  const float* c5c_w  = (const float*)d_in[16];
  const float* bn5c_w = (const float*)d_in[17];
  const float* bn5c_b = (const float*)d_in[18];
  const float* pq_w   = (const float*)d_in[19];
  const float* pq_b   = (const float*)d_in[20];
  const float* pk_w   = (const float*)d_in[21];
  const float* pk_b   = (const float*)d_in[22];
  const float* pv_w   = (const float*)d_in[23];
  const float* pv_b   = (const float*)d_in[24];
  const float* pa_g   = (const float*)d_in[25];
  const float* ca_g   = (const float*)d_in[26];
  const float* c5b_w  = (const float*)d_in[27];
  const float* bn5b_w = (const float*)d_in[28];
  const float* bn5b_b = (const float*)d_in[29];
  const float* c5d_w  = (const float*)d_in[30];
  const float* bn5d_w = (const float*)d_in[31];
  const float* bn5d_b = (const float*)d_in[32];
  const float* c6_w   = (const float*)d_in[33];
  const float* c6_b   = (const float*)d_in[34];

  float* ws = (float*)d_ws;
  float* ZC      = ws;                    // 3,276,800
  float* ZC2     = ZC + 3276800;          // 3,276,800
  float* FPRE    = ZC2 + 3276800;         // 409,600
  float* FEAT    = FPRE + 409600;         // 409,600
  float* QKVT    = FEAT + 409600;         // 256,000
  float* PAM_IN  = QKVT + 256000;         // 204,800
  float* CAM_IN  = PAM_IN + 204800;       // 204,800
  float* BDPRE   = CAM_IN + 204800;       // 409,600
  float* ST      = BDPRE + 409600;
  float* GN_SC    = ST;                   // 1024
  float* BNA_SC   = ST + 1024;            // 64
  float* BNB_SC   = ST + 1088;            // 64
  float* CAM_ATT  = ST + 1152;            // 512
  float* CAM_E    = ST + 1664;            // 512
  float* GN_PART  = ST + 2176;            // 25,600
  float* BNA_PART = ST + 27776;           // 3,200
  float* BNB_PART = ST + 30976;           // 12,800
  float* WTL      = ST + 43776;           // 73,728 (256*288, [ic][k][o])
  float* WT2      = WTL + 73728;          // 4,608  (16*288)
  float* CWT      = WT2 + 4608;           // 65,536 (16*256*16, [ob][c][oi])
  // Aliases into the ZC/ZC2 region:
  //  - PARTIAL (conv5ac split-K, 8*2*32*HW = 3,276,800 floats) = ZC; ZC dead after
  //    k_conv1, PARTIAL dead after k_conv5ac_red.
  //  - PART (PAM partials, 25*18*2*HW = 5,760,000 floats) spans ZC..into ZC2;
  //    both dead before k_pam_a runs.
  float* PARTIAL = ZC;
  float* PART    = ZC;

  k_wprep<<<288, 256, 0, stream>>>(c5a_w, c5c_w, c5b_w, c5d_w, conv_w, WTL, CWT, WT2);
  k_dw<<<dim3(25, 256, 2), 256, 0, stream>>>(z, w_at0, b_at0, w_at1, b_at1,
                                             w_at2, b_at2, w_at3, b_at3, ZC, GN_PART);
  k_gnfin<<<8, 256, 0, stream>>>(GN_PART, gn_w, gn_b, GN_SC);
  k_conv1<<<dim3(25, 16, 2), 256, 0, stream>>>(ZC, GN_SC, CWT, conv_b, ZC2);
  k_conv5ac_part<<<dim3(100, 8, 2), 64, 0, stream>>>(ZC2, WTL, PARTIAL);
  k_conv5ac_red<<<dim3(25, 32, 2), 256, 0, stream>>>(PARTIAL, FPRE, BNA_PART);
  k_bnfin<<<1, 256, 0, stream>>>(BNA_PART, 50, bn5a_w, bn5a_b, bn5c_w, bn5c_b, BNA_SC);
  k_featqkv<<<dim3(25, 2), 256, 0, stream>>>(FPRE, BNA_SC, pq_w, pq_b, pk_w, pk_b,
                                             pv_w, pv_b, FEAT, QKVT);
  k_pam_a<<<dim3(25, 25, 2), 256, 0, stream>>>(QKVT, PART);
  k_pam_b<<<dim3(25, 8, 2), 256, 0, stream>>>(PART, FEAT, pa_g, PAM_IN);
  k_cam_gram<<<dim3(16, 16, 2), 256, 0, stream>>>(FEAT, CAM_E);
  k_cam_soft<<<1, 64, 0, stream>>>(CAM_E, CAM_ATT);
  k_cam_apply<<<dim3(25, 16, 2), 256, 0, stream>>>(CAM_ATT, FEAT, ca_g, CAM_IN);
  k_conv5bd2<<<dim3(100, 8, 2), 64, 0, stream>>>(PAM_IN, CAM_IN, WT2, BDPRE, BNB_PART);
  k_bnfin<<<1, 256, 0, stream>>>(BNB_PART, 200, bn5b_w, bn5b_b, bn5d_w, bn5d_b, BNB_SC);
  k_c6<<<dim3(25, 8, 2), 256, 0, stream>>>(BDPRE, BNB_SC, c6_w, c6_b, (float*)d_out);
}

// Round 7
// 283.374 us; speedup vs baseline: 2.1560x; 1.2214x over previous
//
#include <hip/hip_runtime.h>
#include <math.h>

#define HW 6400

__device__ __forceinline__ float wredsum(float v){
  #pragma unroll
  for (int o = 32; o; o >>= 1) v += __shfl_xor(v, o);
  return v;
}

// ---------------- K0: weight re-layout prep ----------------
// WTL[ic][k][o]: wtl[(ic*9+k)*32+o], o<16 -> c5a, o>=16 -> c5c     (73,728)
// CWT2[c][o]: cwt[c*256+o] = cw[o*256+c]                            (65,536)
// WT2[ic][o*9+k] (o<16 -> c5b, o>=16 -> c5d)                       (4,608)
__global__ __launch_bounds__(256) void k_wprep(
    const float* __restrict__ wa, const float* __restrict__ wc,
    const float* __restrict__ wb, const float* __restrict__ wd,
    const float* __restrict__ cw,
    float* __restrict__ wtl, float* __restrict__ cwt, float* __restrict__ wt2){
  int i = blockIdx.x * 256 + threadIdx.x;
  if (i < 256 * 288){
    int ic = i / 288, r = i - ic * 288;
    int kk = r >> 5, o = r & 31;
    float v = (o < 16) ? wa[(o * 256 + ic) * 9 + kk] : wc[((o - 16) * 256 + ic) * 9 + kk];
    wtl[i] = v;
  }
  if (i < 65536){
    int c = i >> 8, o = i & 255;
    cwt[i] = cw[o * 256 + c];
  }
  if (i < 16 * 288){
    int ic = i / 288, r = i - ic * 288;
    int o = r / 9, k = r - o * 9;
    float v = (o < 16) ? wb[(o * 16 + ic) * 9 + k] : wd[((o - 16) * 16 + ic) * 9 + k];
    wt2[i] = v;
  }
}

// ---------------- K1: depthwise dilated convs + GN partial stats ----------------
__global__ __launch_bounds__(256) void k_dw(
    const float* __restrict__ z,
    const float* __restrict__ w0, const float* __restrict__ b0,
    const float* __restrict__ w1, const float* __restrict__ b1,
    const float* __restrict__ w2, const float* __restrict__ b2,
    const float* __restrict__ w3, const float* __restrict__ b3,
    float* __restrict__ zc, float* __restrict__ gnpart){
  int tid = threadIdx.x;
  int c = blockIdx.y, b = blockIdx.z;
  int pix = blockIdx.x * 256 + tid;
  int h = pix / 80, w = pix % 80;
  int part = c >> 6, cl = c & 63;
  const float* wp; const float* bp; int d;
  if (part == 0)      { wp = w0; bp = b0; d = 7; }
  else if (part == 1) { wp = w1; bp = b1; d = 5; }
  else if (part == 2) { wp = w2; bp = b2; d = 2; }
  else                { wp = w3; bp = b3; d = 1; }
  wp += cl * 9;
  const float* zin = z + (b * 256 + c) * HW;
  float acc = bp[cl];
  #pragma unroll
  for (int kh = 0; kh < 3; kh++){
    int hh = h + (kh - 1) * d;
    if ((unsigned)hh < 80u){
      #pragma unroll
      for (int kw = 0; kw < 3; kw++){
        int ww = w + (kw - 1) * d;
        if ((unsigned)ww < 80u) acc += wp[kh * 3 + kw] * zin[hh * 80 + ww];
      }
    }
  }
  zc[(b * 256 + c) * HW + pix] = acc;
  float S = wredsum(acc), Q = wredsum(acc * acc);
  __shared__ float l[8];
  int lane = tid & 63, wid = tid >> 6;
  if (lane == 0){ l[wid] = S; l[4 + wid] = Q; }
  __syncthreads();
  if (tid == 0){
    float SS = l[0] + l[1] + l[2] + l[3];
    float QQ = l[4] + l[5] + l[6] + l[7];
    int blkid = (b * 256 + c) * 25 + blockIdx.x;
    gnpart[blkid * 2] = SS; gnpart[blkid * 2 + 1] = QQ;
  }
}

// ---------------- K2: GN stats finalize -> per (b,c) scale/shift ----------------
__global__ __launch_bounds__(256) void k_gnfin(
    const float* __restrict__ gnpart, const float* __restrict__ gn_w,
    const float* __restrict__ gn_b, float* __restrict__ gn_sc){
  int tid = threadIdx.x; int bg = blockIdx.x; // b*4+g
  float S = 0.f, Q = 0.f;
  for (int i = tid; i < 1600; i += 256){
    S += gnpart[(bg * 1600 + i) * 2];
    Q += gnpart[(bg * 1600 + i) * 2 + 1];
  }
  S = wredsum(S); Q = wredsum(Q);
  __shared__ float l[8];
  int lane = tid & 63, wid = tid >> 6;
  if (lane == 0){ l[wid] = S; l[4 + wid] = Q; }
  __syncthreads();
  float SS = l[0] + l[1] + l[2] + l[3];
  float QQ = l[4] + l[5] + l[6] + l[7];
  float M = 64.f * HW;
  float mean = SS / M;
  float var = QQ / M - mean * mean;
  float rstd = rsqrtf(var + 1e-5f);
  if (tid < 64){
    int b = bg >> 2, g = bg & 3;
    int c = g * 64 + tid;
    float sc = gn_w[c] * rstd;
    float sh = gn_b[c] - mean * sc;
    gn_sc[(b * 256 + c) * 2] = sc;
    gn_sc[(b * 256 + c) * 2 + 1] = sh;
  }
}

// ---------------- K3: GN-apply + 1x1 conv (256->256) + GELU, register-tiled GEMM ----
// grid (50, 4, 2), block 512: 128 pix x 64 oc per block, 4x4 per thread,
// double-buffered LDS for x (GN applied) and w.
__global__ __launch_bounds__(512) void k_conv1(
    const float* __restrict__ zc, const float* __restrict__ gn_sc,
    const float* __restrict__ cwt2, const float* __restrict__ cb,
    float* __restrict__ zc2){
  __shared__ __align__(16) float lx[2][16][128];
  __shared__ __align__(16) float lwt[2][16][64];
  int tid = threadIdx.x;
  int pixb = blockIdx.x * 128;
  int ocb = blockIdx.y * 64;
  int b = blockIdx.z;
  int og = tid >> 5, pq = tid & 31;
  int scc = tid >> 5;            // staging channel 0..15
  int spix = (tid & 31) << 2;    // staging pixel quad
  int wcc = tid >> 4, wo = (tid & 15) << 2;  // weight staging (tid<256)
  const float* gb = gn_sc + b * 512;
  const float* zb = zc + (size_t)b * 256 * HW + pixb;
  float4 xr, wr;
  {
    float sc = gb[scc * 2], sh = gb[scc * 2 + 1];
    float4 v = *(const float4*)(zb + (size_t)scc * HW + spix);
    xr = make_float4(v.x * sc + sh, v.y * sc + sh, v.z * sc + sh, v.w * sc + sh);
    if (tid < 256) wr = *(const float4*)(cwt2 + wcc * 256 + ocb + wo);
  }
  *(float4*)&lx[0][scc][spix] = xr;
  if (tid < 256) *(float4*)&lwt[0][wcc][wo] = wr;
  float acc[16];
  #pragma unroll
  for (int i = 0; i < 16; i++) acc[i] = 0.f;
  for (int ph = 0; ph < 16; ph++){
    __syncthreads();
    int buf = ph & 1;
    if (ph < 15){
      int c = (ph + 1) * 16 + scc;
      float sc = gb[c * 2], sh = gb[c * 2 + 1];
      float4 v = *(const float4*)(zb + (size_t)c * HW + spix);
      xr = make_float4(v.x * sc + sh, v.y * sc + sh, v.z * sc + sh, v.w * sc + sh);
      if (tid < 256) wr = *(const float4*)(cwt2 + ((ph + 1) * 16 + wcc) * 256 + ocb + wo);
    }
    #pragma unroll
    for (int cc = 0; cc < 16; cc++){
      float4 xv = *(float4*)&lx[buf][cc][pq << 2];
      float4 wv = *(float4*)&lwt[buf][cc][og << 2];
      float xq[4] = {xv.x, xv.y, xv.z, xv.w};
      float wq[4] = {wv.x, wv.y, wv.z, wv.w};
      #pragma unroll
      for (int p = 0; p < 4; p++)
        #pragma unroll
        for (int o = 0; o < 4; o++)
          acc[p * 4 + o] = fmaf(wq[o], xq[p], acc[p * 4 + o]);
    }
    if (ph < 15){
      *(float4*)&lx[buf ^ 1][scc][spix] = xr;
      if (tid < 256) *(float4*)&lwt[buf ^ 1][wcc][wo] = wr;
    }
  }
  #pragma unroll
  for (int o = 0; o < 4; o++){
    int oc = ocb + (og << 2) + o;
    float bias = cb[oc];
    float4 r;
    float v0 = acc[0 * 4 + o] + bias;
    float v1 = acc[1 * 4 + o] + bias;
    float v2 = acc[2 * 4 + o] + bias;
    float v3 = acc[3 * 4 + o] + bias;
    r.x = 0.5f * v0 * (1.f + erff(v0 * 0.70710678118f));
    r.y = 0.5f * v1 * (1.f + erff(v1 * 0.70710678118f));
    r.z = 0.5f * v2 * (1.f + erff(v2 * 0.70710678118f));
    r.w = 0.5f * v3 * (1.f + erff(v3 * 0.70710678118f));
    *(float4*)(zc2 + (size_t)(b * 256 + oc) * HW + pixb + (pq << 2)) = r;
  }
}

// ---------------- K4a helpers ----------------
__device__ __forceinline__ void load9(float* x, const float* base,
                                      const int* off, const float* msk){
  #pragma unroll
  for (int k = 0; k < 9; k++) x[k] = base[off[k]] * msk[k];
}

__device__ __forceinline__ void fma288(float* acc, const float* lwrow, const float* x){
  #pragma unroll
  for (int k = 0; k < 9; k++){
    float xv = x[k];
    const float4* wv = (const float4*)(lwrow + k * 32);
    #pragma unroll
    for (int q = 0; q < 8; q++){
      float4 w4 = wv[q];
      acc[q * 4 + 0] = fmaf(w4.x, xv, acc[q * 4 + 0]);
      acc[q * 4 + 1] = fmaf(w4.y, xv, acc[q * 4 + 1]);
      acc[q * 4 + 2] = fmaf(w4.z, xv, acc[q * 4 + 2]);
      acc[q * 4 + 3] = fmaf(w4.w, xv, acc[q * 4 + 3]);
    }
  }
}

// ---------------- K4a: 3x3 conv 256->32 (c5a|c5c fused), split-K partials ----------------
// grid (100, 8, 2), block 64 (1 wave): weights staged in LDS per 8-ic group.
__global__ __launch_bounds__(64) void k_conv5ac_part(
    const float* __restrict__ zc2, const float* __restrict__ wtl,
    float* __restrict__ partial){
  __shared__ __align__(16) float lw[2304];   // 9.2KB: 8 ic x [k=9][o=32]
  int tid = threadIdx.x;
  int pix = blockIdx.x * 64 + tid;
  int icc = blockIdx.y, b = blockIdx.z;
  int h = pix / 80, w = pix % 80;
  int off[9]; float msk[9];
  #pragma unroll
  for (int dy = 0; dy < 3; dy++){
    #pragma unroll
    for (int dx = 0; dx < 3; dx++){
      int hh = h + dy - 1, ww = w + dx - 1;
      bool ok = ((unsigned)hh < 80u) && ((unsigned)ww < 80u);
      off[dy * 3 + dx] = ok ? hh * 80 + ww : 0;
      msk[dy * 3 + dx] = ok ? 1.f : 0.f;
    }
  }
  float acc[32];
  #pragma unroll
  for (int o = 0; o < 32; o++) acc[o] = 0.f;
  int ic0 = icc * 32;
  const float* xbase = zc2 + (size_t)(b * 256 + ic0) * HW;
  float xA[9], xB[9];
  load9(xA, xbase, off, msk);
  #pragma unroll
  for (int g = 0; g < 4; g++){
    const float* wg = wtl + (ic0 + g * 8) * 288;
    #pragma unroll
    for (int j = 0; j < 9; j++){
      float4 v = *(const float4*)(wg + j * 256 + tid * 4);
      *(float4*)&lw[j * 256 + tid * 4] = v;
    }
    #pragma unroll
    for (int ici = 0; ici < 8; ici++){
      int ic = g * 8 + ici;
      const float* lwrow = lw + ici * 288;
      if (ici & 1){
        if (ic + 1 < 32) load9(xA, xbase + (size_t)(ic + 1) * HW, off, msk);
        fma288(acc, lwrow, xB);
      } else {
        if (ic + 1 < 32) load9(xB, xbase + (size_t)(ic + 1) * HW, off, msk);
        fma288(acc, lwrow, xA);
      }
    }
  }
  float* pp = partial + ((size_t)(icc * 2 + b) * 32) * HW + pix;
  #pragma unroll
  for (int o = 0; o < 32; o++) pp[(size_t)o * HW] = acc[o];
}

// ---------------- K4b: reduce split-K partials -> fpre + BN partial stats ----------------
__global__ __launch_bounds__(256) void k_conv5ac_red(
    const float* __restrict__ partial, float* __restrict__ fpre,
    float* __restrict__ bnpart){
  int tid = threadIdx.x; int oc = blockIdx.y, b = blockIdx.z;
  int pix = blockIdx.x * 256 + tid;
  float s = 0.f;
  #pragma unroll
  for (int icc = 0; icc < 8; icc++)
    s += partial[((size_t)(icc * 2 + b) * 32 + oc) * HW + pix];
  fpre[(b * 32 + oc) * HW + pix] = s;
  float S = wredsum(s), Q = wredsum(s * s);
  __shared__ float l[8];
  int lane = tid & 63, wid = tid >> 6;
  if (lane == 0){ l[wid] = S; l[4 + wid] = Q; }
  __syncthreads();
  if (tid == 0){
    bnpart[oc * 100 + (b * 25 + blockIdx.x) * 2]     = l[0] + l[1] + l[2] + l[3];
    bnpart[oc * 100 + (b * 25 + blockIdx.x) * 2 + 1] = l[4] + l[5] + l[6] + l[7];
  }
}

// ---------------- K5/K12: BN finalize (32 channels), parallel reduce ----------------
__global__ __launch_bounds__(256) void k_bnfin(
    const float* __restrict__ part, int nent,
    const float* __restrict__ w1, const float* __restrict__ b1,
    const float* __restrict__ w2, const float* __restrict__ b2,
    float* __restrict__ sc_out){
  __shared__ float lS[8][32], lQ[8][32];
  int tid = threadIdx.x;
  int oc = tid & 31, sl = tid >> 5;
  float S = 0.f, Q = 0.f;
  for (int i = sl; i < nent; i += 8){
    S += part[oc * 2 * nent + i * 2];
    Q += part[oc * 2 * nent + i * 2 + 1];
  }
  lS[sl][oc] = S; lQ[sl][oc] = Q;
  __syncthreads();
  if (tid < 32){
    float SS = 0.f, QQ = 0.f;
    #pragma unroll
    for (int s = 0; s < 8; s++){ SS += lS[s][oc]; QQ += lQ[s][oc]; }
    float M = 2.f * HW;
    float mean = SS / M, var = QQ / M - mean * mean;
    float rstd = rsqrtf(var + 1e-3f);
    float w  = (oc < 16) ? w1[oc] : w2[oc - 16];
    float bb = (oc < 16) ? b1[oc] : b2[oc - 16];
    float sc = w * rstd, sh = bb - mean * sc;
    sc_out[oc * 2] = sc; sc_out[oc * 2 + 1] = sh;
  }
}

// ---------------- K6: BN+relu apply -> feat1/feat2, and q,k,v 1x1 convs ----------------
__global__ __launch_bounds__(256) void k_featqkv(
    const float* __restrict__ fpre, const float* __restrict__ bnsc,
    const float* __restrict__ pqw, const float* __restrict__ pqb,
    const float* __restrict__ pkw, const float* __restrict__ pkb,
    const float* __restrict__ pvw, const float* __restrict__ pvb,
    float* __restrict__ feat, float* __restrict__ qkvT){
  int tid = threadIdx.x; int b = blockIdx.y;
  int n = blockIdx.x * 256 + tid;
  float f1[16], f2[16];
  #pragma unroll
  for (int c = 0; c < 16; c++){
    float v1 = fpre[(b * 32 + c) * HW + n] * bnsc[c * 2] + bnsc[c * 2 + 1];
    f1[c] = fmaxf(v1, 0.f);
    float v2 = fpre[(b * 32 + 16 + c) * HW + n] * bnsc[(16 + c) * 2] + bnsc[(16 + c) * 2 + 1];
    f2[c] = fmaxf(v2, 0.f);
    feat[(b * 32 + c) * HW + n] = f1[c];
    feat[(b * 32 + 16 + c) * HW + n] = f2[c];
  }
  float* o = qkvT + ((size_t)b * HW + n) * 20;
  #pragma unroll
  for (int j = 0; j < 2; j++){
    float q = pqb[j], k = pkb[j];
    #pragma unroll
    for (int c = 0; c < 16; c++){ q += pqw[j * 16 + c] * f1[c]; k += pkw[j * 16 + c] * f1[c]; }
    o[j] = q; o[2 + j] = k;
  }
  #pragma unroll
  for (int j = 0; j < 16; j++){
    float v = pvb[j];
    #pragma unroll
    for (int c = 0; c < 16; c++) v += pvw[j * 16 + c] * f1[c];
    o[4 + j] = v;
  }
}

// ---------------- K7a: PAM flash partials, 25 m-chunks, LDS-staged KV ----------------
__global__ __launch_bounds__(256) void k_pam_a(
    const float* __restrict__ qkvT, float* __restrict__ part){
  __shared__ __align__(16) float lkv[256 * 20];   // 20KB
  int tid = threadIdx.x;
  int n = blockIdx.x * 256 + tid;
  int mc = blockIdx.y, b = blockIdx.z;
  const float* kvg = qkvT + ((size_t)b * HW + mc * 256) * 20;
  #pragma unroll
  for (int j = 0; j < 5; j++){
    float4 v = *(const float4*)(kvg + j * 1024 + tid * 4);
    *(float4*)&lkv[j * 1024 + tid * 4] = v;
  }
  __syncthreads();
  const float* qp = qkvT + ((size_t)b * HW + n) * 20;
  float q0 = qp[0], q1 = qp[1];
  float mx = -1e30f, Z = 0.f;
  float acc[16];
  #pragma unroll
  for (int c = 0; c < 16; c++) acc[c] = 0.f;
  #pragma unroll 2
  for (int mi = 0; mi < 256; mi++){
    const float* kv = lkv + mi * 20;             // uniform -> LDS broadcast
    float k0 = kv[2], k1 = kv[3];
    float s = q0 * k0 + q1 * k1;
    if (__any(s > mx + 8.f)){                    // rare after warm-up
      float nmx = fmaxf(mx, s);
      float r = __expf(mx - nmx);
      mx = nmx;
      Z *= r;
      #pragma unroll
      for (int c = 0; c < 16; c++) acc[c] *= r;
    }
    float p = __expf(s - mx);                    // bounded by e^8
    Z += p;
    #pragma unroll
    for (int c = 0; c < 16; c++) acc[c] += p * kv[4 + c];
  }
  float* pp = part + ((size_t)(b * 25 + mc) * 18) * HW + n;
  pp[0] = mx; pp[HW] = Z;
  #pragma unroll
  for (int c = 0; c < 16; c++) pp[(size_t)(2 + c) * HW] = acc[c];
}

// ---------------- K7b: merge PAM partials (2 channels/block), residual ----------------
__global__ __launch_bounds__(256) void k_pam_b(
    const float* __restrict__ part, const float* __restrict__ feat,
    const float* __restrict__ gammap, float* __restrict__ pam_in){
  int tid = threadIdx.x; int cg = blockIdx.y, b = blockIdx.z;
  int n = blockIdx.x * 256 + tid;
  float gamma = gammap[0];
  float mxs[25]; float mx = -1e30f;
  #pragma unroll
  for (int mc = 0; mc < 25; mc++){
    mxs[mc] = part[((size_t)(b * 25 + mc) * 18) * HW + n];
    mx = fmaxf(mx, mxs[mc]);
  }
  float Z = 0.f, a0 = 0.f, a1 = 0.f;
  #pragma unroll
  for (int mc = 0; mc < 25; mc++){
    const float* pp = part + ((size_t)(b * 25 + mc) * 18) * HW + n;
    float r = __expf(mxs[mc] - mx);
    Z += pp[HW] * r;
    a0 += pp[(size_t)(2 + cg * 2) * HW] * r;
    a1 += pp[(size_t)(3 + cg * 2) * HW] * r;
  }
  float inv = gamma / Z;
  int c0 = cg * 2;
  pam_in[(b * 16 + c0) * HW + n]     = a0 * inv + feat[(b * 32 + c0) * HW + n];
  pam_in[(b * 16 + c0 + 1) * HW + n] = a1 * inv + feat[(b * 32 + c0 + 1) * HW + n];
}

// ---------------- K8: CAM gram matrix e[b,c,d] ----------------
__global__ __launch_bounds__(256) void k_cam_gram(
    const float* __restrict__ feat, float* __restrict__ e){
  int tid = threadIdx.x;
  int dd = blockIdx.x, c = blockIdx.y, b = blockIdx.z;
  const float* fc = feat + (b * 32 + 16 + c) * HW;
  const float* fd = feat + (b * 32 + 16 + dd) * HW;
  float S = 0.f;
  for (int i = tid; i < HW; i += 256) S += fc[i] * fd[i];
  S = wredsum(S);
  __shared__ float l[4];
  int lane = tid & 63, wid = tid >> 6;
  if (lane == 0) l[wid] = S;
  __syncthreads();
  if (tid == 0) e[(b * 16 + c) * 16 + dd] = l[0] + l[1] + l[2] + l[3];
}

// ---------------- K9: CAM softmax of (max - e) rows ----------------
__global__ void k_cam_soft(const float* __restrict__ e, float* __restrict__ att){
  int tid = threadIdx.x; if (tid >= 32) return;
  int b = tid >> 4, c = tid & 15;
  const float* row = e + (b * 16 + c) * 16;
  float r[16]; float mn = 1e30f;
  #pragma unroll
  for (int d = 0; d < 16; d++){ r[d] = row[d]; mn = fminf(mn, r[d]); }
  float p[16]; float s = 0.f;
  #pragma unroll
  for (int d = 0; d < 16; d++){ p[d] = __expf(mn - r[d]); s += p[d]; }
  float inv = 1.f / s;
  #pragma unroll
  for (int d = 0; d < 16; d++) att[(b * 16 + c) * 16 + d] = p[d] * inv;
}

// ---------------- K10: CAM apply + residual ----------------
__global__ __launch_bounds__(256) void k_cam_apply(
    const float* __restrict__ att, const float* __restrict__ feat,
    const float* __restrict__ gammap, float* __restrict__ cam_in){
  int tid = threadIdx.x; int c = blockIdx.y, b = blockIdx.z;
  int n = blockIdx.x * 256 + tid;
  const float* arow = att + (b * 16 + c) * 16;
  float s = 0.f;
  #pragma unroll
  for (int d = 0; d < 16; d++) s += arow[d] * feat[(b * 32 + 16 + d) * HW + n];
  cam_in[(b * 16 + c) * HW + n] = gammap[0] * s + feat[(b * 32 + 16 + c) * HW + n];
}

// ---------------- K11: 3x3 conv 16->32 (c5b|c5d), 4 outputs/thread + BN stats ----------------
__global__ __launch_bounds__(64) void k_conv5bd2(
    const float* __restrict__ pam_in, const float* __restrict__ cam_in,
    const float* __restrict__ wt2,
    float* __restrict__ bdpre, float* __restrict__ bnpart){
  int tid = threadIdx.x;
  int pix = blockIdx.x * 64 + tid;
  int ocg = blockIdx.y, b = blockIdx.z;
  int half = ocg >> 2, oq = (ocg & 3) * 4;
  int h = pix / 80, w = pix % 80;
  int off[9]; float msk[9];
  #pragma unroll
  for (int dy = 0; dy < 3; dy++){
    #pragma unroll
    for (int dx = 0; dx < 3; dx++){
      int hh = h + dy - 1, ww = w + dx - 1;
      bool ok = ((unsigned)hh < 80u) && ((unsigned)ww < 80u);
      off[dy * 3 + dx] = ok ? hh * 80 + ww : 0;
      msk[dy * 3 + dx] = ok ? 1.f : 0.f;
    }
  }
  const float* in = (half ? cam_in : pam_in) + (size_t)b * 16 * HW;
  int obase = half * 16 + oq;
  float acc[4];
  #pragma unroll
  for (int o = 0; o < 4; o++) acc[o] = 0.f;
  float xa[9], xb[9];
  #pragma unroll
  for (int k = 0; k < 9; k++) xa[k] = in[off[k]] * msk[k];
  #pragma unroll
  for (int ic = 0; ic < 16; ic += 2){
    const float* xin1 = in + (size_t)(ic + 1) * HW;
    #pragma unroll
    for (int k = 0; k < 9; k++) xb[k] = xin1[off[k]] * msk[k];
    const float* wr0 = wt2 + ic * 288 + obase * 9;
    #pragma unroll
    for (int o = 0; o < 4; o++){
      float a = acc[o];
      #pragma unroll
      for (int k = 0; k < 9; k++) a += wr0[o * 9 + k] * xa[k];
      acc[o] = a;
    }
    if (ic + 2 < 16){
      const float* xin2 = in + (size_t)(ic + 2) * HW;
      #pragma unroll
      for (int k = 0; k < 9; k++) xa[k] = xin2[off[k]] * msk[k];
    }
    const float* wr1 = wt2 + (ic + 1) * 288 + obase * 9;
    #pragma unroll
    for (int o = 0; o < 4; o++){
      float a = acc[o];
      #pragma unroll
      for (int k = 0; k < 9; k++) a += wr1[o * 9 + k] * xb[k];
      acc[o] = a;
    }
  }
  #pragma unroll
  for (int o = 0; o < 4; o++){
    float v = acc[o];
    bdpre[(b * 32 + obase + o) * HW + pix] = v;
    float S = wredsum(v), Q = wredsum(v * v);
    if (tid == 0){
      bnpart[(obase + o) * 400 + (b * 100 + blockIdx.x) * 2]     = S;
      bnpart[(obase + o) * 400 + (b * 100 + blockIdx.x) * 2 + 1] = Q;
    }
  }
}

// ---------------- K13: fused BN+relu+sum + 1x1 conv 16->256 + relu -> out ----------------
__global__ __launch_bounds__(256) void k_c6(
    const float* __restrict__ bdpre, const float* __restrict__ bnsc,
    const float* __restrict__ w6, const float* __restrict__ b6,
    float* __restrict__ out){
  int tid = threadIdx.x; int og = blockIdx.y * 32, b = blockIdx.z;
  int n = blockIdx.x * 256 + tid;
  float x[16];
  #pragma unroll
  for (int c = 0; c < 16; c++){
    float v1 = bdpre[(b * 32 + c) * HW + n] * bnsc[c * 2] + bnsc[c * 2 + 1];
    float v2 = bdpre[(b * 32 + 16 + c) * HW + n] * bnsc[(16 + c) * 2] + bnsc[(16 + c) * 2 + 1];
    x[c] = fmaxf(v1, 0.f) + fmaxf(v2, 0.f);
  }
  #pragma unroll
  for (int o = 0; o < 32; o++){
    float a = b6[og + o];
    #pragma unroll
    for (int c = 0; c < 16; c++) a += w6[(og + o) * 16 + c] * x[c];
    out[(b * 256 + og + o) * HW + n] = fmaxf(a, 0.f);
  }
}

extern "C" void kernel_launch(void* const* d_in, const int* in_sizes, int n_in,
                              void* d_out, int out_size, void* d_ws, size_t ws_size,
                              hipStream_t stream){
  const float* z      = (const float*)d_in[0];
  const float* w_at0  = (const float*)d_in[1];
  const float* b_at0  = (const float*)d_in[2];
  const float* w_at1  = (const float*)d_in[3];
  const float* b_at1  = (const float*)d_in[4];
  const float* w_at2  = (const float*)d_in[5];
  const float* b_at2  = (const float*)d_in[6];
  const float* w_at3  = (const float*)d_in[7];
  const float* b_at3  = (const float*)d_in[8];
  const float* gn_w   = (const float*)d_in[9];
  const float* gn_b   = (const float*)d_in[10];
  const float* conv_w = (const float*)d_in[11];
  const float* conv_b = (const float*)d_in[12];
  const float* c5a_w  = (const float*)d_in[13];
  const float* bn5a_w = (const float*)d_in[14];
  const float* bn5a_b = (const float*)d_in[15];
  const float* c5c_w  = (const float*)d_in[16];
  const float* bn5c_w = (const float*)d_in[17];
  const float* bn5c_b = (const float*)d_in[18];
  const float* pq_w   = (const float*)d_in[19];
  const float* pq_b   = (const float*)d_in[20];
  const float* pk_w   = (const float*)d_in[21];
  const float* pk_b   = (const float*)d_in[22];
  const float* pv_w   = (const float*)d_in[23];
  const float* pv_b   = (const float*)d_in[24];
  const float* pa_g   = (const float*)d_in[25];
  const float* ca_g   = (const float*)d_in[26];
  const float* c5b_w  = (const float*)d_in[27];
  const float* bn5b_w = (const float*)d_in[28];
  const float* bn5b_b = (const float*)d_in[29];
  const float* c5d_w  = (const float*)d_in[30];
  const float* bn5d_w = (const float*)d_in[31];
  const float* bn5d_b = (const float*)d_in[32];
  const float* c6_w   = (const float*)d_in[33];
  const float* c6_b   = (const float*)d_in[34];

  float* ws = (float*)d_ws;
  float* ZC      = ws;                    // 3,276,800
  float* ZC2     = ZC + 3276800;          // 3,276,800
  float* FPRE    = ZC2 + 3276800;         // 409,600
  float* FEAT    = FPRE + 409600;         // 409,600
  float* QKVT    = FEAT + 409600;         // 256,000
  float* PAM_IN  = QKVT + 256000;         // 204,800
  float* CAM_IN  = PAM_IN + 204800;       // 204,800
  float* BDPRE   = CAM_IN + 204800;       // 409,600
  float* ST      = BDPRE + 409600;
  float* GN_SC    = ST;                   // 1024
  float* BNA_SC   = ST + 1024;            // 64
  float* BNB_SC   = ST + 1088;            // 64
  float* CAM_ATT  = ST + 1152;            // 512
  float* CAM_E    = ST + 1664;            // 512
  float* GN_PART  = ST + 2176;            // 25,600
  float* BNA_PART = ST + 27776;           // 3,200
  float* BNB_PART = ST + 30976;           // 12,800
  float* WTL      = ST + 43776;           // 73,728 (256*288, [ic][k][o])
  float* WT2      = WTL + 73728;          // 4,608  (16*288)
  float* CWT      = WT2 + 4608;           // 65,536 ([c][o] full transpose)
  float* PARTIAL = ZC;
  float* PART    = ZC;

  k_wprep<<<288, 256, 0, stream>>>(c5a_w, c5c_w, c5b_w, c5d_w, conv_w, WTL, CWT, WT2);
  k_dw<<<dim3(25, 256, 2), 256, 0, stream>>>(z, w_at0, b_at0, w_at1, b_at1,
                                             w_at2, b_at2, w_at3, b_at3, ZC, GN_PART);
  k_gnfin<<<8, 256, 0, stream>>>(GN_PART, gn_w, gn_b, GN_SC);
  k_conv1<<<dim3(50, 4, 2), 512, 0, stream>>>(ZC, GN_SC, CWT, conv_b, ZC2);
  k_conv5ac_part<<<dim3(100, 8, 2), 64, 0, stream>>>(ZC2, WTL, PARTIAL);
  k_conv5ac_red<<<dim3(25, 32, 2), 256, 0, stream>>>(PARTIAL, FPRE, BNA_PART);
  k_bnfin<<<1, 256, 0, stream>>>(BNA_PART, 50, bn5a_w, bn5a_b, bn5c_w, bn5c_b, BNA_SC);
  k_featqkv<<<dim3(25, 2), 256, 0, stream>>>(FPRE, BNA_SC, pq_w, pq_b, pk_w, pk_b,
                                             pv_w, pv_b, FEAT, QKVT);
  k_pam_a<<<dim3(25, 25, 2), 256, 0, stream>>>(QKVT, PART);
  k_pam_b<<<dim3(25, 8, 2), 256, 0, stream>>>(PART, FEAT, pa_g, PAM_IN);
  k_cam_gram<<<dim3(16, 16, 2), 256, 0, stream>>>(FEAT, CAM_E);
  k_cam_soft<<<1, 64, 0, stream>>>(CAM_E, CAM_ATT);
  k_cam_apply<<<dim3(25, 16, 2), 256, 0, stream>>>(CAM_ATT, FEAT, ca_g, CAM_IN);
  k_conv5bd2<<<dim3(100, 8, 2), 64, 0, stream>>>(PAM_IN, CAM_IN, WT2, BDPRE, BNB_PART);
  k_bnfin<<<1, 256, 0, stream>>>(BNB_PART, 200, bn5b_w, bn5b_b, bn5d_w, bn5d_b, BNB_SC);
  k_c6<<<dim3(25, 8, 2), 256, 0, stream>>>(BDPRE, BNB_SC, c6_w, c6_b, (float*)d_out);
}

// Round 8
// 252.868 us; speedup vs baseline: 2.4161x; 1.1206x over previous
//
#include <hip/hip_runtime.h>
#include <math.h>

#define HW 6400

typedef __attribute__((ext_vector_type(8))) short bf16x8;
typedef __attribute__((ext_vector_type(4))) float f32x4;

__device__ __forceinline__ float wredsum(float v){
  #pragma unroll
  for (int o = 32; o; o >>= 1) v += __shfl_xor(v, o);
  return v;
}

__device__ __forceinline__ unsigned short f2bf(float f){
  unsigned int u = __float_as_uint(f);
  u += 0x7FFF + ((u >> 16) & 1);   // RNE
  return (unsigned short)(u >> 16);
}

// ---------------- K0: weight re-layout prep ----------------
// CWT[c][o] = cw[o*256+c]                                          (65,536 f32)
// WT2[ic][o*9+k] (o<16 -> c5b, o>=16 -> c5d)                       (4,608 f32)
// WBBF[ss][f][l][j] bf16: k=ss*32+(l>>4)*8+j, off=k>>8, ic=k&255,
//                         oc=f*16+(l&15); o<16->c5a else c5c       (73,728 bf16)
__global__ __launch_bounds__(256) void k_wprep(
    const float* __restrict__ wa, const float* __restrict__ wc,
    const float* __restrict__ wb, const float* __restrict__ wd,
    const float* __restrict__ cw,
    float* __restrict__ cwt, float* __restrict__ wt2,
    unsigned short* __restrict__ wbbf){
  int i = blockIdx.x * 256 + threadIdx.x;
  if (i < 65536){
    int c = i >> 8, o = i & 255;
    cwt[i] = cw[o * 256 + c];
  }
  if (i < 16 * 288){
    int ic = i / 288, r = i - ic * 288;
    int o = r / 9, k = r - o * 9;
    float v = (o < 16) ? wb[(o * 16 + ic) * 9 + k] : wd[((o - 16) * 16 + ic) * 9 + k];
    wt2[i] = v;
  }
  if (i < 73728){
    int j = i & 7, l = (i >> 3) & 63, f = (i >> 9) & 1, ss = i >> 10;
    int k = ss * 32 + (l >> 4) * 8 + j;
    int off = k >> 8, ic = k & 255;
    int oc = f * 16 + (l & 15);
    float v = (oc < 16) ? wa[(oc * 256 + ic) * 9 + off]
                        : wc[((oc - 16) * 256 + ic) * 9 + off];
    wbbf[i] = f2bf(v);
  }
}

// ---------------- K1: depthwise dilated convs + GN partial stats ----------------
__global__ __launch_bounds__(256) void k_dw(
    const float* __restrict__ z,
    const float* __restrict__ w0, const float* __restrict__ b0,
    const float* __restrict__ w1, const float* __restrict__ b1,
    const float* __restrict__ w2, const float* __restrict__ b2,
    const float* __restrict__ w3, const float* __restrict__ b3,
    float* __restrict__ zc, float* __restrict__ gnpart){
  int tid = threadIdx.x;
  int c = blockIdx.y, b = blockIdx.z;
  int pix = blockIdx.x * 256 + tid;
  int h = pix / 80, w = pix % 80;
  int part = c >> 6, cl = c & 63;
  const float* wp; const float* bp; int d;
  if (part == 0)      { wp = w0; bp = b0; d = 7; }
  else if (part == 1) { wp = w1; bp = b1; d = 5; }
  else if (part == 2) { wp = w2; bp = b2; d = 2; }
  else                { wp = w3; bp = b3; d = 1; }
  wp += cl * 9;
  const float* zin = z + (b * 256 + c) * HW;
  float acc = bp[cl];
  #pragma unroll
  for (int kh = 0; kh < 3; kh++){
    int hh = h + (kh - 1) * d;
    if ((unsigned)hh < 80u){
      #pragma unroll
      for (int kw = 0; kw < 3; kw++){
        int ww = w + (kw - 1) * d;
        if ((unsigned)ww < 80u) acc += wp[kh * 3 + kw] * zin[hh * 80 + ww];
      }
    }
  }
  zc[(b * 256 + c) * HW + pix] = acc;
  float S = wredsum(acc), Q = wredsum(acc * acc);
  __shared__ float l[8];
  int lane = tid & 63, wid = tid >> 6;
  if (lane == 0){ l[wid] = S; l[4 + wid] = Q; }
  __syncthreads();
  if (tid == 0){
    float SS = l[0] + l[1] + l[2] + l[3];
    float QQ = l[4] + l[5] + l[6] + l[7];
    int blkid = (b * 256 + c) * 25 + blockIdx.x;
    gnpart[blkid * 2] = SS; gnpart[blkid * 2 + 1] = QQ;
  }
}

// ---------------- K2: GN stats finalize -> per (b,c) scale/shift ----------------
__global__ __launch_bounds__(256) void k_gnfin(
    const float* __restrict__ gnpart, const float* __restrict__ gn_w,
    const float* __restrict__ gn_b, float* __restrict__ gn_sc){
  int tid = threadIdx.x; int bg = blockIdx.x; // b*4+g
  float S = 0.f, Q = 0.f;
  for (int i = tid; i < 1600; i += 256){
    S += gnpart[(bg * 1600 + i) * 2];
    Q += gnpart[(bg * 1600 + i) * 2 + 1];
  }
  S = wredsum(S); Q = wredsum(Q);
  __shared__ float l[8];
  int lane = tid & 63, wid = tid >> 6;
  if (lane == 0){ l[wid] = S; l[4 + wid] = Q; }
  __syncthreads();
  float SS = l[0] + l[1] + l[2] + l[3];
  float QQ = l[4] + l[5] + l[6] + l[7];
  float M = 64.f * HW;
  float mean = SS / M;
  float var = QQ / M - mean * mean;
  float rstd = rsqrtf(var + 1e-5f);
  if (tid < 64){
    int b = bg >> 2, g = bg & 3;
    int c = g * 64 + tid;
    float sc = gn_w[c] * rstd;
    float sh = gn_b[c] - mean * sc;
    gn_sc[(b * 256 + c) * 2] = sc;
    gn_sc[(b * 256 + c) * 2 + 1] = sh;
  }
}

// ---------------- K3: GN-apply + 1x1 conv (256->256) + GELU, register-tiled GEMM ----
// grid (50, 4, 2), block 512: 128 pix x 64 oc per block, 4x4 per thread.
// Output: bf16 TRANSPOSED zbfT[b][pix][oc] (consumed by MFMA conv5ac).
__global__ __launch_bounds__(512) void k_conv1(
    const float* __restrict__ zc, const float* __restrict__ gn_sc,
    const float* __restrict__ cwt2, const float* __restrict__ cb,
    unsigned short* __restrict__ zbfT){
  __shared__ __align__(16) float lx[2][16][128];
  __shared__ __align__(16) float lwt[2][16][64];
  int tid = threadIdx.x;
  int pixb = blockIdx.x * 128;
  int ocb = blockIdx.y * 64;
  int b = blockIdx.z;
  int og = tid >> 5, pq = tid & 31;
  int scc = tid >> 5;            // staging channel 0..15
  int spix = (tid & 31) << 2;    // staging pixel quad
  int wcc = tid >> 4, wo = (tid & 15) << 2;  // weight staging (tid<256)
  const float* gb = gn_sc + b * 512;
  const float* zb = zc + (size_t)b * 256 * HW + pixb;
  float4 xr, wr;
  {
    float sc = gb[scc * 2], sh = gb[scc * 2 + 1];
    float4 v = *(const float4*)(zb + (size_t)scc * HW + spix);
    xr = make_float4(v.x * sc + sh, v.y * sc + sh, v.z * sc + sh, v.w * sc + sh);
    if (tid < 256) wr = *(const float4*)(cwt2 + wcc * 256 + ocb + wo);
  }
  *(float4*)&lx[0][scc][spix] = xr;
  if (tid < 256) *(float4*)&lwt[0][wcc][wo] = wr;
  float acc[16];
  #pragma unroll
  for (int i = 0; i < 16; i++) acc[i] = 0.f;
  for (int ph = 0; ph < 16; ph++){
    __syncthreads();
    int buf = ph & 1;
    if (ph < 15){
      int c = (ph + 1) * 16 + scc;
      float sc = gb[c * 2], sh = gb[c * 2 + 1];
      float4 v = *(const float4*)(zb + (size_t)c * HW + spix);
      xr = make_float4(v.x * sc + sh, v.y * sc + sh, v.z * sc + sh, v.w * sc + sh);
      if (tid < 256) wr = *(const float4*)(cwt2 + ((ph + 1) * 16 + wcc) * 256 + ocb + wo);
    }
    #pragma unroll
    for (int cc = 0; cc < 16; cc++){
      float4 xv = *(float4*)&lx[buf][cc][pq << 2];
      float4 wv = *(float4*)&lwt[buf][cc][og << 2];
      float xq[4] = {xv.x, xv.y, xv.z, xv.w};
      float wq[4] = {wv.x, wv.y, wv.z, wv.w};
      #pragma unroll
      for (int p = 0; p < 4; p++)
        #pragma unroll
        for (int o = 0; o < 4; o++)
          acc[p * 4 + o] = fmaf(wq[o], xq[p], acc[p * 4 + o]);
    }
    if (ph < 15){
      *(float4*)&lx[buf ^ 1][scc][spix] = xr;
      if (tid < 256) *(float4*)&lwt[buf ^ 1][wcc][wo] = wr;
    }
  }
  float bs[4];
  #pragma unroll
  for (int o = 0; o < 4; o++) bs[o] = cb[ocb + (og << 2) + o];
  #pragma unroll
  for (int p = 0; p < 4; p++){
    float g[4];
    #pragma unroll
    for (int o = 0; o < 4; o++){
      float v = acc[p * 4 + o] + bs[o];
      g[o] = 0.5f * v * (1.f + erff(v * 0.70710678118f));
    }
    ushort4 r = make_ushort4(f2bf(g[0]), f2bf(g[1]), f2bf(g[2]), f2bf(g[3]));
    *(ushort4*)(zbfT + ((size_t)b * HW + pixb + (pq << 2) + p) * 256 + ocb + (og << 2)) = r;
  }
}

// ---------------- K4a: 3x3 conv 256->32 (c5a|c5c fused) via bf16 MFMA ----------------
// grid (100 pixtiles, 2 kchunks, 2 b), block 256 = 4 waves.
// Wave: 16 pix rows x 32 oc, K = 36 slices of 32 (k = off*256 + ic).
// A = zbfT[pix][ic] (16B/lane direct global), B = WBBF frag-ready (16B/lane).
__global__ __launch_bounds__(256) void k_conv5ac_mfma(
    const unsigned short* __restrict__ zbfT,
    const unsigned short* __restrict__ wbbf,
    float* __restrict__ partial){
  int tid = threadIdx.x;
  int wv = tid >> 6, l = tid & 63;
  int kc = blockIdx.y, b = blockIdx.z;
  int row = l & 15, kg = l >> 4;
  int pix = blockIdx.x * 64 + wv * 16 + row;
  int h = pix / 80, w = pix % 80;
  const unsigned short* aoff[9];
  bool av[9];
  #pragma unroll
  for (int dy = 0; dy < 3; dy++){
    #pragma unroll
    for (int dx = 0; dx < 3; dx++){
      int hh = h + dy - 1, ww = w + dx - 1;
      bool ok = ((unsigned)hh < 80u) && ((unsigned)ww < 80u);
      int pp = ok ? (pix + (dy - 1) * 80 + (dx - 1)) : pix;
      aoff[dy * 3 + dx] = zbfT + ((size_t)b * HW + pp) * 256 + kg * 8;
      av[dy * 3 + dx] = ok;
    }
  }
  f32x4 acc0 = {0.f, 0.f, 0.f, 0.f};
  f32x4 acc1 = {0.f, 0.f, 0.f, 0.f};
  const unsigned short* wp = wbbf + (size_t)kc * 36 * 1024 + l * 8;
  #pragma unroll
  for (int s = 0; s < 36; s++){
    int ss = kc * 36 + s;
    int off = ss >> 3, ic0 = (ss & 7) * 32;
    bf16x8 a = {0, 0, 0, 0, 0, 0, 0, 0};
    if (av[off]) a = *(const bf16x8*)(aoff[off] + ic0);
    bf16x8 b0 = *(const bf16x8*)(wp + s * 1024);
    bf16x8 b1 = *(const bf16x8*)(wp + s * 1024 + 512);
    acc0 = __builtin_amdgcn_mfma_f32_16x16x32_bf16(a, b0, acc0, 0, 0, 0);
    acc1 = __builtin_amdgcn_mfma_f32_16x16x32_bf16(a, b1, acc1, 0, 0, 0);
  }
  // C/D layout (m89): col = lane&15 (oc), row = (lane>>4)*4 + reg (pix in tile)
  int oc = l & 15;
  int prow = blockIdx.x * 64 + wv * 16 + kg * 4;
  float* pp0 = partial + ((size_t)(kc * 2 + b) * 32 + oc) * HW + prow;
  float* pp1 = pp0 + (size_t)16 * HW;
  *(f32x4*)pp0 = acc0;
  *(f32x4*)pp1 = acc1;
}

// ---------------- K4b: reduce split-K partials -> fpre + BN partial stats ----------------
__global__ __launch_bounds__(256) void k_conv5ac_red(
    const float* __restrict__ partial, float* __restrict__ fpre,
    float* __restrict__ bnpart){
  int tid = threadIdx.x; int oc = blockIdx.y, b = blockIdx.z;
  int pix = blockIdx.x * 256 + tid;
  float s = 0.f;
  #pragma unroll
  for (int kc = 0; kc < 2; kc++)
    s += partial[((size_t)(kc * 2 + b) * 32 + oc) * HW + pix];
  fpre[(b * 32 + oc) * HW + pix] = s;
  float S = wredsum(s), Q = wredsum(s * s);
  __shared__ float l[8];
  int lane = tid & 63, wid = tid >> 6;
  if (lane == 0){ l[wid] = S; l[4 + wid] = Q; }
  __syncthreads();
  if (tid == 0){
    bnpart[oc * 100 + (b * 25 + blockIdx.x) * 2]     = l[0] + l[1] + l[2] + l[3];
    bnpart[oc * 100 + (b * 25 + blockIdx.x) * 2 + 1] = l[4] + l[5] + l[6] + l[7];
  }
}

// ---------------- K5/K12: BN finalize (32 channels), parallel reduce ----------------
__global__ __launch_bounds__(256) void k_bnfin(
    const float* __restrict__ part, int nent,
    const float* __restrict__ w1, const float* __restrict__ b1,
    const float* __restrict__ w2, const float* __restrict__ b2,
    float* __restrict__ sc_out){
  __shared__ float lS[8][32], lQ[8][32];
  int tid = threadIdx.x;
  int oc = tid & 31, sl = tid >> 5;
  float S = 0.f, Q = 0.f;
  for (int i = sl; i < nent; i += 8){
    S += part[oc * 2 * nent + i * 2];
    Q += part[oc * 2 * nent + i * 2 + 1];
  }
  lS[sl][oc] = S; lQ[sl][oc] = Q;
  __syncthreads();
  if (tid < 32){
    float SS = 0.f, QQ = 0.f;
    #pragma unroll
    for (int s = 0; s < 8; s++){ SS += lS[s][oc]; QQ += lQ[s][oc]; }
    float M = 2.f * HW;
    float mean = SS / M, var = QQ / M - mean * mean;
    float rstd = rsqrtf(var + 1e-3f);
    float w  = (oc < 16) ? w1[oc] : w2[oc - 16];
    float bb = (oc < 16) ? b1[oc] : b2[oc - 16];
    float sc = w * rstd, sh = bb - mean * sc;
    sc_out[oc * 2] = sc; sc_out[oc * 2 + 1] = sh;
  }
}

// ---------------- K6: BN+relu apply -> feat1/feat2, and q,k,v 1x1 convs ----------------
__global__ __launch_bounds__(256) void k_featqkv(
    const float* __restrict__ fpre, const float* __restrict__ bnsc,
    const float* __restrict__ pqw, const float* __restrict__ pqb,
    const float* __restrict__ pkw, const float* __restrict__ pkb,
    const float* __restrict__ pvw, const float* __restrict__ pvb,
    float* __restrict__ feat, float* __restrict__ qkvT){
  int tid = threadIdx.x; int b = blockIdx.y;
  int n = blockIdx.x * 256 + tid;
  float f1[16], f2[16];
  #pragma unroll
  for (int c = 0; c < 16; c++){
    float v1 = fpre[(b * 32 + c) * HW + n] * bnsc[c * 2] + bnsc[c * 2 + 1];
    f1[c] = fmaxf(v1, 0.f);
    float v2 = fpre[(b * 32 + 16 + c) * HW + n] * bnsc[(16 + c) * 2] + bnsc[(16 + c) * 2 + 1];
    f2[c] = fmaxf(v2, 0.f);
    feat[(b * 32 + c) * HW + n] = f1[c];
    feat[(b * 32 + 16 + c) * HW + n] = f2[c];
  }
  float* o = qkvT + ((size_t)b * HW + n) * 20;
  #pragma unroll
  for (int j = 0; j < 2; j++){
    float q = pqb[j], k = pkb[j];
    #pragma unroll
    for (int c = 0; c < 16; c++){ q += pqw[j * 16 + c] * f1[c]; k += pkw[j * 16 + c] * f1[c]; }
    o[j] = q; o[2 + j] = k;
  }
  #pragma unroll
  for (int j = 0; j < 16; j++){
    float v = pvb[j];
    #pragma unroll
    for (int c = 0; c < 16; c++) v += pvw[j * 16 + c] * f1[c];
    o[4 + j] = v;
  }
}

// ---------------- K7a: PAM flash partials, 25 m-chunks, LDS-staged KV ----------------
__global__ __launch_bounds__(256) void k_pam_a(
    const float* __restrict__ qkvT, float* __restrict__ part){
  __shared__ __align__(16) float lkv[256 * 20];   // 20KB
  int tid = threadIdx.x;
  int n = blockIdx.x * 256 + tid;
  int mc = blockIdx.y, b = blockIdx.z;
  const float* kvg = qkvT + ((size_t)b * HW + mc * 256) * 20;
  #pragma unroll
  for (int j = 0; j < 5; j++){
    float4 v = *(const float4*)(kvg + j * 1024 + tid * 4);
    *(float4*)&lkv[j * 1024 + tid * 4] = v;
  }
  __syncthreads();
  const float* qp = qkvT + ((size_t)b * HW + n) * 20;
  float q0 = qp[0], q1 = qp[1];
  float mx = -1e30f, Z = 0.f;
  float acc[16];
  #pragma unroll
  for (int c = 0; c < 16; c++) acc[c] = 0.f;
  #pragma unroll 2
  for (int mi = 0; mi < 256; mi++){
    const float* kv = lkv + mi * 20;             // uniform -> LDS broadcast
    float k0 = kv[2], k1 = kv[3];
    float s = q0 * k0 + q1 * k1;
    if (__any(s > mx + 8.f)){                    // rare after warm-up
      float nmx = fmaxf(mx, s);
      float r = __expf(mx - nmx);
      mx = nmx;
      Z *= r;
      #pragma unroll
      for (int c = 0; c < 16; c++) acc[c] *= r;
    }
    float p = __expf(s - mx);                    // bounded by e^8
    Z += p;
    #pragma unroll
    for (int c = 0; c < 16; c++) acc[c] += p * kv[4 + c];
  }
  float* pp = part + ((size_t)(b * 25 + mc) * 18) * HW + n;
  pp[0] = mx; pp[HW] = Z;
  #pragma unroll
  for (int c = 0; c < 16; c++) pp[(size_t)(2 + c) * HW] = acc[c];
}

// ---------------- K7b: merge PAM partials (2 channels/block), residual ----------------
__global__ __launch_bounds__(256) void k_pam_b(
    const float* __restrict__ part, const float* __restrict__ feat,
    const float* __restrict__ gammap, float* __restrict__ pam_in){
  int tid = threadIdx.x; int cg = blockIdx.y, b = blockIdx.z;
  int n = blockIdx.x * 256 + tid;
  float gamma = gammap[0];
  float mxs[25]; float mx = -1e30f;
  #pragma unroll
  for (int mc = 0; mc < 25; mc++){
    mxs[mc] = part[((size_t)(b * 25 + mc) * 18) * HW + n];
    mx = fmaxf(mx, mxs[mc]);
  }
  float Z = 0.f, a0 = 0.f, a1 = 0.f;
  #pragma unroll
  for (int mc = 0; mc < 25; mc++){
    const float* pp = part + ((size_t)(b * 25 + mc) * 18) * HW + n;
    float r = __expf(mxs[mc] - mx);
    Z += pp[HW] * r;
    a0 += pp[(size_t)(2 + cg * 2) * HW] * r;
    a1 += pp[(size_t)(3 + cg * 2) * HW] * r;
  }
  float inv = gamma / Z;
  int c0 = cg * 2;
  pam_in[(b * 16 + c0) * HW + n]     = a0 * inv + feat[(b * 32 + c0) * HW + n];
  pam_in[(b * 16 + c0 + 1) * HW + n] = a1 * inv + feat[(b * 32 + c0 + 1) * HW + n];
}

// ---------------- K8: CAM gram matrix e[b,c,d] ----------------
__global__ __launch_bounds__(256) void k_cam_gram(
    const float* __restrict__ feat, float* __restrict__ e){
  int tid = threadIdx.x;
  int dd = blockIdx.x, c = blockIdx.y, b = blockIdx.z;
  const float* fc = feat + (b * 32 + 16 + c) * HW;
  const float* fd = feat + (b * 32 + 16 + dd) * HW;
  float S = 0.f;
  for (int i = tid; i < HW; i += 256) S += fc[i] * fd[i];
  S = wredsum(S);
  __shared__ float l[4];
  int lane = tid & 63, wid = tid >> 6;
  if (lane == 0) l[wid] = S;
  __syncthreads();
  if (tid == 0) e[(b * 16 + c) * 16 + dd] = l[0] + l[1] + l[2] + l[3];
}

// ---------------- K9: CAM softmax of (max - e) rows ----------------
__global__ void k_cam_soft(const float* __restrict__ e, float* __restrict__ att){
  int tid = threadIdx.x; if (tid >= 32) return;
  int b = tid >> 4, c = tid & 15;
  const float* row = e + (b * 16 + c) * 16;
  float r[16]; float mn = 1e30f;
  #pragma unroll
  for (int d = 0; d < 16; d++){ r[d] = row[d]; mn = fminf(mn, r[d]); }
  float p[16]; float s = 0.f;
  #pragma unroll
  for (int d = 0; d < 16; d++){ p[d] = __expf(mn - r[d]); s += p[d]; }
  float inv = 1.f / s;
  #pragma unroll
  for (int d = 0; d < 16; d++) att[(b * 16 + c) * 16 + d] = p[d] * inv;
}

// ---------------- K10: CAM apply + residual ----------------
__global__ __launch_bounds__(256) void k_cam_apply(
    const float* __restrict__ att, const float* __restrict__ feat,
    const float* __restrict__ gammap, float* __restrict__ cam_in){
  int tid = threadIdx.x; int c = blockIdx.y, b = blockIdx.z;
  int n = blockIdx.x * 256 + tid;
  const float* arow = att + (b * 16 + c) * 16;
  float s = 0.f;
  #pragma unroll
  for (int d = 0; d < 16; d++) s += arow[d] * feat[(b * 32 + 16 + d) * HW + n];
  cam_in[(b * 16 + c) * HW + n] = gammap[0] * s + feat[(b * 32 + 16 + c) * HW + n];
}

// ---------------- K11: 3x3 conv 16->32 (c5b|c5d), 4 outputs/thread + BN stats ----------------
__global__ __launch_bounds__(64) void k_conv5bd2(
    const float* __restrict__ pam_in, const float* __restrict__ cam_in,
    const float* __restrict__ wt2,
    float* __restrict__ bdpre, float* __restrict__ bnpart){
  int tid = threadIdx.x;
  int pix = blockIdx.x * 64 + tid;
  int ocg = blockIdx.y, b = blockIdx.z;
  int half = ocg >> 2, oq = (ocg & 3) * 4;
  int h = pix / 80, w = pix % 80;
  int off[9]; float msk[9];
  #pragma unroll
  for (int dy = 0; dy < 3; dy++){
    #pragma unroll
    for (int dx = 0; dx < 3; dx++){
      int hh = h + dy - 1, ww = w + dx - 1;
      bool ok = ((unsigned)hh < 80u) && ((unsigned)ww < 80u);
      off[dy * 3 + dx] = ok ? hh * 80 + ww : 0;
      msk[dy * 3 + dx] = ok ? 1.f : 0.f;
    }
  }
  const float* in = (half ? cam_in : pam_in) + (size_t)b * 16 * HW;
  int obase = half * 16 + oq;
  float acc[4];
  #pragma unroll
  for (int o = 0; o < 4; o++) acc[o] = 0.f;
  float xa[9], xb[9];
  #pragma unroll
  for (int k = 0; k < 9; k++) xa[k] = in[off[k]] * msk[k];
  #pragma unroll
  for (int ic = 0; ic < 16; ic += 2){
    const float* xin1 = in + (size_t)(ic + 1) * HW;
    #pragma unroll
    for (int k = 0; k < 9; k++) xb[k] = xin1[off[k]] * msk[k];
    const float* wr0 = wt2 + ic * 288 + obase * 9;
    #pragma unroll
    for (int o = 0; o < 4; o++){
      float a = acc[o];
      #pragma unroll
      for (int k = 0; k < 9; k++) a += wr0[o * 9 + k] * xa[k];
      acc[o] = a;
    }
    if (ic + 2 < 16){
      const float* xin2 = in + (size_t)(ic + 2) * HW;
      #pragma unroll
      for (int k = 0; k < 9; k++) xa[k] = xin2[off[k]] * msk[k];
    }
    const float* wr1 = wt2 + (ic + 1) * 288 + obase * 9;
    #pragma unroll
    for (int o = 0; o < 4; o++){
      float a = acc[o];
      #pragma unroll
      for (int k = 0; k < 9; k++) a += wr1[o * 9 + k] * xb[k];
      acc[o] = a;
    }
  }
  #pragma unroll
  for (int o = 0; o < 4; o++){
    float v = acc[o];
    bdpre[(b * 32 + obase + o) * HW + pix] = v;
    float S = wredsum(v), Q = wredsum(v * v);
    if (tid == 0){
      bnpart[(obase + o) * 400 + (b * 100 + blockIdx.x) * 2]     = S;
      bnpart[(obase + o) * 400 + (b * 100 + blockIdx.x) * 2 + 1] = Q;
    }
  }
}

// ---------------- K13: fused BN+relu+sum + 1x1 conv 16->256 + relu -> out ----------------
__global__ __launch_bounds__(256) void k_c6(
    const float* __restrict__ bdpre, const float* __restrict__ bnsc,
    const float* __restrict__ w6, const float* __restrict__ b6,
    float* __restrict__ out){
  int tid = threadIdx.x; int og = blockIdx.y * 32, b = blockIdx.z;
  int n = blockIdx.x * 256 + tid;
  float x[16];
  #pragma unroll
  for (int c = 0; c < 16; c++){
    float v1 = bdpre[(b * 32 + c) * HW + n] * bnsc[c * 2] + bnsc[c * 2 + 1];
    float v2 = bdpre[(b * 32 + 16 + c) * HW + n] * bnsc[(16 + c) * 2] + bnsc[(16 + c) * 2 + 1];
    x[c] = fmaxf(v1, 0.f) + fmaxf(v2, 0.f);
  }
  #pragma unroll
  for (int o = 0; o < 32; o++){
    float a = b6[og + o];
    #pragma unroll
    for (int c = 0; c < 16; c++) a += w6[(og + o) * 16 + c] * x[c];
    out[(b * 256 + og + o) * HW + n] = fmaxf(a, 0.f);
  }
}

extern "C" void kernel_launch(void* const* d_in, const int* in_sizes, int n_in,
                              void* d_out, int out_size, void* d_ws, size_t ws_size,
                              hipStream_t stream){
  const float* z      = (const float*)d_in[0];
  const float* w_at0  = (const float*)d_in[1];
  const float* b_at0  = (const float*)d_in[2];
  const float* w_at1  = (const float*)d_in[3];
  const float* b_at1  = (const float*)d_in[4];
  const float* w_at2  = (const float*)d_in[5];
  const float* b_at2  = (const float*)d_in[6];
  const float* w_at3  = (const float*)d_in[7];
  const float* b_at3  = (const float*)d_in[8];
  const float* gn_w   = (const float*)d_in[9];
  const float* gn_b   = (const float*)d_in[10];
  const float* conv_w = (const float*)d_in[11];
  const float* conv_b = (const float*)d_in[12];
  const float* c5a_w  = (const float*)d_in[13];
  const float* bn5a_w = (const float*)d_in[14];
  const float* bn5a_b = (const float*)d_in[15];
  const float* c5c_w  = (const float*)d_in[16];
  const float* bn5c_w = (const float*)d_in[17];
  const float* bn5c_b = (const float*)d_in[18];
  const float* pq_w   = (const float*)d_in[19];
  const float* pq_b   = (const float*)d_in[20];
  const float* pk_w   = (const float*)d_in[21];
  const float* pk_b   = (const float*)d_in[22];
  const float* pv_w   = (const float*)d_in[23];
  const float* pv_b   = (const float*)d_in[24];
  const float* pa_g   = (const float*)d_in[25];
  const float* ca_g   = (const float*)d_in[26];
  const float* c5b_w  = (const float*)d_in[27];
  const float* bn5b_w = (const float*)d_in[28];
  const float* bn5b_b = (const float*)d_in[29];
  const float* c5d_w  = (const float*)d_in[30];
  const float* bn5d_w = (const float*)d_in[31];
  const float* bn5d_b = (const float*)d_in[32];
  const float* c6_w   = (const float*)d_in[33];
  const float* c6_b   = (const float*)d_in[34];

  float* ws = (float*)d_ws;
  float* ZC      = ws;                    // 3,276,800 fp32 (k_dw out, conv1 in)
  float* ZC2     = ZC + 3276800;          // 3,276,800 region
  float* FPRE    = ZC2 + 3276800;         // 409,600
  float* FEAT    = FPRE + 409600;         // 409,600
  float* QKVT    = FEAT + 409600;         // 256,000
  float* PAM_IN  = QKVT + 256000;         // 204,800
  float* CAM_IN  = PAM_IN + 204800;       // 204,800
  float* BDPRE   = CAM_IN + 204800;       // 409,600
  float* ST      = BDPRE + 409600;
  float* GN_SC    = ST;                   // 1024
  float* BNA_SC   = ST + 1024;            // 64
  float* BNB_SC   = ST + 1088;            // 64
  float* CAM_ATT  = ST + 1152;            // 512
  float* CAM_E    = ST + 1664;            // 512
  float* GN_PART  = ST + 2176;            // 25,600
  float* BNA_PART = ST + 27776;           // 3,200
  float* BNB_PART = ST + 30976;           // 12,800
  float* WT2      = ST + 43776;           // 4,608
  float* CWT      = ST + 48384;           // 65,536 ([c][o] transpose)
  unsigned short* WBBF = (unsigned short*)(ST + 113920);  // 73,728 bf16 (36,864 f32)
  // Aliases:
  //  - ZC2BFT (bf16 zc2^T [b][pix][oc], 3,276,800 ushort = 1,638,400 f32) at the TAIL
  //    of the ZC2 region [4,915,200 .. 6,553,600): written by k_conv1, read by
  //    k_conv5ac_mfma, dead after.
  //  - PARTIAL (conv5ac split-K, 2*2*32*HW = 819,200 f32) = ZC[0..819,200): disjoint
  //    from ZC2BFT; ZC fp32 dead after k_conv1 reads it.
  //  - PART (PAM partials, 25*18*2*HW = 5,760,000 f32) spans [0 .. 5,760,000):
  //    clobbers ZC2BFT, which is dead before k_pam_a runs.
  unsigned short* ZC2BFT = (unsigned short*)(ws + 4915200);
  float* PARTIAL = ZC;
  float* PART    = ZC;

  k_wprep<<<288, 256, 0, stream>>>(c5a_w, c5c_w, c5b_w, c5d_w, conv_w, CWT, WT2, WBBF);
  k_dw<<<dim3(25, 256, 2), 256, 0, stream>>>(z, w_at0, b_at0, w_at1, b_at1,
                                             w_at2, b_at2, w_at3, b_at3, ZC, GN_PART);
  k_gnfin<<<8, 256, 0, stream>>>(GN_PART, gn_w, gn_b, GN_SC);
  k_conv1<<<dim3(50, 4, 2), 512, 0, stream>>>(ZC, GN_SC, CWT, conv_b, ZC2BFT);
  k_conv5ac_mfma<<<dim3(100, 2, 2), 256, 0, stream>>>(ZC2BFT, WBBF, PARTIAL);
  k_conv5ac_red<<<dim3(25, 32, 2), 256, 0, stream>>>(PARTIAL, FPRE, BNA_PART);
  k_bnfin<<<1, 256, 0, stream>>>(BNA_PART, 50, bn5a_w, bn5a_b, bn5c_w, bn5c_b, BNA_SC);
  k_featqkv<<<dim3(25, 2), 256, 0, stream>>>(FPRE, BNA_SC, pq_w, pq_b, pk_w, pk_b,
                                             pv_w, pv_b, FEAT, QKVT);
  k_pam_a<<<dim3(25, 25, 2), 256, 0, stream>>>(QKVT, PART);
  k_pam_b<<<dim3(25, 8, 2), 256, 0, stream>>>(PART, FEAT, pa_g, PAM_IN);
  k_cam_gram<<<dim3(16, 16, 2), 256, 0, stream>>>(FEAT, CAM_E);
  k_cam_soft<<<1, 64, 0, stream>>>(CAM_E, CAM_ATT);
  k_cam_apply<<<dim3(25, 16, 2), 256, 0, stream>>>(CAM_ATT, FEAT, ca_g, CAM_IN);
  k_conv5bd2<<<dim3(100, 8, 2), 64, 0, stream>>>(PAM_IN, CAM_IN, WT2, BDPRE, BNB_PART);
  k_bnfin<<<1, 256, 0, stream>>>(BNB_PART, 200, bn5b_w, bn5b_b, bn5d_w, bn5d_b, BNB_SC);
  k_c6<<<dim3(25, 8, 2), 256, 0, stream>>>(BDPRE, BNB_SC, c6_w, c6_b, (float*)d_out);
}

// Round 9
// 238.523 us; speedup vs baseline: 2.5614x; 1.0601x over previous
//
#include <hip/hip_runtime.h>
#include <math.h>

#define HW 6400

typedef __attribute__((ext_vector_type(8))) short bf16x8;
typedef __attribute__((ext_vector_type(4))) float f32x4;

__device__ __forceinline__ float wredsum(float v){
  #pragma unroll
  for (int o = 32; o; o >>= 1) v += __shfl_xor(v, o);
  return v;
}

__device__ __forceinline__ unsigned short f2bf(float f){
  unsigned int u = __float_as_uint(f);
  u += 0x7FFF + ((u >> 16) & 1);   // RNE
  return (unsigned short)(u >> 16);
}

// ---------------- K0: weight re-layout prep ----------------
// CWT[c][o] = cw[o*256+c]                                          (65,536 f32)
// WT2[ic][o*9+k] (o<16 -> c5b, o>=16 -> c5d)                       (4,608 f32)
// WBBF[ss][f][l][j] bf16: k=ss*32+(l>>4)*8+j, off=k>>8, ic=k&255,
//                         oc=f*16+(l&15); o<16->c5a else c5c       (73,728 bf16)
// (ss = off*8 + s : 8 ic-slices per halo offset, in order)
__global__ __launch_bounds__(256) void k_wprep(
    const float* __restrict__ wa, const float* __restrict__ wc,
    const float* __restrict__ wb, const float* __restrict__ wd,
    const float* __restrict__ cw,
    float* __restrict__ cwt, float* __restrict__ wt2,
    unsigned short* __restrict__ wbbf){
  int i = blockIdx.x * 256 + threadIdx.x;
  if (i < 65536){
    int c = i >> 8, o = i & 255;
    cwt[i] = cw[o * 256 + c];
  }
  if (i < 16 * 288){
    int ic = i / 288, r = i - ic * 288;
    int o = r / 9, k = r - o * 9;
    float v = (o < 16) ? wb[(o * 16 + ic) * 9 + k] : wd[((o - 16) * 16 + ic) * 9 + k];
    wt2[i] = v;
  }
  if (i < 73728){
    int j = i & 7, l = (i >> 3) & 63, f = (i >> 9) & 1, ss = i >> 10;
    int k = ss * 32 + (l >> 4) * 8 + j;
    int off = k >> 8, ic = k & 255;
    int oc = f * 16 + (l & 15);
    float v = (oc < 16) ? wa[(oc * 256 + ic) * 9 + off]
                        : wc[((oc - 16) * 256 + ic) * 9 + off];
    wbbf[i] = f2bf(v);
  }
}

// ---------------- K1: depthwise dilated convs + GN partial stats ----------------
__global__ __launch_bounds__(256) void k_dw(
    const float* __restrict__ z,
    const float* __restrict__ w0, const float* __restrict__ b0,
    const float* __restrict__ w1, const float* __restrict__ b1,
    const float* __restrict__ w2, const float* __restrict__ b2,
    const float* __restrict__ w3, const float* __restrict__ b3,
    float* __restrict__ zc, float* __restrict__ gnpart){
  int tid = threadIdx.x;
  int c = blockIdx.y, b = blockIdx.z;
  int pix = blockIdx.x * 256 + tid;
  int h = pix / 80, w = pix % 80;
  int part = c >> 6, cl = c & 63;
  const float* wp; const float* bp; int d;
  if (part == 0)      { wp = w0; bp = b0; d = 7; }
  else if (part == 1) { wp = w1; bp = b1; d = 5; }
  else if (part == 2) { wp = w2; bp = b2; d = 2; }
  else                { wp = w3; bp = b3; d = 1; }
  wp += cl * 9;
  const float* zin = z + (b * 256 + c) * HW;
  float acc = bp[cl];
  #pragma unroll
  for (int kh = 0; kh < 3; kh++){
    int hh = h + (kh - 1) * d;
    if ((unsigned)hh < 80u){
      #pragma unroll
      for (int kw = 0; kw < 3; kw++){
        int ww = w + (kw - 1) * d;
        if ((unsigned)ww < 80u) acc += wp[kh * 3 + kw] * zin[hh * 80 + ww];
      }
    }
  }
  zc[(b * 256 + c) * HW + pix] = acc;
  float S = wredsum(acc), Q = wredsum(acc * acc);
  __shared__ float l[8];
  int lane = tid & 63, wid = tid >> 6;
  if (lane == 0){ l[wid] = S; l[4 + wid] = Q; }
  __syncthreads();
  if (tid == 0){
    float SS = l[0] + l[1] + l[2] + l[3];
    float QQ = l[4] + l[5] + l[6] + l[7];
    int blkid = (b * 256 + c) * 25 + blockIdx.x;
    gnpart[blkid * 2] = SS; gnpart[blkid * 2 + 1] = QQ;
  }
}

// ---------------- K2: GN stats finalize -> per (b,c) scale/shift ----------------
__global__ __launch_bounds__(256) void k_gnfin(
    const float* __restrict__ gnpart, const float* __restrict__ gn_w,
    const float* __restrict__ gn_b, float* __restrict__ gn_sc){
  int tid = threadIdx.x; int bg = blockIdx.x; // b*4+g
  float S = 0.f, Q = 0.f;
  for (int i = tid; i < 1600; i += 256){
    S += gnpart[(bg * 1600 + i) * 2];
    Q += gnpart[(bg * 1600 + i) * 2 + 1];
  }
  S = wredsum(S); Q = wredsum(Q);
  __shared__ float l[8];
  int lane = tid & 63, wid = tid >> 6;
  if (lane == 0){ l[wid] = S; l[4 + wid] = Q; }
  __syncthreads();
  float SS = l[0] + l[1] + l[2] + l[3];
  float QQ = l[4] + l[5] + l[6] + l[7];
  float M = 64.f * HW;
  float mean = SS / M;
  float var = QQ / M - mean * mean;
  float rstd = rsqrtf(var + 1e-5f);
  if (tid < 64){
    int b = bg >> 2, g = bg & 3;
    int c = g * 64 + tid;
    float sc = gn_w[c] * rstd;
    float sh = gn_b[c] - mean * sc;
    gn_sc[(b * 256 + c) * 2] = sc;
    gn_sc[(b * 256 + c) * 2 + 1] = sh;
  }
}

// ---------------- K3: GN-apply + 1x1 conv (256->256) + GELU, register-tiled GEMM ----
// grid (50, 4, 2), block 512: 128 pix x 64 oc per block, 4x4 per thread.
// Output: bf16 TRANSPOSED zbfT[b][pix][oc] (consumed by MFMA conv5ac).
__global__ __launch_bounds__(512) void k_conv1(
    const float* __restrict__ zc, const float* __restrict__ gn_sc,
    const float* __restrict__ cwt2, const float* __restrict__ cb,
    unsigned short* __restrict__ zbfT){
  __shared__ __align__(16) float lx[2][16][128];
  __shared__ __align__(16) float lwt[2][16][64];
  int tid = threadIdx.x;
  int pixb = blockIdx.x * 128;
  int ocb = blockIdx.y * 64;
  int b = blockIdx.z;
  int og = tid >> 5, pq = tid & 31;
  int scc = tid >> 5;            // staging channel 0..15
  int spix = (tid & 31) << 2;    // staging pixel quad
  int wcc = tid >> 4, wo = (tid & 15) << 2;  // weight staging (tid<256)
  const float* gb = gn_sc + b * 512;
  const float* zb = zc + (size_t)b * 256 * HW + pixb;
  float4 xr, wr;
  {
    float sc = gb[scc * 2], sh = gb[scc * 2 + 1];
    float4 v = *(const float4*)(zb + (size_t)scc * HW + spix);
    xr = make_float4(v.x * sc + sh, v.y * sc + sh, v.z * sc + sh, v.w * sc + sh);
    if (tid < 256) wr = *(const float4*)(cwt2 + wcc * 256 + ocb + wo);
  }
  *(float4*)&lx[0][scc][spix] = xr;
  if (tid < 256) *(float4*)&lwt[0][wcc][wo] = wr;
  float acc[16];
  #pragma unroll
  for (int i = 0; i < 16; i++) acc[i] = 0.f;
  for (int ph = 0; ph < 16; ph++){
    __syncthreads();
    int buf = ph & 1;
    if (ph < 15){
      int c = (ph + 1) * 16 + scc;
      float sc = gb[c * 2], sh = gb[c * 2 + 1];
      float4 v = *(const float4*)(zb + (size_t)c * HW + spix);
      xr = make_float4(v.x * sc + sh, v.y * sc + sh, v.z * sc + sh, v.w * sc + sh);
      if (tid < 256) wr = *(const float4*)(cwt2 + ((ph + 1) * 16 + wcc) * 256 + ocb + wo);
    }
    #pragma unroll
    for (int cc = 0; cc < 16; cc++){
      float4 xv = *(float4*)&lx[buf][cc][pq << 2];
      float4 wv = *(float4*)&lwt[buf][cc][og << 2];
      float xq[4] = {xv.x, xv.y, xv.z, xv.w};
      float wq[4] = {wv.x, wv.y, wv.z, wv.w};
      #pragma unroll
      for (int p = 0; p < 4; p++)
        #pragma unroll
        for (int o = 0; o < 4; o++)
          acc[p * 4 + o] = fmaf(wq[o], xq[p], acc[p * 4 + o]);
    }
    if (ph < 15){
      *(float4*)&lx[buf ^ 1][scc][spix] = xr;
      if (tid < 256) *(float4*)&lwt[buf ^ 1][wcc][wo] = wr;
    }
  }
  float bs[4];
  #pragma unroll
  for (int o = 0; o < 4; o++) bs[o] = cb[ocb + (og << 2) + o];
  #pragma unroll
  for (int p = 0; p < 4; p++){
    float g[4];
    #pragma unroll
    for (int o = 0; o < 4; o++){
      float v = acc[p * 4 + o] + bs[o];
      g[o] = 0.5f * v * (1.f + erff(v * 0.70710678118f));
    }
    ushort4 r = make_ushort4(f2bf(g[0]), f2bf(g[1]), f2bf(g[2]), f2bf(g[3]));
    *(ushort4*)(zbfT + ((size_t)b * HW + pixb + (pq << 2) + p) * 256 + ocb + (og << 2)) = r;
  }
}

// ---------------- K4a: 3x3 conv 256->32 (c5a|c5c fused) via bf16 MFMA, LDS-staged ----
// grid (100 pixtiles, 9 halo offsets, 2 b), block 256 = 4 waves.
// Stage: 64 rows x 512B of zbfT (shifted by this block's halo offset, masked at
// stage time), coalesced 32KB contiguous read, XOR-swizzled for conflict-free
// ds_read_b128. Per wave: 16 pix x 32 oc, 8 ic-slices -> 16 MFMA.
// Output transposed through LDS -> fully coalesced 256B-per-oc-row writes.
__global__ __launch_bounds__(256) void k_conv5ac_mfma(
    const unsigned short* __restrict__ zbfT,
    const unsigned short* __restrict__ wbbf,
    float* __restrict__ partial){
  __shared__ __align__(16) unsigned char lmem[64 * 512];   // 32KB
  unsigned short* lda = (unsigned short*)lmem;
  float* lout = (float*)lmem;                              // reused after barrier
  int tid = threadIdx.x;
  int off = blockIdx.y, b = blockIdx.z;
  int dy = off / 3, dx = off % 3;
  int doff = (dy - 1) * 80 + (dx - 1);
  int p0 = blockIdx.x * 64;
  // ---- stage A panel (masked, swizzled) ----
  #pragma unroll
  for (int k = 0; k < 8; k++){
    int m = tid + k * 256;
    int i = m >> 5, c = m & 31;
    int op = p0 + i;
    int h = op / 80, w = op % 80;
    bool v = ((unsigned)(h + dy - 1) < 80u) && ((unsigned)(w + dx - 1) < 80u);
    int sp = v ? (op + doff) : op;               // clamped, always in-bounds
    bf16x8 val = *(const bf16x8*)(zbfT + ((size_t)b * HW + sp) * 256 + c * 8);
    if (!v) val = (bf16x8){0, 0, 0, 0, 0, 0, 0, 0};
    *(bf16x8*)(lda + i * 256 + (c ^ (i & 7)) * 8) = val;
  }
  __syncthreads();
  int wv = tid >> 6, l = tid & 63;
  int row = l & 15, kg = l >> 4;
  int i = wv * 16 + row;
  f32x4 acc0 = {0.f, 0.f, 0.f, 0.f};
  f32x4 acc1 = {0.f, 0.f, 0.f, 0.f};
  const unsigned short* wp = wbbf + (size_t)off * 8 * 1024 + l * 8;
  #pragma unroll
  for (int s = 0; s < 8; s++){
    int c = s * 4 + kg;
    bf16x8 a = *(const bf16x8*)(lda + i * 256 + (c ^ (i & 7)) * 8);
    bf16x8 b0 = *(const bf16x8*)(wp + s * 1024);
    bf16x8 b1 = *(const bf16x8*)(wp + s * 1024 + 512);
    acc0 = __builtin_amdgcn_mfma_f32_16x16x32_bf16(a, b0, acc0, 0, 0, 0);
    acc1 = __builtin_amdgcn_mfma_f32_16x16x32_bf16(a, b1, acc1, 0, 0, 0);
  }
  __syncthreads();   // all lda reads done; reuse lmem as lout [32 oc][65]
  // C/D layout (m89): col = lane&15 (oc), row = (lane>>4)*4 + reg (pix in tile)
  int oc0 = l & 15;
  int plocal = wv * 16 + kg * 4;
  #pragma unroll
  for (int r = 0; r < 4; r++){
    lout[oc0 * 65 + plocal + r] = acc0[r];
    lout[(16 + oc0) * 65 + plocal + r] = acc1[r];
  }
  __syncthreads();
  #pragma unroll
  for (int k = 0; k < 8; k++){
    int m = tid + k * 256;
    int oc = m >> 6, pl = m & 63;
    partial[((size_t)(off * 2 + b) * 32 + oc) * HW + p0 + pl] = lout[oc * 65 + pl];
  }
}

// ---------------- K4b: reduce 9 halo partials -> fpre + BN partial stats ----------------
__global__ __launch_bounds__(256) void k_conv5ac_red(
    const float* __restrict__ partial, float* __restrict__ fpre,
    float* __restrict__ bnpart){
  int tid = threadIdx.x; int oc = blockIdx.y, b = blockIdx.z;
  int pix = blockIdx.x * 256 + tid;
  float s = 0.f;
  #pragma unroll
  for (int off = 0; off < 9; off++)
    s += partial[((size_t)(off * 2 + b) * 32 + oc) * HW + pix];
  fpre[(b * 32 + oc) * HW + pix] = s;
  float S = wredsum(s), Q = wredsum(s * s);
  __shared__ float l[8];
  int lane = tid & 63, wid = tid >> 6;
  if (lane == 0){ l[wid] = S; l[4 + wid] = Q; }
  __syncthreads();
  if (tid == 0){
    bnpart[oc * 100 + (b * 25 + blockIdx.x) * 2]     = l[0] + l[1] + l[2] + l[3];
    bnpart[oc * 100 + (b * 25 + blockIdx.x) * 2 + 1] = l[4] + l[5] + l[6] + l[7];
  }
}

// ---------------- K5/K12: BN finalize (32 channels), parallel reduce ----------------
__global__ __launch_bounds__(256) void k_bnfin(
    const float* __restrict__ part, int nent,
    const float* __restrict__ w1, const float* __restrict__ b1,
    const float* __restrict__ w2, const float* __restrict__ b2,
    float* __restrict__ sc_out){
  __shared__ float lS[8][32], lQ[8][32];
  int tid = threadIdx.x;
  int oc = tid & 31, sl = tid >> 5;
  float S = 0.f, Q = 0.f;
  for (int i = sl; i < nent; i += 8){
    S += part[oc * 2 * nent + i * 2];
    Q += part[oc * 2 * nent + i * 2 + 1];
  }
  lS[sl][oc] = S; lQ[sl][oc] = Q;
  __syncthreads();
  if (tid < 32){
    float SS = 0.f, QQ = 0.f;
    #pragma unroll
    for (int s = 0; s < 8; s++){ SS += lS[s][oc]; QQ += lQ[s][oc]; }
    float M = 2.f * HW;
    float mean = SS / M, var = QQ / M - mean * mean;
    float rstd = rsqrtf(var + 1e-3f);
    float w  = (oc < 16) ? w1[oc] : w2[oc - 16];
    float bb = (oc < 16) ? b1[oc] : b2[oc - 16];
    float sc = w * rstd, sh = bb - mean * sc;
    sc_out[oc * 2] = sc; sc_out[oc * 2 + 1] = sh;
  }
}

// ---------------- K6: BN+relu apply -> feat1/feat2, and q,k,v 1x1 convs ----------------
__global__ __launch_bounds__(256) void k_featqkv(
    const float* __restrict__ fpre, const float* __restrict__ bnsc,
    const float* __restrict__ pqw, const float* __restrict__ pqb,
    const float* __restrict__ pkw, const float* __restrict__ pkb,
    const float* __restrict__ pvw, const float* __restrict__ pvb,
    float* __restrict__ feat, float* __restrict__ qkvT){
  int tid = threadIdx.x; int b = blockIdx.y;
  int n = blockIdx.x * 256 + tid;
  float f1[16], f2[16];
  #pragma unroll
  for (int c = 0; c < 16; c++){
    float v1 = fpre[(b * 32 + c) * HW + n] * bnsc[c * 2] + bnsc[c * 2 + 1];
    f1[c] = fmaxf(v1, 0.f);
    float v2 = fpre[(b * 32 + 16 + c) * HW + n] * bnsc[(16 + c) * 2] + bnsc[(16 + c) * 2 + 1];
    f2[c] = fmaxf(v2, 0.f);
    feat[(b * 32 + c) * HW + n] = f1[c];
    feat[(b * 32 + 16 + c) * HW + n] = f2[c];
  }
  float* o = qkvT + ((size_t)b * HW + n) * 20;
  #pragma unroll
  for (int j = 0; j < 2; j++){
    float q = pqb[j], k = pkb[j];
    #pragma unroll
    for (int c = 0; c < 16; c++){ q += pqw[j * 16 + c] * f1[c]; k += pkw[j * 16 + c] * f1[c]; }
    o[j] = q; o[2 + j] = k;
  }
  #pragma unroll
  for (int j = 0; j < 16; j++){
    float v = pvb[j];
    #pragma unroll
    for (int c = 0; c < 16; c++) v += pvw[j * 16 + c] * f1[c];
    o[4 + j] = v;
  }
}

// ---------------- K7a: PAM flash partials, 25 m-chunks, LDS-staged KV ----------------
__global__ __launch_bounds__(256) void k_pam_a(
    const float* __restrict__ qkvT, float* __restrict__ part){
  __shared__ __align__(16) float lkv[256 * 20];   // 20KB
  int tid = threadIdx.x;
  int n = blockIdx.x * 256 + tid;
  int mc = blockIdx.y, b = blockIdx.z;
  const float* kvg = qkvT + ((size_t)b * HW + mc * 256) * 20;
  #pragma unroll
  for (int j = 0; j < 5; j++){
    float4 v = *(const float4*)(kvg + j * 1024 + tid * 4);
    *(float4*)&lkv[j * 1024 + tid * 4] = v;
  }
  __syncthreads();
  const float* qp = qkvT + ((size_t)b * HW + n) * 20;
  float q0 = qp[0], q1 = qp[1];
  float mx = -1e30f, Z = 0.f;
  float acc[16];
  #pragma unroll
  for (int c = 0; c < 16; c++) acc[c] = 0.f;
  #pragma unroll 2
  for (int mi = 0; mi < 256; mi++){
    const float* kv = lkv + mi * 20;             // uniform -> LDS broadcast
    float k0 = kv[2], k1 = kv[3];
    float s = q0 * k0 + q1 * k1;
    if (__any(s > mx + 8.f)){                    // rare after warm-up
      float nmx = fmaxf(mx, s);
      float r = __expf(mx - nmx);
      mx = nmx;
      Z *= r;
      #pragma unroll
      for (int c = 0; c < 16; c++) acc[c] *= r;
    }
    float p = __expf(s - mx);                    // bounded by e^8
    Z += p;
    #pragma unroll
    for (int c = 0; c < 16; c++) acc[c] += p * kv[4 + c];
  }
  float* pp = part + ((size_t)(b * 25 + mc) * 18) * HW + n;
  pp[0] = mx; pp[HW] = Z;
  #pragma unroll
  for (int c = 0; c < 16; c++) pp[(size_t)(2 + c) * HW] = acc[c];
}

// ---------------- K7b: merge PAM partials (2 channels/block), residual ----------------
__global__ __launch_bounds__(256) void k_pam_b(
    const float* __restrict__ part, const float* __restrict__ feat,
    const float* __restrict__ gammap, float* __restrict__ pam_in){
  int tid = threadIdx.x; int cg = blockIdx.y, b = blockIdx.z;
  int n = blockIdx.x * 256 + tid;
  float gamma = gammap[0];
  float mxs[25]; float mx = -1e30f;
  #pragma unroll
  for (int mc = 0; mc < 25; mc++){
    mxs[mc] = part[((size_t)(b * 25 + mc) * 18) * HW + n];
    mx = fmaxf(mx, mxs[mc]);
  }
  float Z = 0.f, a0 = 0.f, a1 = 0.f;
  #pragma unroll
  for (int mc = 0; mc < 25; mc++){
    const float* pp = part + ((size_t)(b * 25 + mc) * 18) * HW + n;
    float r = __expf(mxs[mc] - mx);
    Z += pp[HW] * r;
    a0 += pp[(size_t)(2 + cg * 2) * HW] * r;
    a1 += pp[(size_t)(3 + cg * 2) * HW] * r;
  }
  float inv = gamma / Z;
  int c0 = cg * 2;
  pam_in[(b * 16 + c0) * HW + n]     = a0 * inv + feat[(b * 32 + c0) * HW + n];
  pam_in[(b * 16 + c0 + 1) * HW + n] = a1 * inv + feat[(b * 32 + c0 + 1) * HW + n];
}

// ---------------- K8: CAM gram matrix e[b,c,d] ----------------
__global__ __launch_bounds__(256) void k_cam_gram(
    const float* __restrict__ feat, float* __restrict__ e){
  int tid = threadIdx.x;
  int dd = blockIdx.x, c = blockIdx.y, b = blockIdx.z;
  const float* fc = feat + (b * 32 + 16 + c) * HW;
  const float* fd = feat + (b * 32 + 16 + dd) * HW;
  float S = 0.f;
  for (int i = tid; i < HW; i += 256) S += fc[i] * fd[i];
  S = wredsum(S);
  __shared__ float l[4];
  int lane = tid & 63, wid = tid >> 6;
  if (lane == 0) l[wid] = S;
  __syncthreads();
  if (tid == 0) e[(b * 16 + c) * 16 + dd] = l[0] + l[1] + l[2] + l[3];
}

// ---------------- K9: CAM softmax of (max - e) rows ----------------
__global__ void k_cam_soft(const float* __restrict__ e, float* __restrict__ att){
  int tid = threadIdx.x; if (tid >= 32) return;
  int b = tid >> 4, c = tid & 15;
  const float* row = e + (b * 16 + c) * 16;
  float r[16]; float mn = 1e30f;
  #pragma unroll
  for (int d = 0; d < 16; d++){ r[d] = row[d]; mn = fminf(mn, r[d]); }
  float p[16]; float s = 0.f;
  #pragma unroll
  for (int d = 0; d < 16; d++){ p[d] = __expf(mn - r[d]); s += p[d]; }
  float inv = 1.f / s;
  #pragma unroll
  for (int d = 0; d < 16; d++) att[(b * 16 + c) * 16 + d] = p[d] * inv;
}

// ---------------- K10: CAM apply + residual ----------------
__global__ __launch_bounds__(256) void k_cam_apply(
    const float* __restrict__ att, const float* __restrict__ feat,
    const float* __restrict__ gammap, float* __restrict__ cam_in){
  int tid = threadIdx.x; int c = blockIdx.y, b = blockIdx.z;
  int n = blockIdx.x * 256 + tid;
  const float* arow = att + (b * 16 + c) * 16;
  float s = 0.f;
  #pragma unroll
  for (int d = 0; d < 16; d++) s += arow[d] * feat[(b * 32 + 16 + d) * HW + n];
  cam_in[(b * 16 + c) * HW + n] = gammap[0] * s + feat[(b * 32 + 16 + c) * HW + n];
}

// ---------------- K11: 3x3 conv 16->32 (c5b|c5d), 4 outputs/thread + BN stats ----------------
__global__ __launch_bounds__(64) void k_conv5bd2(
    const float* __restrict__ pam_in, const float* __restrict__ cam_in,
    const float* __restrict__ wt2,
    float* __restrict__ bdpre, float* __restrict__ bnpart){
  int tid = threadIdx.x;
  int pix = blockIdx.x * 64 + tid;
  int ocg = blockIdx.y, b = blockIdx.z;
  int half = ocg >> 2, oq = (ocg & 3) * 4;
  int h = pix / 80, w = pix % 80;
  int off[9]; float msk[9];
  #pragma unroll
  for (int dy = 0; dy < 3; dy++){
    #pragma unroll
    for (int dx = 0; dx < 3; dx++){
      int hh = h + dy - 1, ww = w + dx - 1;
      bool ok = ((unsigned)hh < 80u) && ((unsigned)ww < 80u);
      off[dy * 3 + dx] = ok ? hh * 80 + ww : 0;
      msk[dy * 3 + dx] = ok ? 1.f : 0.f;
    }
  }
  const float* in = (half ? cam_in : pam_in) + (size_t)b * 16 * HW;
  int obase = half * 16 + oq;
  float acc[4];
  #pragma unroll
  for (int o = 0; o < 4; o++) acc[o] = 0.f;
  float xa[9], xb[9];
  #pragma unroll
  for (int k = 0; k < 9; k++) xa[k] = in[off[k]] * msk[k];
  #pragma unroll
  for (int ic = 0; ic < 16; ic += 2){
    const float* xin1 = in + (size_t)(ic + 1) * HW;
    #pragma unroll
    for (int k = 0; k < 9; k++) xb[k] = xin1[off[k]] * msk[k];
    const float* wr0 = wt2 + ic * 288 + obase * 9;
    #pragma unroll
    for (int o = 0; o < 4; o++){
      float a = acc[o];
      #pragma unroll
      for (int k = 0; k < 9; k++) a += wr0[o * 9 + k] * xa[k];
      acc[o] = a;
    }
    if (ic + 2 < 16){
      const float* xin2 = in + (size_t)(ic + 2) * HW;
      #pragma unroll
      for (int k = 0; k < 9; k++) xa[k] = xin2[off[k]] * msk[k];
    }
    const float* wr1 = wt2 + (ic + 1) * 288 + obase * 9;
    #pragma unroll
    for (int o = 0; o < 4; o++){
      float a = acc[o];
      #pragma unroll
      for (int k = 0; k < 9; k++) a += wr1[o * 9 + k] * xb[k];
      acc[o] = a;
    }
  }
  #pragma unroll
  for (int o = 0; o < 4; o++){
    float v = acc[o];
    bdpre[(b * 32 + obase + o) * HW + pix] = v;
    float S = wredsum(v), Q = wredsum(v * v);
    if (tid == 0){
      bnpart[(obase + o) * 400 + (b * 100 + blockIdx.x) * 2]     = S;
      bnpart[(obase + o) * 400 + (b * 100 + blockIdx.x) * 2 + 1] = Q;
    }
  }
}

// ---------------- K13: fused BN+relu+sum + 1x1 conv 16->256 + relu -> out ----------------
__global__ __launch_bounds__(256) void k_c6(
    const float* __restrict__ bdpre, const float* __restrict__ bnsc,
    const float* __restrict__ w6, const float* __restrict__ b6,
    float* __restrict__ out){
  int tid = threadIdx.x; int og = blockIdx.y * 32, b = blockIdx.z;
  int n = blockIdx.x * 256 + tid;
  float x[16];
  #pragma unroll
  for (int c = 0; c < 16; c++){
    float v1 = bdpre[(b * 32 + c) * HW + n] * bnsc[c * 2] + bnsc[c * 2 + 1];
    float v2 = bdpre[(b * 32 + 16 + c) * HW + n] * bnsc[(16 + c) * 2] + bnsc[(16 + c) * 2 + 1];
    x[c] = fmaxf(v1, 0.f) + fmaxf(v2, 0.f);
  }
  #pragma unroll
  for (int o = 0; o < 32; o++){
    float a = b6[og + o];
    #pragma unroll
    for (int c = 0; c < 16; c++) a += w6[(og + o) * 16 + c] * x[c];
    out[(b * 256 + og + o) * HW + n] = fmaxf(a, 0.f);
  }
}

extern "C" void kernel_launch(void* const* d_in, const int* in_sizes, int n_in,
                              void* d_out, int out_size, void* d_ws, size_t ws_size,
                              hipStream_t stream){
  const float* z      = (const float*)d_in[0];
  const float* w_at0  = (const float*)d_in[1];
  const float* b_at0  = (const float*)d_in[2];
  const float* w_at1  = (const float*)d_in[3];
  const float* b_at1  = (const float*)d_in[4];
  const float* w_at2  = (const float*)d_in[5];
  const float* b_at2  = (const float*)d_in[6];
  const float* w_at3  = (const float*)d_in[7];
  const float* b_at3  = (const float*)d_in[8];
  const float* gn_w   = (const float*)d_in[9];
  const float* gn_b   = (const float*)d_in[10];
  const float* conv_w = (const float*)d_in[11];
  const float* conv_b = (const float*)d_in[12];
  const float* c5a_w  = (const float*)d_in[13];
  const float* bn5a_w = (const float*)d_in[14];
  const float* bn5a_b = (const float*)d_in[15];
  const float* c5c_w  = (const float*)d_in[16];
  const float* bn5c_w = (const float*)d_in[17];
  const float* bn5c_b = (const float*)d_in[18];
  const float* pq_w   = (const float*)d_in[19];
  const float* pq_b   = (const float*)d_in[20];
  const float* pk_w   = (const float*)d_in[21];
  const float* pk_b   = (const float*)d_in[22];
  const float* pv_w   = (const float*)d_in[23];
  const float* pv_b   = (const float*)d_in[24];
  const float* pa_g   = (const float*)d_in[25];
  const float* ca_g   = (const float*)d_in[26];
  const float* c5b_w  = (const float*)d_in[27];
  const float* bn5b_w = (const float*)d_in[28];
  const float* bn5b_b = (const float*)d_in[29];
  const float* c5d_w  = (const float*)d_in[30];
  const float* bn5d_w = (const float*)d_in[31];
  const float* bn5d_b = (const float*)d_in[32];
  const float* c6_w   = (const float*)d_in[33];
  const float* c6_b   = (const float*)d_in[34];

  float* ws = (float*)d_ws;
  float* ZC      = ws;                    // 3,276,800 fp32 (k_dw out, conv1 in)
  float* ZC2     = ZC + 3276800;          // 3,276,800 region
  float* FPRE    = ZC2 + 3276800;         // 409,600
  float* FEAT    = FPRE + 409600;         // 409,600
  float* QKVT    = FEAT + 409600;         // 256,000
  float* PAM_IN  = QKVT + 256000;         // 204,800
  float* CAM_IN  = PAM_IN + 204800;       // 204,800
  float* BDPRE   = CAM_IN + 204800;       // 409,600
  float* ST      = BDPRE + 409600;
  float* GN_SC    = ST;                   // 1024
  float* BNA_SC   = ST + 1024;            // 64
  float* BNB_SC   = ST + 1088;            // 64
  float* CAM_ATT  = ST + 1152;            // 512
  float* CAM_E    = ST + 1664;            // 512
  float* GN_PART  = ST + 2176;            // 25,600
  float* BNA_PART = ST + 27776;           // 3,200
  float* BNB_PART = ST + 30976;           // 12,800
  float* WT2      = ST + 43776;           // 4,608
  float* CWT      = ST + 48384;           // 65,536 ([c][o] transpose)
  unsigned short* WBBF = (unsigned short*)(ST + 113920);  // 73,728 bf16 (36,864 f32)
  // Aliases:
  //  - ZC2BFT (bf16 zc2^T [b][pix][oc], 3,276,800 ushort = 1,638,400 f32) at the TAIL
  //    of the ZC2 region [4,915,200 .. 6,553,600): written by k_conv1, read by
  //    k_conv5ac_mfma, dead after.
  //  - PARTIAL (conv5ac halo partials, 9*2*32*HW = 3,686,400 f32) = [0 .. 3,686,400):
  //    disjoint from ZC2BFT; ZC fp32 dead after k_conv1 reads it.
  //  - PART (PAM partials, 25*18*2*HW = 5,760,000 f32) spans [0 .. 5,760,000):
  //    clobbers ZC2BFT, which is dead before k_pam_a runs.
  unsigned short* ZC2BFT = (unsigned short*)(ws + 4915200);
  float* PARTIAL = ZC;
  float* PART    = ZC;

  k_wprep<<<288, 256, 0, stream>>>(c5a_w, c5c_w, c5b_w, c5d_w, conv_w, CWT, WT2, WBBF);
  k_dw<<<dim3(25, 256, 2), 256, 0, stream>>>(z, w_at0, b_at0, w_at1, b_at1,
                                             w_at2, b_at2, w_at3, b_at3, ZC, GN_PART);
  k_gnfin<<<8, 256, 0, stream>>>(GN_PART, gn_w, gn_b, GN_SC);
  k_conv1<<<dim3(50, 4, 2), 512, 0, stream>>>(ZC, GN_SC, CWT, conv_b, ZC2BFT);
  k_conv5ac_mfma<<<dim3(100, 9, 2), 256, 0, stream>>>(ZC2BFT, WBBF, PARTIAL);
  k_conv5ac_red<<<dim3(25, 32, 2), 256, 0, stream>>>(PARTIAL, FPRE, BNA_PART);
  k_bnfin<<<1, 256, 0, stream>>>(BNA_PART, 50, bn5a_w, bn5a_b, bn5c_w, bn5c_b, BNA_SC);
  k_featqkv<<<dim3(25, 2), 256, 0, stream>>>(FPRE, BNA_SC, pq_w, pq_b, pk_w, pk_b,
                                             pv_w, pv_b, FEAT, QKVT);
  k_pam_a<<<dim3(25, 25, 2), 256, 0, stream>>>(QKVT, PART);
  k_pam_b<<<dim3(25, 8, 2), 256, 0, stream>>>(PART, FEAT, pa_g, PAM_IN);
  k_cam_gram<<<dim3(16, 16, 2), 256, 0, stream>>>(FEAT, CAM_E);
  k_cam_soft<<<1, 64, 0, stream>>>(CAM_E, CAM_ATT);
  k_cam_apply<<<dim3(25, 16, 2), 256, 0, stream>>>(CAM_ATT, FEAT, ca_g, CAM_IN);
  k_conv5bd2<<<dim3(100, 8, 2), 64, 0, stream>>>(PAM_IN, CAM_IN, WT2, BDPRE, BNB_PART);
  k_bnfin<<<1, 256, 0, stream>>>(BNB_PART, 200, bn5b_w, bn5b_b, bn5d_w, bn5d_b, BNB_SC);
  k_c6<<<dim3(25, 8, 2), 256, 0, stream>>>(BDPRE, BNB_SC, c6_w, c6_b, (float*)d_out);
}

// Round 10
// 201.514 us; speedup vs baseline: 3.0319x; 1.1837x over previous
//
#include <hip/hip_runtime.h>
#include <math.h>

#define HW 6400

typedef __attribute__((ext_vector_type(8))) short bf16x8;
typedef __attribute__((ext_vector_type(4))) float f32x4;

__device__ __forceinline__ float wredsum(float v){
  #pragma unroll
  for (int o = 32; o; o >>= 1) v += __shfl_xor(v, o);
  return v;
}

__device__ __forceinline__ unsigned short f2bf(float f){
  unsigned int u = __float_as_uint(f);
  u += 0x7FFF + ((u >> 16) & 1);   // RNE
  return (unsigned short)(u >> 16);
}

__device__ __forceinline__ unsigned int cvt_pk_bf16(float lo, float hi){
  unsigned int r;
  asm("v_cvt_pk_bf16_f32 %0, %1, %2" : "=v"(r) : "v"(lo), "v"(hi));
  return r;
}

// ---------------- K0: weight re-layout prep ----------------
__global__ __launch_bounds__(256) void k_wprep(
    const float* __restrict__ wa, const float* __restrict__ wc,
    const float* __restrict__ wb, const float* __restrict__ wd,
    const float* __restrict__ cw,
    float* __restrict__ cwt, float* __restrict__ wt2,
    unsigned short* __restrict__ wbbf){
  int i = blockIdx.x * 256 + threadIdx.x;
  if (i < 65536){
    int c = i >> 8, o = i & 255;
    cwt[i] = cw[o * 256 + c];
  }
  if (i < 16 * 288){
    int ic = i / 288, r = i - ic * 288;
    int o = r / 9, k = r - o * 9;
    float v = (o < 16) ? wb[(o * 16 + ic) * 9 + k] : wd[((o - 16) * 16 + ic) * 9 + k];
    wt2[i] = v;
  }
  if (i < 73728){
    int j = i & 7, l = (i >> 3) & 63, f = (i >> 9) & 1, ss = i >> 10;
    int k = ss * 32 + (l >> 4) * 8 + j;
    int off = k >> 8, ic = k & 255;
    int oc = f * 16 + (l & 15);
    float v = (oc < 16) ? wa[(oc * 256 + ic) * 9 + off]
                        : wc[((oc - 16) * 256 + ic) * 9 + off];
    wbbf[i] = f2bf(v);
  }
}

// ---------------- K1: depthwise dilated convs + GN partial stats ----------------
__global__ __launch_bounds__(256) void k_dw(
    const float* __restrict__ z,
    const float* __restrict__ w0, const float* __restrict__ b0,
    const float* __restrict__ w1, const float* __restrict__ b1,
    const float* __restrict__ w2, const float* __restrict__ b2,
    const float* __restrict__ w3, const float* __restrict__ b3,
    float* __restrict__ zc, float* __restrict__ gnpart){
  int tid = threadIdx.x;
  int c = blockIdx.y, b = blockIdx.z;
  int pix = blockIdx.x * 256 + tid;
  int h = pix / 80, w = pix % 80;
  int part = c >> 6, cl = c & 63;
  const float* wp; const float* bp; int d;
  if (part == 0)      { wp = w0; bp = b0; d = 7; }
  else if (part == 1) { wp = w1; bp = b1; d = 5; }
  else if (part == 2) { wp = w2; bp = b2; d = 2; }
  else                { wp = w3; bp = b3; d = 1; }
  wp += cl * 9;
  const float* zin = z + (b * 256 + c) * HW;
  float acc = bp[cl];
  #pragma unroll
  for (int kh = 0; kh < 3; kh++){
    int hh = h + (kh - 1) * d;
    if ((unsigned)hh < 80u){
      #pragma unroll
      for (int kw = 0; kw < 3; kw++){
        int ww = w + (kw - 1) * d;
        if ((unsigned)ww < 80u) acc += wp[kh * 3 + kw] * zin[hh * 80 + ww];
      }
    }
  }
  zc[(b * 256 + c) * HW + pix] = acc;
  float S = wredsum(acc), Q = wredsum(acc * acc);
  __shared__ float l[8];
  int lane = tid & 63, wid = tid >> 6;
  if (lane == 0){ l[wid] = S; l[4 + wid] = Q; }
  __syncthreads();
  if (tid == 0){
    float SS = l[0] + l[1] + l[2] + l[3];
    float QQ = l[4] + l[5] + l[6] + l[7];
    int blkid = (b * 256 + c) * 25 + blockIdx.x;
    gnpart[blkid * 2] = SS; gnpart[blkid * 2 + 1] = QQ;
  }
}

// ---------------- K2: GN stats finalize -> per (b,c) scale/shift ----------------
__global__ __launch_bounds__(256) void k_gnfin(
    const float* __restrict__ gnpart, const float* __restrict__ gn_w,
    const float* __restrict__ gn_b, float* __restrict__ gn_sc){
  int tid = threadIdx.x; int bg = blockIdx.x; // b*4+g
  float S = 0.f, Q = 0.f;
  for (int i = tid; i < 1600; i += 256){
    S += gnpart[(bg * 1600 + i) * 2];
    Q += gnpart[(bg * 1600 + i) * 2 + 1];
  }
  S = wredsum(S); Q = wredsum(Q);
  __shared__ float l[8];
  int lane = tid & 63, wid = tid >> 6;
  if (lane == 0){ l[wid] = S; l[4 + wid] = Q; }
  __syncthreads();
  float SS = l[0] + l[1] + l[2] + l[3];
  float QQ = l[4] + l[5] + l[6] + l[7];
  float M = 64.f * HW;
  float mean = SS / M;
  float var = QQ / M - mean * mean;
  float rstd = rsqrtf(var + 1e-5f);
  if (tid < 64){
    int b = bg >> 2, g = bg & 3;
    int c = g * 64 + tid;
    float sc = gn_w[c] * rstd;
    float sh = gn_b[c] - mean * sc;
    gn_sc[(b * 256 + c) * 2] = sc;
    gn_sc[(b * 256 + c) * 2 + 1] = sh;
  }
}

// ---------------- K3: GN-apply + 1x1 conv (256->256) + GELU, register-tiled GEMM ----
__global__ __launch_bounds__(512) void k_conv1(
    const float* __restrict__ zc, const float* __restrict__ gn_sc,
    const float* __restrict__ cwt2, const float* __restrict__ cb,
    unsigned short* __restrict__ zbfT){
  __shared__ __align__(16) float lx[2][16][128];
  __shared__ __align__(16) float lwt[2][16][64];
  int tid = threadIdx.x;
  int pixb = blockIdx.x * 128;
  int ocb = blockIdx.y * 64;
  int b = blockIdx.z;
  int og = tid >> 5, pq = tid & 31;
  int scc = tid >> 5;
  int spix = (tid & 31) << 2;
  int wcc = tid >> 4, wo = (tid & 15) << 2;
  const float* gb = gn_sc + b * 512;
  const float* zb = zc + (size_t)b * 256 * HW + pixb;
  float4 xr, wr;
  {
    float sc = gb[scc * 2], sh = gb[scc * 2 + 1];
    float4 v = *(const float4*)(zb + (size_t)scc * HW + spix);
    xr = make_float4(v.x * sc + sh, v.y * sc + sh, v.z * sc + sh, v.w * sc + sh);
    if (tid < 256) wr = *(const float4*)(cwt2 + wcc * 256 + ocb + wo);
  }
  *(float4*)&lx[0][scc][spix] = xr;
  if (tid < 256) *(float4*)&lwt[0][wcc][wo] = wr;
  float acc[16];
  #pragma unroll
  for (int i = 0; i < 16; i++) acc[i] = 0.f;
  for (int ph = 0; ph < 16; ph++){
    __syncthreads();
    int buf = ph & 1;
    if (ph < 15){
      int c = (ph + 1) * 16 + scc;
      float sc = gb[c * 2], sh = gb[c * 2 + 1];
      float4 v = *(const float4*)(zb + (size_t)c * HW + spix);
      xr = make_float4(v.x * sc + sh, v.y * sc + sh, v.z * sc + sh, v.w * sc + sh);
      if (tid < 256) wr = *(const float4*)(cwt2 + ((ph + 1) * 16 + wcc) * 256 + ocb + wo);
    }
    #pragma unroll
    for (int cc = 0; cc < 16; cc++){
      float4 xv = *(float4*)&lx[buf][cc][pq << 2];
      float4 wv = *(float4*)&lwt[buf][cc][og << 2];
      float xq[4] = {xv.x, xv.y, xv.z, xv.w};
      float wq[4] = {wv.x, wv.y, wv.z, wv.w};
      #pragma unroll
      for (int p = 0; p < 4; p++)
        #pragma unroll
        for (int o = 0; o < 4; o++)
          acc[p * 4 + o] = fmaf(wq[o], xq[p], acc[p * 4 + o]);
    }
    if (ph < 15){
      *(float4*)&lx[buf ^ 1][scc][spix] = xr;
      if (tid < 256) *(float4*)&lwt[buf ^ 1][wcc][wo] = wr;
    }
  }
  float bs[4];
  #pragma unroll
  for (int o = 0; o < 4; o++) bs[o] = cb[ocb + (og << 2) + o];
  #pragma unroll
  for (int p = 0; p < 4; p++){
    float g[4];
    #pragma unroll
    for (int o = 0; o < 4; o++){
      float v = acc[p * 4 + o] + bs[o];
      g[o] = 0.5f * v * (1.f + erff(v * 0.70710678118f));
    }
    ushort4 r = make_ushort4(f2bf(g[0]), f2bf(g[1]), f2bf(g[2]), f2bf(g[3]));
    *(ushort4*)(zbfT + ((size_t)b * HW + pixb + (pq << 2) + p) * 256 + ocb + (og << 2)) = r;
  }
}

// ---------------- K4a: 3x3 conv 256->32 (c5a|c5c fused) via bf16 MFMA, LDS-staged ----
__global__ __launch_bounds__(256) void k_conv5ac_mfma(
    const unsigned short* __restrict__ zbfT,
    const unsigned short* __restrict__ wbbf,
    float* __restrict__ partial){
  __shared__ __align__(16) unsigned char lmem[64 * 512];   // 32KB
  unsigned short* lda = (unsigned short*)lmem;
  float* lout = (float*)lmem;
  int tid = threadIdx.x;
  int off = blockIdx.y, b = blockIdx.z;
  int dy = off / 3, dx = off % 3;
  int doff = (dy - 1) * 80 + (dx - 1);
  int p0 = blockIdx.x * 64;
  #pragma unroll
  for (int k = 0; k < 8; k++){
    int m = tid + k * 256;
    int i = m >> 5, c = m & 31;
    int op = p0 + i;
    int h = op / 80, w = op % 80;
    bool v = ((unsigned)(h + dy - 1) < 80u) && ((unsigned)(w + dx - 1) < 80u);
    int sp = v ? (op + doff) : op;
    bf16x8 val = *(const bf16x8*)(zbfT + ((size_t)b * HW + sp) * 256 + c * 8);
    if (!v) val = (bf16x8){0, 0, 0, 0, 0, 0, 0, 0};
    *(bf16x8*)(lda + i * 256 + (c ^ (i & 7)) * 8) = val;
  }
  __syncthreads();
  int wv = tid >> 6, l = tid & 63;
  int row = l & 15, kg = l >> 4;
  int i = wv * 16 + row;
  f32x4 acc0 = {0.f, 0.f, 0.f, 0.f};
  f32x4 acc1 = {0.f, 0.f, 0.f, 0.f};
  const unsigned short* wp = wbbf + (size_t)off * 8 * 1024 + l * 8;
  #pragma unroll
  for (int s = 0; s < 8; s++){
    int c = s * 4 + kg;
    bf16x8 a = *(const bf16x8*)(lda + i * 256 + (c ^ (i & 7)) * 8);
    bf16x8 b0 = *(const bf16x8*)(wp + s * 1024);
    bf16x8 b1 = *(const bf16x8*)(wp + s * 1024 + 512);
    acc0 = __builtin_amdgcn_mfma_f32_16x16x32_bf16(a, b0, acc0, 0, 0, 0);
    acc1 = __builtin_amdgcn_mfma_f32_16x16x32_bf16(a, b1, acc1, 0, 0, 0);
  }
  __syncthreads();
  int oc0 = l & 15;
  int plocal = wv * 16 + kg * 4;
  #pragma unroll
  for (int r = 0; r < 4; r++){
    lout[oc0 * 65 + plocal + r] = acc0[r];
    lout[(16 + oc0) * 65 + plocal + r] = acc1[r];
  }
  __syncthreads();
  #pragma unroll
  for (int k = 0; k < 8; k++){
    int m = tid + k * 256;
    int oc = m >> 6, pl = m & 63;
    partial[((size_t)(off * 2 + b) * 32 + oc) * HW + p0 + pl] = lout[oc * 65 + pl];
  }
}

// ---------------- K4b: reduce 9 halo partials -> fpre + BN partial stats ----------------
__global__ __launch_bounds__(256) void k_conv5ac_red(
    const float* __restrict__ partial, float* __restrict__ fpre,
    float* __restrict__ bnpart){
  int tid = threadIdx.x; int oc = blockIdx.y, b = blockIdx.z;
  int pix = blockIdx.x * 256 + tid;
  float s = 0.f;
  #pragma unroll
  for (int off = 0; off < 9; off++)
    s += partial[((size_t)(off * 2 + b) * 32 + oc) * HW + pix];
  fpre[(b * 32 + oc) * HW + pix] = s;
  float S = wredsum(s), Q = wredsum(s * s);
  __shared__ float l[8];
  int lane = tid & 63, wid = tid >> 6;
  if (lane == 0){ l[wid] = S; l[4 + wid] = Q; }
  __syncthreads();
  if (tid == 0){
    bnpart[oc * 100 + (b * 25 + blockIdx.x) * 2]     = l[0] + l[1] + l[2] + l[3];
    bnpart[oc * 100 + (b * 25 + blockIdx.x) * 2 + 1] = l[4] + l[5] + l[6] + l[7];
  }
}

// ---------------- K5/K12: BN finalize (32 channels), parallel reduce ----------------
__global__ __launch_bounds__(256) void k_bnfin(
    const float* __restrict__ part, int nent,
    const float* __restrict__ w1, const float* __restrict__ b1,
    const float* __restrict__ w2, const float* __restrict__ b2,
    float* __restrict__ sc_out){
  __shared__ float lS[8][32], lQ[8][32];
  int tid = threadIdx.x;
  int oc = tid & 31, sl = tid >> 5;
  float S = 0.f, Q = 0.f;
  for (int i = sl; i < nent; i += 8){
    S += part[oc * 2 * nent + i * 2];
    Q += part[oc * 2 * nent + i * 2 + 1];
  }
  lS[sl][oc] = S; lQ[sl][oc] = Q;
  __syncthreads();
  if (tid < 32){
    float SS = 0.f, QQ = 0.f;
    #pragma unroll
    for (int s = 0; s < 8; s++){ SS += lS[s][oc]; QQ += lQ[s][oc]; }
    float M = 2.f * HW;
    float mean = SS / M, var = QQ / M - mean * mean;
    float rstd = rsqrtf(var + 1e-3f);
    float w  = (oc < 16) ? w1[oc] : w2[oc - 16];
    float bb = (oc < 16) ? b1[oc] : b2[oc - 16];
    float sc = w * rstd, sh = bb - mean * sc;
    sc_out[oc * 2] = sc; sc_out[oc * 2 + 1] = sh;
  }
}

// ---------------- K6: BN+relu apply -> feat1/feat2, and q,k,v 1x1 convs ----------------
__global__ __launch_bounds__(256) void k_featqkv(
    const float* __restrict__ fpre, const float* __restrict__ bnsc,
    const float* __restrict__ pqw, const float* __restrict__ pqb,
    const float* __restrict__ pkw, const float* __restrict__ pkb,
    const float* __restrict__ pvw, const float* __restrict__ pvb,
    float* __restrict__ feat, float* __restrict__ qkvT){
  int tid = threadIdx.x; int b = blockIdx.y;
  int n = blockIdx.x * 256 + tid;
  float f1[16], f2[16];
  #pragma unroll
  for (int c = 0; c < 16; c++){
    float v1 = fpre[(b * 32 + c) * HW + n] * bnsc[c * 2] + bnsc[c * 2 + 1];
    f1[c] = fmaxf(v1, 0.f);
    float v2 = fpre[(b * 32 + 16 + c) * HW + n] * bnsc[(16 + c) * 2] + bnsc[(16 + c) * 2 + 1];
    f2[c] = fmaxf(v2, 0.f);
    feat[(b * 32 + c) * HW + n] = f1[c];
    feat[(b * 32 + 16 + c) * HW + n] = f2[c];
  }
  float* o = qkvT + ((size_t)b * HW + n) * 20;
  #pragma unroll
  for (int j = 0; j < 2; j++){
    float q = pqb[j], k = pkb[j];
    #pragma unroll
    for (int c = 0; c < 16; c++){ q += pqw[j * 16 + c] * f1[c]; k += pkw[j * 16 + c] * f1[c]; }
    o[j] = q; o[2 + j] = k;
  }
  #pragma unroll
  for (int j = 0; j < 16; j++){
    float v = pvb[j];
    #pragma unroll
    for (int c = 0; c < 16; c++) v += pvw[j * 16 + c] * f1[c];
    o[4 + j] = v;
  }
}

// ---------------- K7a: PAM flash partials via MFMA PV, 8 m-chunks of 800 ----------------
// grid (100 n-tiles, 8, 2), block 256 = 4 waves; wave = 16 n-rows x 16 ch.
// Bound-max: mx_r = |q_r| * max_chunk|k| (p <= 1, no rescale branches).
// P computed in VALU (s, exp), packed bf16 via v_cvt_pk_bf16_f32, PV via MFMA.
__global__ __launch_bounds__(256) void k_pam_a(
    const float* __restrict__ qkvT, float* __restrict__ part){
  __shared__ __align__(16) float lk0[800];
  __shared__ __align__(16) float lk1[800];
  __shared__ __align__(16) unsigned short lvb[16][808];
  __shared__ float lred[4];
  int tid = threadIdx.x;
  int mc = blockIdx.y, b = blockIdx.z;
  float sqm = 0.f;
  for (int m = tid; m < 800; m += 256){
    const float* kv = qkvT + ((size_t)b * HW + mc * 800 + m) * 20;
    float4 a0 = *(const float4*)kv;
    lk0[m] = a0.z; lk1[m] = a0.w;
    sqm = fmaxf(sqm, a0.z * a0.z + a0.w * a0.w);
    float4 v0 = *(const float4*)(kv + 4);
    float4 v1 = *(const float4*)(kv + 8);
    float4 v2 = *(const float4*)(kv + 12);
    float4 v3 = *(const float4*)(kv + 16);
    lvb[0][m]  = f2bf(v0.x); lvb[1][m]  = f2bf(v0.y);
    lvb[2][m]  = f2bf(v0.z); lvb[3][m]  = f2bf(v0.w);
    lvb[4][m]  = f2bf(v1.x); lvb[5][m]  = f2bf(v1.y);
    lvb[6][m]  = f2bf(v1.z); lvb[7][m]  = f2bf(v1.w);
    lvb[8][m]  = f2bf(v2.x); lvb[9][m]  = f2bf(v2.y);
    lvb[10][m] = f2bf(v2.z); lvb[11][m] = f2bf(v2.w);
    lvb[12][m] = f2bf(v3.x); lvb[13][m] = f2bf(v3.y);
    lvb[14][m] = f2bf(v3.z); lvb[15][m] = f2bf(v3.w);
  }
  #pragma unroll
  for (int o = 32; o; o >>= 1) sqm = fmaxf(sqm, __shfl_xor(sqm, o));
  int lane = tid & 63, wid = tid >> 6;
  if (lane == 0) lred[wid] = sqm;
  __syncthreads();
  float kmax = sqrtf(fmaxf(fmaxf(lred[0], lred[1]), fmaxf(lred[2], lred[3])));
  int wv = tid >> 6, l = tid & 63;
  int row = l & 15, kg = l >> 4;
  int n = blockIdx.x * 64 + wv * 16 + row;
  const float* qp = qkvT + ((size_t)b * HW + n) * 20;
  float q0 = qp[0], q1 = qp[1];
  float mxr = sqrtf(q0 * q0 + q1 * q1) * kmax;   // s <= mxr for all m in chunk
  f32x4 acc = {0.f, 0.f, 0.f, 0.f};
  float zp = 0.f;
  for (int t = 0; t < 25; t++){
    int m0 = t * 32 + kg * 8;
    float4 k0a = *(const float4*)&lk0[m0];
    float4 k0b = *(const float4*)&lk0[m0 + 4];
    float4 k1a = *(const float4*)&lk1[m0];
    float4 k1b = *(const float4*)&lk1[m0 + 4];
    float p0 = __expf(fmaf(q0, k0a.x, q1 * k1a.x) - mxr);
    float p1 = __expf(fmaf(q0, k0a.y, q1 * k1a.y) - mxr);
    float p2 = __expf(fmaf(q0, k0a.z, q1 * k1a.z) - mxr);
    float p3 = __expf(fmaf(q0, k0a.w, q1 * k1a.w) - mxr);
    float p4 = __expf(fmaf(q0, k0b.x, q1 * k1b.x) - mxr);
    float p5 = __expf(fmaf(q0, k0b.y, q1 * k1b.y) - mxr);
    float p6 = __expf(fmaf(q0, k0b.z, q1 * k1b.z) - mxr);
    float p7 = __expf(fmaf(q0, k0b.w, q1 * k1b.w) - mxr);
    zp += ((p0 + p1) + (p2 + p3)) + ((p4 + p5) + (p6 + p7));
    union { unsigned int u[4]; bf16x8 v; } pk;
    pk.u[0] = cvt_pk_bf16(p0, p1);
    pk.u[1] = cvt_pk_bf16(p2, p3);
    pk.u[2] = cvt_pk_bf16(p4, p5);
    pk.u[3] = cvt_pk_bf16(p6, p7);
    bf16x8 vb = *(const bf16x8*)&lvb[row][m0];
    acc = __builtin_amdgcn_mfma_f32_16x16x32_bf16(pk.v, vb, acc, 0, 0, 0);
  }
  zp += __shfl_xor(zp, 16);
  zp += __shfl_xor(zp, 32);
  float* pp = part + ((size_t)(b * 8 + mc) * 18) * HW;
  if (kg == 0){ pp[n] = mxr; pp[HW + n] = zp; }
  // C/D layout (verified round 8): col = lane&15 (ch), row = (lane>>4)*4 + reg (n)
  int c = l & 15;
  int nr = blockIdx.x * 64 + wv * 16 + (l >> 4) * 4;
  *(f32x4*)&pp[(size_t)(2 + c) * HW + nr] = acc;
}

// ---------------- K7b: merge 8 PAM partials (2 channels/block), residual ----------------
__global__ __launch_bounds__(256) void k_pam_b(
    const float* __restrict__ part, const float* __restrict__ feat,
    const float* __restrict__ gammap, float* __restrict__ pam_in){
  int tid = threadIdx.x; int cg = blockIdx.y, b = blockIdx.z;
  int n = blockIdx.x * 256 + tid;
  float gamma = gammap[0];
  float mxs[8]; float mx = -1e30f;
  #pragma unroll
  for (int mc = 0; mc < 8; mc++){
    mxs[mc] = part[((size_t)(b * 8 + mc) * 18) * HW + n];
    mx = fmaxf(mx, mxs[mc]);
  }
  float Z = 0.f, a0 = 0.f, a1 = 0.f;
  #pragma unroll
  for (int mc = 0; mc < 8; mc++){
    const float* pp = part + ((size_t)(b * 8 + mc) * 18) * HW + n;
    float r = __expf(mxs[mc] - mx);
    Z += pp[HW] * r;
    a0 += pp[(size_t)(2 + cg * 2) * HW] * r;
    a1 += pp[(size_t)(3 + cg * 2) * HW] * r;
  }
  float inv = gamma / Z;
  int c0 = cg * 2;
  pam_in[(b * 16 + c0) * HW + n]     = a0 * inv + feat[(b * 32 + c0) * HW + n];
  pam_in[(b * 16 + c0 + 1) * HW + n] = a1 * inv + feat[(b * 32 + c0 + 1) * HW + n];
}

// ---------------- K8: CAM gram matrix e[b,c,d] ----------------
__global__ __launch_bounds__(256) void k_cam_gram(
    const float* __restrict__ feat, float* __restrict__ e){
  int tid = threadIdx.x;
  int dd = blockIdx.x, c = blockIdx.y, b = blockIdx.z;
  const float* fc = feat + (b * 32 + 16 + c) * HW;
  const float* fd = feat + (b * 32 + 16 + dd) * HW;
  float S = 0.f;
  for (int i = tid; i < HW; i += 256) S += fc[i] * fd[i];
  S = wredsum(S);
  __shared__ float l[4];
  int lane = tid & 63, wid = tid >> 6;
  if (lane == 0) l[wid] = S;
  __syncthreads();
  if (tid == 0) e[(b * 16 + c) * 16 + dd] = l[0] + l[1] + l[2] + l[3];
}

// ---------------- K9: CAM softmax of (max - e) rows ----------------
__global__ void k_cam_soft(const float* __restrict__ e, float* __restrict__ att){
  int tid = threadIdx.x; if (tid >= 32) return;
  int b = tid >> 4, c = tid & 15;
  const float* row = e + (b * 16 + c) * 16;
  float r[16]; float mn = 1e30f;
  #pragma unroll
  for (int d = 0; d < 16; d++){ r[d] = row[d]; mn = fminf(mn, r[d]); }
  float p[16]; float s = 0.f;
  #pragma unroll
  for (int d = 0; d < 16; d++){ p[d] = __expf(mn - r[d]); s += p[d]; }
  float inv = 1.f / s;
  #pragma unroll
  for (int d = 0; d < 16; d++) att[(b * 16 + c) * 16 + d] = p[d] * inv;
}

// ---------------- K10: CAM apply + residual ----------------
__global__ __launch_bounds__(256) void k_cam_apply(
    const float* __restrict__ att, const float* __restrict__ feat,
    const float* __restrict__ gammap, float* __restrict__ cam_in){
  int tid = threadIdx.x; int c = blockIdx.y, b = blockIdx.z;
  int n = blockIdx.x * 256 + tid;
  const float* arow = att + (b * 16 + c) * 16;
  float s = 0.f;
  #pragma unroll
  for (int d = 0; d < 16; d++) s += arow[d] * feat[(b * 32 + 16 + d) * HW + n];
  cam_in[(b * 16 + c) * HW + n] = gammap[0] * s + feat[(b * 32 + 16 + c) * HW + n];
}

// ---------------- K11: 3x3 conv 16->32 (c5b|c5d), 4 outputs/thread + BN stats ----------------
__global__ __launch_bounds__(64) void k_conv5bd2(
    const float* __restrict__ pam_in, const float* __restrict__ cam_in,
    const float* __restrict__ wt2,
    float* __restrict__ bdpre, float* __restrict__ bnpart){
  int tid = threadIdx.x;
  int pix = blockIdx.x * 64 + tid;
  int ocg = blockIdx.y, b = blockIdx.z;
  int half = ocg >> 2, oq = (ocg & 3) * 4;
  int h = pix / 80, w = pix % 80;
  int off[9]; float msk[9];
  #pragma unroll
  for (int dy = 0; dy < 3; dy++){
    #pragma unroll
    for (int dx = 0; dx < 3; dx++){
      int hh = h + dy - 1, ww = w + dx - 1;
      bool ok = ((unsigned)hh < 80u) && ((unsigned)ww < 80u);
      off[dy * 3 + dx] = ok ? hh * 80 + ww : 0;
      msk[dy * 3 + dx] = ok ? 1.f : 0.f;
    }
  }
  const float* in = (half ? cam_in : pam_in) + (size_t)b * 16 * HW;
  int obase = half * 16 + oq;
  float acc[4];
  #pragma unroll
  for (int o = 0; o < 4; o++) acc[o] = 0.f;
  float xa[9], xb[9];
  #pragma unroll
  for (int k = 0; k < 9; k++) xa[k] = in[off[k]] * msk[k];
  #pragma unroll
  for (int ic = 0; ic < 16; ic += 2){
    const float* xin1 = in + (size_t)(ic + 1) * HW;
    #pragma unroll
    for (int k = 0; k < 9; k++) xb[k] = xin1[off[k]] * msk[k];
    const float* wr0 = wt2 + ic * 288 + obase * 9;
    #pragma unroll
    for (int o = 0; o < 4; o++){
      float a = acc[o];
      #pragma unroll
      for (int k = 0; k < 9; k++) a += wr0[o * 9 + k] * xa[k];
      acc[o] = a;
    }
    if (ic + 2 < 16){
      const float* xin2 = in + (size_t)(ic + 2) * HW;
      #pragma unroll
      for (int k = 0; k < 9; k++) xa[k] = xin2[off[k]] * msk[k];
    }
    const float* wr1 = wt2 + (ic + 1) * 288 + obase * 9;
    #pragma unroll
    for (int o = 0; o < 4; o++){
      float a = acc[o];
      #pragma unroll
      for (int k = 0; k < 9; k++) a += wr1[o * 9 + k] * xb[k];
      acc[o] = a;
    }
  }
  #pragma unroll
  for (int o = 0; o < 4; o++){
    float v = acc[o];
    bdpre[(b * 32 + obase + o) * HW + pix] = v;
    float S = wredsum(v), Q = wredsum(v * v);
    if (tid == 0){
      bnpart[(obase + o) * 400 + (b * 100 + blockIdx.x) * 2]     = S;
      bnpart[(obase + o) * 400 + (b * 100 + blockIdx.x) * 2 + 1] = Q;
    }
  }
}

// ---------------- K13: fused BN+relu+sum + 1x1 conv 16->256 + relu -> out ----------------
__global__ __launch_bounds__(256) void k_c6(
    const float* __restrict__ bdpre, const float* __restrict__ bnsc,
    const float* __restrict__ w6, const float* __restrict__ b6,
    float* __restrict__ out){
  int tid = threadIdx.x; int og = blockIdx.y * 32, b = blockIdx.z;
  int n = blockIdx.x * 256 + tid;
  float x[16];
  #pragma unroll
  for (int c = 0; c < 16; c++){
    float v1 = bdpre[(b * 32 + c) * HW + n] * bnsc[c * 2] + bnsc[c * 2 + 1];
    float v2 = bdpre[(b * 32 + 16 + c) * HW + n] * bnsc[(16 + c) * 2] + bnsc[(16 + c) * 2 + 1];
    x[c] = fmaxf(v1, 0.f) + fmaxf(v2, 0.f);
  }
  #pragma unroll
  for (int o = 0; o < 32; o++){
    float a = b6[og + o];
    #pragma unroll
    for (int c = 0; c < 16; c++) a += w6[(og + o) * 16 + c] * x[c];
    out[(b * 256 + og + o) * HW + n] = fmaxf(a, 0.f);
  }
}

extern "C" void kernel_launch(void* const* d_in, const int* in_sizes, int n_in,
                              void* d_out, int out_size, void* d_ws, size_t ws_size,
                              hipStream_t stream){
  const float* z      = (const float*)d_in[0];
  const float* w_at0  = (const float*)d_in[1];
  const float* b_at0  = (const float*)d_in[2];
  const float* w_at1  = (const float*)d_in[3];
  const float* b_at1  = (const float*)d_in[4];
  const float* w_at2  = (const float*)d_in[5];
  const float* b_at2  = (const float*)d_in[6];
  const float* w_at3  = (const float*)d_in[7];
  const float* b_at3  = (const float*)d_in[8];
  const float* gn_w   = (const float*)d_in[9];
  const float* gn_b   = (const float*)d_in[10];
  const float* conv_w = (const float*)d_in[11];
  const float* conv_b = (const float*)d_in[12];
  const float* c5a_w  = (const float*)d_in[13];
  const float* bn5a_w = (const float*)d_in[14];
  const float* bn5a_b = (const float*)d_in[15];
  const float* c5c_w  = (const float*)d_in[16];
  const float* bn5c_w = (const float*)d_in[17];
  const float* bn5c_b = (const float*)d_in[18];
  const float* pq_w   = (const float*)d_in[19];
  const float* pq_b   = (const float*)d_in[20];
  const float* pk_w   = (const float*)d_in[21];
  const float* pk_b   = (const float*)d_in[22];
  const float* pv_w   = (const float*)d_in[23];
  const float* pv_b   = (const float*)d_in[24];
  const float* pa_g   = (const float*)d_in[25];
  const float* ca_g   = (const float*)d_in[26];
  const float* c5b_w  = (const float*)d_in[27];
  const float* bn5b_w = (const float*)d_in[28];
  const float* bn5b_b = (const float*)d_in[29];
  const float* c5d_w  = (const float*)d_in[30];
  const float* bn5d_w = (const float*)d_in[31];
  const float* bn5d_b = (const float*)d_in[32];
  const float* c6_w   = (const float*)d_in[33];
  const float* c6_b   = (const float*)d_in[34];

  float* ws = (float*)d_ws;
  float* ZC      = ws;                    // 3,276,800 fp32 (k_dw out, conv1 in)
  float* ZC2     = ZC + 3276800;          // 3,276,800 region
  float* FPRE    = ZC2 + 3276800;         // 409,600
  float* FEAT    = FPRE + 409600;         // 409,600
  float* QKVT    = FEAT + 409600;         // 256,000
  float* PAM_IN  = QKVT + 256000;         // 204,800
  float* CAM_IN  = PAM_IN + 204800;       // 204,800
  float* BDPRE   = CAM_IN + 204800;       // 409,600
  float* ST      = BDPRE + 409600;
  float* GN_SC    = ST;                   // 1024
  float* BNA_SC   = ST + 1024;            // 64
  float* BNB_SC   = ST + 1088;            // 64
  float* CAM_ATT  = ST + 1152;            // 512
  float* CAM_E    = ST + 1664;            // 512
  float* GN_PART  = ST + 2176;            // 25,600
  float* BNA_PART = ST + 27776;           // 3,200
  float* BNB_PART = ST + 30976;           // 12,800
  float* WT2      = ST + 43776;           // 4,608
  float* CWT      = ST + 48384;           // 65,536 ([c][o] transpose)
  unsigned short* WBBF = (unsigned short*)(ST + 113920);  // 73,728 bf16
  // Aliases:
  //  - ZC2BFT (bf16 zc2^T, 3,276,800 ushort) at [4,915,200 .. 6,553,600) f32-units:
  //    written by k_conv1, read by k_conv5ac_mfma, dead after.
  //  - PARTIAL (conv5ac halo partials, 9*2*32*HW = 3,686,400 f32) = [0..3,686,400):
  //    disjoint from ZC2BFT.
  //  - PART (PAM partials, 8*18*2*HW = 1,843,200 f32) = [0..1,843,200): written
  //    after PARTIAL is dead; disjoint from ZC2BFT (which is dead by then anyway).
  unsigned short* ZC2BFT = (unsigned short*)(ws + 4915200);
  float* PARTIAL = ZC;
  float* PART    = ZC;

  k_wprep<<<288, 256, 0, stream>>>(c5a_w, c5c_w, c5b_w, c5d_w, conv_w, CWT, WT2, WBBF);
  k_dw<<<dim3(25, 256, 2), 256, 0, stream>>>(z, w_at0, b_at0, w_at1, b_at1,
                                             w_at2, b_at2, w_at3, b_at3, ZC, GN_PART);
  k_gnfin<<<8, 256, 0, stream>>>(GN_PART, gn_w, gn_b, GN_SC);
  k_conv1<<<dim3(50, 4, 2), 512, 0, stream>>>(ZC, GN_SC, CWT, conv_b, ZC2BFT);
  k_conv5ac_mfma<<<dim3(100, 9, 2), 256, 0, stream>>>(ZC2BFT, WBBF, PARTIAL);
  k_conv5ac_red<<<dim3(25, 32, 2), 256, 0, stream>>>(PARTIAL, FPRE, BNA_PART);
  k_bnfin<<<1, 256, 0, stream>>>(BNA_PART, 50, bn5a_w, bn5a_b, bn5c_w, bn5c_b, BNA_SC);
  k_featqkv<<<dim3(25, 2), 256, 0, stream>>>(FPRE, BNA_SC, pq_w, pq_b, pk_w, pk_b,
                                             pv_w, pv_b, FEAT, QKVT);
  k_pam_a<<<dim3(100, 8, 2), 256, 0, stream>>>(QKVT, PART);
  k_pam_b<<<dim3(25, 8, 2), 256, 0, stream>>>(PART, FEAT, pa_g, PAM_IN);
  k_cam_gram<<<dim3(16, 16, 2), 256, 0, stream>>>(FEAT, CAM_E);
  k_cam_soft<<<1, 64, 0, stream>>>(CAM_E, CAM_ATT);
  k_cam_apply<<<dim3(25, 16, 2), 256, 0, stream>>>(CAM_ATT, FEAT, ca_g, CAM_IN);
  k_conv5bd2<<<dim3(100, 8, 2), 64, 0, stream>>>(PAM_IN, CAM_IN, WT2, BDPRE, BNB_PART);
  k_bnfin<<<1, 256, 0, stream>>>(BNB_PART, 200, bn5b_w, bn5b_b, bn5d_w, bn5d_b, BNB_SC);
  k_c6<<<dim3(25, 8, 2), 256, 0, stream>>>(BDPRE, BNB_SC, c6_w, c6_b, (float*)d_out);
}

// Round 11
// 177.176 us; speedup vs baseline: 3.4483x; 1.1374x over previous
//
#include <hip/hip_runtime.h>
#include <math.h>

#define HW 6400

typedef __attribute__((ext_vector_type(8))) short bf16x8;
typedef __attribute__((ext_vector_type(4))) float f32x4;

__device__ __forceinline__ float wredsum(float v){
  #pragma unroll
  for (int o = 32; o; o >>= 1) v += __shfl_xor(v, o);
  return v;
}

__device__ __forceinline__ unsigned short f2bf(float f){
  unsigned int u = __float_as_uint(f);
  u += 0x7FFF + ((u >> 16) & 1);   // RNE
  return (unsigned short)(u >> 16);
}

__device__ __forceinline__ unsigned int cvt_pk_bf16(float lo, float hi){
  unsigned int r;
  asm("v_cvt_pk_bf16_f32 %0, %1, %2" : "=v"(r) : "v"(lo), "v"(hi));
  return r;
}

__device__ __forceinline__ float gelu(float v){
  return 0.5f * v * (1.f + erff(v * 0.70710678118f));
}

// ---------------- K0: weight re-layout prep (conv5 weights) ----------------
// WT2[ic][o*9+k] (o<16 -> c5b, o>=16 -> c5d)                       (4,608 f32)
// WBBF[ss][f][l][j] bf16: k=ss*32+(l>>4)*8+j, off=k>>8, ic=k&255,
//                         oc=f*16+(l&15); o<16->c5a else c5c       (73,728 bf16)
__global__ __launch_bounds__(256) void k_wprep(
    const float* __restrict__ wa, const float* __restrict__ wc,
    const float* __restrict__ wb, const float* __restrict__ wd,
    float* __restrict__ wt2, unsigned short* __restrict__ wbbf){
  int i = blockIdx.x * 256 + threadIdx.x;
  if (i < 16 * 288){
    int ic = i / 288, r = i - ic * 288;
    int o = r / 9, k = r - o * 9;
    float v = (o < 16) ? wb[(o * 16 + ic) * 9 + k] : wd[((o - 16) * 16 + ic) * 9 + k];
    wt2[i] = v;
  }
  if (i < 73728){
    int j = i & 7, l = (i >> 3) & 63, f = (i >> 9) & 1, ss = i >> 10;
    int k = ss * 32 + (l >> 4) * 8 + j;
    int off = k >> 8, ic = k & 255;
    int oc = f * 16 + (l & 15);
    float v = (oc < 16) ? wa[(oc * 256 + ic) * 9 + off]
                        : wc[((oc - 16) * 256 + ic) * 9 + off];
    wbbf[i] = f2bf(v);
  }
}

// ---------------- K0b: conv1 weights with GN scale folded, frag-ready bf16 ----------
// CWBF[b][ss][f][l][j]: ic=ss*32+(l>>4)*8+j, oc=f*16+(l&15), val=cw[oc][ic]*sc[b][ic]
__global__ __launch_bounds__(256) void k_gnw(
    const float* __restrict__ cw, const float* __restrict__ gn_sc,
    unsigned short* __restrict__ cwbf){
  int i = blockIdx.x * 256 + threadIdx.x;   // 512 blocks -> 131072
  int b = i >> 16, r = i & 65535;
  int j = r & 7, l = (r >> 3) & 63, f = (r >> 9) & 15, ss = r >> 13;
  int ic = ss * 32 + (l >> 4) * 8 + j;
  int oc = f * 16 + (l & 15);
  cwbf[i] = f2bf(cw[oc * 256 + ic] * gn_sc[(b * 256 + ic) * 2]);
}

// ---------------- K0c: conv1 bias with GN shift folded ----------------
// cbp[b][oc] = cb[oc] + sum_c cw[oc][c]*sh[b][c];  grid (16,2), block 256
__global__ void k_cbp(
    const float* __restrict__ cw, const float* __restrict__ gn_sc,
    const float* __restrict__ cb, float* __restrict__ cbp){
  int tid = threadIdx.x;
  int b = blockIdx.y;
  int oc = blockIdx.x * 16 + (tid >> 4);
  int cp = tid & 15;
  float s = 0.f;
  #pragma unroll
  for (int k = 0; k < 16; k++){
    int c = cp * 16 + k;
    s += cw[oc * 256 + c] * gn_sc[(b * 256 + c) * 2 + 1];
  }
  s += __shfl_xor(s, 1); s += __shfl_xor(s, 2);
  s += __shfl_xor(s, 4); s += __shfl_xor(s, 8);
  if (cp == 0) cbp[b * 256 + oc] = cb[oc] + s;
}

// ---------------- K1: depthwise dilated convs + GN partial stats ----------------
__global__ __launch_bounds__(256) void k_dw(
    const float* __restrict__ z,
    const float* __restrict__ w0, const float* __restrict__ b0,
    const float* __restrict__ w1, const float* __restrict__ b1,
    const float* __restrict__ w2, const float* __restrict__ b2,
    const float* __restrict__ w3, const float* __restrict__ b3,
    float* __restrict__ zc, float* __restrict__ gnpart){
  int tid = threadIdx.x;
  int c = blockIdx.y, b = blockIdx.z;
  int pix = blockIdx.x * 256 + tid;
  int h = pix / 80, w = pix % 80;
  int part = c >> 6, cl = c & 63;
  const float* wp; const float* bp; int d;
  if (part == 0)      { wp = w0; bp = b0; d = 7; }
  else if (part == 1) { wp = w1; bp = b1; d = 5; }
  else if (part == 2) { wp = w2; bp = b2; d = 2; }
  else                { wp = w3; bp = b3; d = 1; }
  wp += cl * 9;
  const float* zin = z + (b * 256 + c) * HW;
  float acc = bp[cl];
  #pragma unroll
  for (int kh = 0; kh < 3; kh++){
    int hh = h + (kh - 1) * d;
    if ((unsigned)hh < 80u){
      #pragma unroll
      for (int kw = 0; kw < 3; kw++){
        int ww = w + (kw - 1) * d;
        if ((unsigned)ww < 80u) acc += wp[kh * 3 + kw] * zin[hh * 80 + ww];
      }
    }
  }
  zc[(b * 256 + c) * HW + pix] = acc;
  float S = wredsum(acc), Q = wredsum(acc * acc);
  __shared__ float l[8];
  int lane = tid & 63, wid = tid >> 6;
  if (lane == 0){ l[wid] = S; l[4 + wid] = Q; }
  __syncthreads();
  if (tid == 0){
    float SS = l[0] + l[1] + l[2] + l[3];
    float QQ = l[4] + l[5] + l[6] + l[7];
    int blkid = (b * 256 + c) * 25 + blockIdx.x;
    gnpart[blkid * 2] = SS; gnpart[blkid * 2 + 1] = QQ;
  }
}

// ---------------- K1b: transpose zc fp32 [c][pix] -> zbf bf16 [pix][c] ----------------
// grid (50, 4, 2), block 256: 128 pix x 64 ch per block
__global__ __launch_bounds__(256) void k_zbf(
    const float* __restrict__ zc, unsigned short* __restrict__ zbf){
  __shared__ __align__(16) unsigned short lt[128 * 72];
  int tid = threadIdx.x;
  int pixb = blockIdx.x * 128, cg = blockIdx.y, b = blockIdx.z;
  #pragma unroll
  for (int p = 0; p < 8; p++){
    int cl = p * 8 + (tid >> 5);
    int px = (tid & 31) * 4;
    float4 v = *(const float4*)(zc + (size_t)(b * 256 + cg * 64 + cl) * HW + pixb + px);
    lt[(px + 0) * 72 + cl] = f2bf(v.x);
    lt[(px + 1) * 72 + cl] = f2bf(v.y);
    lt[(px + 2) * 72 + cl] = f2bf(v.z);
    lt[(px + 3) * 72 + cl] = f2bf(v.w);
  }
  __syncthreads();
  int pix = tid >> 1, half = tid & 1;
  unsigned short* dst = zbf + ((size_t)b * HW + pixb + pix) * 256 + cg * 64 + half * 32;
  const unsigned short* src = lt + pix * 72 + half * 32;
  *(uint4*)(dst)      = *(const uint4*)(src);
  *(uint4*)(dst + 8)  = *(const uint4*)(src + 8);
  *(uint4*)(dst + 16) = *(const uint4*)(src + 16);
  *(uint4*)(dst + 24) = *(const uint4*)(src + 24);
}

// ---------------- K3: 1x1 conv 256->256 (GN folded) via bf16 MFMA + GELU ----------------
// grid (100, 4, 2), block 256 = 4 waves. Block: 64 pix x 64 oc, K=256.
__global__ __launch_bounds__(256) void k_conv1_mfma(
    const unsigned short* __restrict__ zbf,
    const unsigned short* __restrict__ cwbf,
    const float* __restrict__ cbp,
    unsigned short* __restrict__ zbfT){
  __shared__ __align__(16) unsigned char lmem[64 * 512];   // 32KB
  unsigned short* lda = (unsigned short*)lmem;
  unsigned short* lout = (unsigned short*)lmem;
  int tid = threadIdx.x;
  int p0 = blockIdx.x * 64, ocg = blockIdx.y, b = blockIdx.z;
  #pragma unroll
  for (int k = 0; k < 8; k++){
    int m = tid + k * 256;
    int i = m >> 5, c = m & 31;
    bf16x8 val = *(const bf16x8*)(zbf + ((size_t)b * HW + p0 + i) * 256 + c * 8);
    *(bf16x8*)(lda + i * 256 + (c ^ (i & 7)) * 8) = val;
  }
  __syncthreads();
  int wv = tid >> 6, l = tid & 63;
  int row = l & 15, kg = l >> 4;
  int i = wv * 16 + row;
  f32x4 acc0 = {0.f,0.f,0.f,0.f}, acc1 = {0.f,0.f,0.f,0.f};
  f32x4 acc2 = {0.f,0.f,0.f,0.f}, acc3 = {0.f,0.f,0.f,0.f};
  const unsigned short* wp = cwbf + (size_t)b * 65536 + (ocg * 4) * 512 + l * 8;
  #pragma unroll
  for (int s = 0; s < 8; s++){
    int c = s * 4 + kg;
    bf16x8 a = *(const bf16x8*)(lda + i * 256 + (c ^ (i & 7)) * 8);
    const unsigned short* wps = wp + s * 8192;
    bf16x8 b0 = *(const bf16x8*)(wps);
    bf16x8 b1 = *(const bf16x8*)(wps + 512);
    bf16x8 b2 = *(const bf16x8*)(wps + 1024);
    bf16x8 b3 = *(const bf16x8*)(wps + 1536);
    acc0 = __builtin_amdgcn_mfma_f32_16x16x32_bf16(a, b0, acc0, 0, 0, 0);
    acc1 = __builtin_amdgcn_mfma_f32_16x16x32_bf16(a, b1, acc1, 0, 0, 0);
    acc2 = __builtin_amdgcn_mfma_f32_16x16x32_bf16(a, b2, acc2, 0, 0, 0);
    acc3 = __builtin_amdgcn_mfma_f32_16x16x32_bf16(a, b3, acc3, 0, 0, 0);
  }
  __syncthreads();   // lda reads done -> reuse lmem as lout [64 pix][72] ushort
  const float* cbb = cbp + b * 256 + ocg * 64;
  int oc_l = l & 15;
  int pl = wv * 16 + kg * 4;
  float bs0 = cbb[oc_l], bs1 = cbb[16 + oc_l], bs2 = cbb[32 + oc_l], bs3 = cbb[48 + oc_l];
  #pragma unroll
  for (int r = 0; r < 4; r++){
    lout[(pl + r) * 72 + oc_l]      = f2bf(gelu(acc0[r] + bs0));
    lout[(pl + r) * 72 + 16 + oc_l] = f2bf(gelu(acc1[r] + bs1));
    lout[(pl + r) * 72 + 32 + oc_l] = f2bf(gelu(acc2[r] + bs2));
    lout[(pl + r) * 72 + 48 + oc_l] = f2bf(gelu(acc3[r] + bs3));
  }
  __syncthreads();
  int pix = tid >> 2, q = tid & 3;
  unsigned short* dst = zbfT + ((size_t)b * HW + p0 + pix) * 256 + ocg * 64 + q * 16;
  const unsigned short* src = lout + pix * 72 + q * 16;
  *(uint4*)dst       = *(const uint4*)src;
  *(uint4*)(dst + 8) = *(const uint4*)(src + 8);
}

// ---------------- K4a: 3x3 conv 256->32 (c5a|c5c fused) via bf16 MFMA, LDS-staged ----
__global__ __launch_bounds__(256) void k_conv5ac_mfma(
    const unsigned short* __restrict__ zbfT,
    const unsigned short* __restrict__ wbbf,
    float* __restrict__ partial){
  __shared__ __align__(16) unsigned char lmem[64 * 512];   // 32KB
  unsigned short* lda = (unsigned short*)lmem;
  float* lout = (float*)lmem;
  int tid = threadIdx.x;
  int off = blockIdx.y, b = blockIdx.z;
  int dy = off / 3, dx = off % 3;
  int doff = (dy - 1) * 80 + (dx - 1);
  int p0 = blockIdx.x * 64;
  #pragma unroll
  for (int k = 0; k < 8; k++){
    int m = tid + k * 256;
    int i = m >> 5, c = m & 31;
    int op = p0 + i;
    int h = op / 80, w = op % 80;
    bool v = ((unsigned)(h + dy - 1) < 80u) && ((unsigned)(w + dx - 1) < 80u);
    int sp = v ? (op + doff) : op;
    bf16x8 val = *(const bf16x8*)(zbfT + ((size_t)b * HW + sp) * 256 + c * 8);
    if (!v) val = (bf16x8){0, 0, 0, 0, 0, 0, 0, 0};
    *(bf16x8*)(lda + i * 256 + (c ^ (i & 7)) * 8) = val;
  }
  __syncthreads();
  int wv = tid >> 6, l = tid & 63;
  int row = l & 15, kg = l >> 4;
  int i = wv * 16 + row;
  f32x4 acc0 = {0.f, 0.f, 0.f, 0.f};
  f32x4 acc1 = {0.f, 0.f, 0.f, 0.f};
  const unsigned short* wp = wbbf + (size_t)off * 8 * 1024 + l * 8;
  #pragma unroll
  for (int s = 0; s < 8; s++){
    int c = s * 4 + kg;
    bf16x8 a = *(const bf16x8*)(lda + i * 256 + (c ^ (i & 7)) * 8);
    bf16x8 b0 = *(const bf16x8*)(wp + s * 1024);
    bf16x8 b1 = *(const bf16x8*)(wp + s * 1024 + 512);
    acc0 = __builtin_amdgcn_mfma_f32_16x16x32_bf16(a, b0, acc0, 0, 0, 0);
    acc1 = __builtin_amdgcn_mfma_f32_16x16x32_bf16(a, b1, acc1, 0, 0, 0);
  }
  __syncthreads();
  int oc0 = l & 15;
  int plocal = wv * 16 + kg * 4;
  #pragma unroll
  for (int r = 0; r < 4; r++){
    lout[oc0 * 65 + plocal + r] = acc0[r];
    lout[(16 + oc0) * 65 + plocal + r] = acc1[r];
  }
  __syncthreads();
  #pragma unroll
  for (int k = 0; k < 8; k++){
    int m = tid + k * 256;
    int oc = m >> 6, pl = m & 63;
    partial[((size_t)(off * 2 + b) * 32 + oc) * HW + p0 + pl] = lout[oc * 65 + pl];
  }
}

// ---------------- K4b: reduce 9 halo partials -> fpre + BN partial stats ----------------
__global__ __launch_bounds__(256) void k_conv5ac_red(
    const float* __restrict__ partial, float* __restrict__ fpre,
    float* __restrict__ bnpart){
  int tid = threadIdx.x; int oc = blockIdx.y, b = blockIdx.z;
  int pix = blockIdx.x * 256 + tid;
  float s = 0.f;
  #pragma unroll
  for (int off = 0; off < 9; off++)
    s += partial[((size_t)(off * 2 + b) * 32 + oc) * HW + pix];
  fpre[(b * 32 + oc) * HW + pix] = s;
  float S = wredsum(s), Q = wredsum(s * s);
  __shared__ float l[8];
  int lane = tid & 63, wid = tid >> 6;
  if (lane == 0){ l[wid] = S; l[4 + wid] = Q; }
  __syncthreads();
  if (tid == 0){
    bnpart[oc * 100 + (b * 25 + blockIdx.x) * 2]     = l[0] + l[1] + l[2] + l[3];
    bnpart[oc * 100 + (b * 25 + blockIdx.x) * 2 + 1] = l[4] + l[5] + l[6] + l[7];
  }
}

// ---------------- K5/K12: BN finalize (32 channels), parallel reduce ----------------
__global__ __launch_bounds__(256) void k_bnfin(
    const float* __restrict__ part, int nent,
    const float* __restrict__ w1, const float* __restrict__ b1,
    const float* __restrict__ w2, const float* __restrict__ b2,
    float* __restrict__ sc_out){
  __shared__ float lS[8][32], lQ[8][32];
  int tid = threadIdx.x;
  int oc = tid & 31, sl = tid >> 5;
  float S = 0.f, Q = 0.f;
  for (int i = sl; i < nent; i += 8){
    S += part[oc * 2 * nent + i * 2];
    Q += part[oc * 2 * nent + i * 2 + 1];
  }
  lS[sl][oc] = S; lQ[sl][oc] = Q;
  __syncthreads();
  if (tid < 32){
    float SS = 0.f, QQ = 0.f;
    #pragma unroll
    for (int s = 0; s < 8; s++){ SS += lS[s][oc]; QQ += lQ[s][oc]; }
    float M = 2.f * HW;
    float mean = SS / M, var = QQ / M - mean * mean;
    float rstd = rsqrtf(var + 1e-3f);
    float w  = (oc < 16) ? w1[oc] : w2[oc - 16];
    float bb = (oc < 16) ? b1[oc] : b2[oc - 16];
    float sc = w * rstd, sh = bb - mean * sc;
    sc_out[oc * 2] = sc; sc_out[oc * 2 + 1] = sh;
  }
}

// ---------------- K2: GN stats finalize -> per (b,c) scale/shift ----------------
__global__ __launch_bounds__(256) void k_gnfin(
    const float* __restrict__ gnpart, const float* __restrict__ gn_w,
    const float* __restrict__ gn_b, float* __restrict__ gn_sc){
  int tid = threadIdx.x; int bg = blockIdx.x; // b*4+g
  float S = 0.f, Q = 0.f;
  for (int i = tid; i < 1600; i += 256){
    S += gnpart[(bg * 1600 + i) * 2];
    Q += gnpart[(bg * 1600 + i) * 2 + 1];
  }
  S = wredsum(S); Q = wredsum(Q);
  __shared__ float l[8];
  int lane = tid & 63, wid = tid >> 6;
  if (lane == 0){ l[wid] = S; l[4 + wid] = Q; }
  __syncthreads();
  float SS = l[0] + l[1] + l[2] + l[3];
  float QQ = l[4] + l[5] + l[6] + l[7];
  float M = 64.f * HW;
  float mean = SS / M;
  float var = QQ / M - mean * mean;
  float rstd = rsqrtf(var + 1e-5f);
  if (tid < 64){
    int b = bg >> 2, g = bg & 3;
    int c = g * 64 + tid;
    float sc = gn_w[c] * rstd;
    float sh = gn_b[c] - mean * sc;
    gn_sc[(b * 256 + c) * 2] = sc;
    gn_sc[(b * 256 + c) * 2 + 1] = sh;
  }
}

// ---------------- K6: BN+relu apply -> feat1/feat2, and q,k,v 1x1 convs ----------------
__global__ __launch_bounds__(256) void k_featqkv(
    const float* __restrict__ fpre, const float* __restrict__ bnsc,
    const float* __restrict__ pqw, const float* __restrict__ pqb,
    const float* __restrict__ pkw, const float* __restrict__ pkb,
    const float* __restrict__ pvw, const float* __restrict__ pvb,
    float* __restrict__ feat, float* __restrict__ qkvT){
  int tid = threadIdx.x; int b = blockIdx.y;
  int n = blockIdx.x * 256 + tid;
  float f1[16], f2[16];
  #pragma unroll
  for (int c = 0; c < 16; c++){
    float v1 = fpre[(b * 32 + c) * HW + n] * bnsc[c * 2] + bnsc[c * 2 + 1];
    f1[c] = fmaxf(v1, 0.f);
    float v2 = fpre[(b * 32 + 16 + c) * HW + n] * bnsc[(16 + c) * 2] + bnsc[(16 + c) * 2 + 1];
    f2[c] = fmaxf(v2, 0.f);
    feat[(b * 32 + c) * HW + n] = f1[c];
    feat[(b * 32 + 16 + c) * HW + n] = f2[c];
  }
  float* o = qkvT + ((size_t)b * HW + n) * 20;
  #pragma unroll
  for (int j = 0; j < 2; j++){
    float q = pqb[j], k = pkb[j];
    #pragma unroll
    for (int c = 0; c < 16; c++){ q += pqw[j * 16 + c] * f1[c]; k += pkw[j * 16 + c] * f1[c]; }
    o[j] = q; o[2 + j] = k;
  }
  #pragma unroll
  for (int j = 0; j < 16; j++){
    float v = pvb[j];
    #pragma unroll
    for (int c = 0; c < 16; c++) v += pvw[j * 16 + c] * f1[c];
    o[4 + j] = v;
  }
}

// ---------------- K7a: PAM flash partials via MFMA PV, 8 m-chunks of 800 ----------------
__global__ __launch_bounds__(256) void k_pam_a(
    const float* __restrict__ qkvT, float* __restrict__ part){
  __shared__ __align__(16) float lk0[800];
  __shared__ __align__(16) float lk1[800];
  __shared__ __align__(16) unsigned short lvb[16][808];
  __shared__ float lred[4];
  int tid = threadIdx.x;
  int mc = blockIdx.y, b = blockIdx.z;
  float sqm = 0.f;
  for (int m = tid; m < 800; m += 256){
    const float* kv = qkvT + ((size_t)b * HW + mc * 800 + m) * 20;
    float4 a0 = *(const float4*)kv;
    lk0[m] = a0.z; lk1[m] = a0.w;
    sqm = fmaxf(sqm, a0.z * a0.z + a0.w * a0.w);
    float4 v0 = *(const float4*)(kv + 4);
    float4 v1 = *(const float4*)(kv + 8);
    float4 v2 = *(const float4*)(kv + 12);
    float4 v3 = *(const float4*)(kv + 16);
    lvb[0][m]  = f2bf(v0.x); lvb[1][m]  = f2bf(v0.y);
    lvb[2][m]  = f2bf(v0.z); lvb[3][m]  = f2bf(v0.w);
    lvb[4][m]  = f2bf(v1.x); lvb[5][m]  = f2bf(v1.y);
    lvb[6][m]  = f2bf(v1.z); lvb[7][m]  = f2bf(v1.w);
    lvb[8][m]  = f2bf(v2.x); lvb[9][m]  = f2bf(v2.y);
    lvb[10][m] = f2bf(v2.z); lvb[11][m] = f2bf(v2.w);
    lvb[12][m] = f2bf(v3.x); lvb[13][m] = f2bf(v3.y);
    lvb[14][m] = f2bf(v3.z); lvb[15][m] = f2bf(v3.w);
  }
  #pragma unroll
  for (int o = 32; o; o >>= 1) sqm = fmaxf(sqm, __shfl_xor(sqm, o));
  int lane = tid & 63, wid = tid >> 6;
  if (lane == 0) lred[wid] = sqm;
  __syncthreads();
  float kmax = sqrtf(fmaxf(fmaxf(lred[0], lred[1]), fmaxf(lred[2], lred[3])));
  int wv = tid >> 6, l = tid & 63;
  int row = l & 15, kg = l >> 4;
  int n = blockIdx.x * 64 + wv * 16 + row;
  const float* qp = qkvT + ((size_t)b * HW + n) * 20;
  float q0 = qp[0], q1 = qp[1];
  float mxr = sqrtf(q0 * q0 + q1 * q1) * kmax;
  f32x4 acc = {0.f, 0.f, 0.f, 0.f};
  float zp = 0.f;
  for (int t = 0; t < 25; t++){
    int m0 = t * 32 + kg * 8;
    float4 k0a = *(const float4*)&lk0[m0];
    float4 k0b = *(const float4*)&lk0[m0 + 4];
    float4 k1a = *(const float4*)&lk1[m0];
    float4 k1b = *(const float4*)&lk1[m0 + 4];
    float p0 = __expf(fmaf(q0, k0a.x, q1 * k1a.x) - mxr);
    float p1 = __expf(fmaf(q0, k0a.y, q1 * k1a.y) - mxr);
    float p2 = __expf(fmaf(q0, k0a.z, q1 * k1a.z) - mxr);
    float p3 = __expf(fmaf(q0, k0a.w, q1 * k1a.w) - mxr);
    float p4 = __expf(fmaf(q0, k0b.x, q1 * k1b.x) - mxr);
    float p5 = __expf(fmaf(q0, k0b.y, q1 * k1b.y) - mxr);
    float p6 = __expf(fmaf(q0, k0b.z, q1 * k1b.z) - mxr);
    float p7 = __expf(fmaf(q0, k0b.w, q1 * k1b.w) - mxr);
    zp += ((p0 + p1) + (p2 + p3)) + ((p4 + p5) + (p6 + p7));
    union { unsigned int u[4]; bf16x8 v; } pk;
    pk.u[0] = cvt_pk_bf16(p0, p1);
    pk.u[1] = cvt_pk_bf16(p2, p3);
    pk.u[2] = cvt_pk_bf16(p4, p5);
    pk.u[3] = cvt_pk_bf16(p6, p7);
    bf16x8 vb = *(const bf16x8*)&lvb[row][m0];
    acc = __builtin_amdgcn_mfma_f32_16x16x32_bf16(pk.v, vb, acc, 0, 0, 0);
  }
  zp += __shfl_xor(zp, 16);
  zp += __shfl_xor(zp, 32);
  float* pp = part + ((size_t)(b * 8 + mc) * 18) * HW;
  if (kg == 0){ pp[n] = mxr; pp[HW + n] = zp; }
  int c = l & 15;
  int nr = blockIdx.x * 64 + wv * 16 + (l >> 4) * 4;
  *(f32x4*)&pp[(size_t)(2 + c) * HW + nr] = acc;
}

// ---------------- K7b: merge 8 PAM partials (2 channels/block), residual ----------------
__global__ __launch_bounds__(256) void k_pam_b(
    const float* __restrict__ part, const float* __restrict__ feat,
    const float* __restrict__ gammap, float* __restrict__ pam_in){
  int tid = threadIdx.x; int cg = blockIdx.y, b = blockIdx.z;
  int n = blockIdx.x * 256 + tid;
  float gamma = gammap[0];
  float mxs[8]; float mx = -1e30f;
  #pragma unroll
  for (int mc = 0; mc < 8; mc++){
    mxs[mc] = part[((size_t)(b * 8 + mc) * 18) * HW + n];
    mx = fmaxf(mx, mxs[mc]);
  }
  float Z = 0.f, a0 = 0.f, a1 = 0.f;
  #pragma unroll
  for (int mc = 0; mc < 8; mc++){
    const float* pp = part + ((size_t)(b * 8 + mc) * 18) * HW + n;
    float r = __expf(mxs[mc] - mx);
    Z += pp[HW] * r;
    a0 += pp[(size_t)(2 + cg * 2) * HW] * r;
    a1 += pp[(size_t)(3 + cg * 2) * HW] * r;
  }
  float inv = gamma / Z;
  int c0 = cg * 2;
  pam_in[(b * 16 + c0) * HW + n]     = a0 * inv + feat[(b * 32 + c0) * HW + n];
  pam_in[(b * 16 + c0 + 1) * HW + n] = a1 * inv + feat[(b * 32 + c0 + 1) * HW + n];
}

// ---------------- K8: CAM gram matrix e[b,c,d] ----------------
__global__ __launch_bounds__(256) void k_cam_gram(
    const float* __restrict__ feat, float* __restrict__ e){
  int tid = threadIdx.x;
  int dd = blockIdx.x, c = blockIdx.y, b = blockIdx.z;
  const float* fc = feat + (b * 32 + 16 + c) * HW;
  const float* fd = feat + (b * 32 + 16 + dd) * HW;
  float S = 0.f;
  for (int i = tid; i < HW; i += 256) S += fc[i] * fd[i];
  S = wredsum(S);
  __shared__ float l[4];
  int lane = tid & 63, wid = tid >> 6;
  if (lane == 0) l[wid] = S;
  __syncthreads();
  if (tid == 0) e[(b * 16 + c) * 16 + dd] = l[0] + l[1] + l[2] + l[3];
}

// ---------------- K9: CAM softmax of (max - e) rows ----------------
__global__ void k_cam_soft(const float* __restrict__ e, float* __restrict__ att){
  int tid = threadIdx.x; if (tid >= 32) return;
  int b = tid >> 4, c = tid & 15;
  const float* row = e + (b * 16 + c) * 16;
  float r[16]; float mn = 1e30f;
  #pragma unroll
  for (int d = 0; d < 16; d++){ r[d] = row[d]; mn = fminf(mn, r[d]); }
  float p[16]; float s = 0.f;
  #pragma unroll
  for (int d = 0; d < 16; d++){ p[d] = __expf(mn - r[d]); s += p[d]; }
  float inv = 1.f / s;
  #pragma unroll
  for (int d = 0; d < 16; d++) att[(b * 16 + c) * 16 + d] = p[d] * inv;
}

// ---------------- K10: CAM apply + residual ----------------
__global__ __launch_bounds__(256) void k_cam_apply(
    const float* __restrict__ att, const float* __restrict__ feat,
    const float* __restrict__ gammap, float* __restrict__ cam_in){
  int tid = threadIdx.x; int c = blockIdx.y, b = blockIdx.z;
  int n = blockIdx.x * 256 + tid;
  const float* arow = att + (b * 16 + c) * 16;
  float s = 0.f;
  #pragma unroll
  for (int d = 0; d < 16; d++) s += arow[d] * feat[(b * 32 + 16 + d) * HW + n];
  cam_in[(b * 16 + c) * HW + n] = gammap[0] * s + feat[(b * 32 + 16 + c) * HW + n];
}

// ---------------- K11: 3x3 conv 16->32 (c5b|c5d), 4 outputs/thread + BN stats ----------------
__global__ __launch_bounds__(64) void k_conv5bd2(
    const float* __restrict__ pam_in, const float* __restrict__ cam_in,
    const float* __restrict__ wt2,
    float* __restrict__ bdpre, float* __restrict__ bnpart){
  int tid = threadIdx.x;
  int pix = blockIdx.x * 64 + tid;
  int ocg = blockIdx.y, b = blockIdx.z;
  int half = ocg >> 2, oq = (ocg & 3) * 4;
  int h = pix / 80, w = pix % 80;
  int off[9]; float msk[9];
  #pragma unroll
  for (int dy = 0; dy < 3; dy++){
    #pragma unroll
    for (int dx = 0; dx < 3; dx++){
      int hh = h + dy - 1, ww = w + dx - 1;
      bool ok = ((unsigned)hh < 80u) && ((unsigned)ww < 80u);
      off[dy * 3 + dx] = ok ? hh * 80 + ww : 0;
      msk[dy * 3 + dx] = ok ? 1.f : 0.f;
    }
  }
  const float* in = (half ? cam_in : pam_in) + (size_t)b * 16 * HW;
  int obase = half * 16 + oq;
  float acc[4];
  #pragma unroll
  for (int o = 0; o < 4; o++) acc[o] = 0.f;
  float xa[9], xb[9];
  #pragma unroll
  for (int k = 0; k < 9; k++) xa[k] = in[off[k]] * msk[k];
  #pragma unroll
  for (int ic = 0; ic < 16; ic += 2){
    const float* xin1 = in + (size_t)(ic + 1) * HW;
    #pragma unroll
    for (int k = 0; k < 9; k++) xb[k] = xin1[off[k]] * msk[k];
    const float* wr0 = wt2 + ic * 288 + obase * 9;
    #pragma unroll
    for (int o = 0; o < 4; o++){
      float a = acc[o];
      #pragma unroll
      for (int k = 0; k < 9; k++) a += wr0[o * 9 + k] * xa[k];
      acc[o] = a;
    }
    if (ic + 2 < 16){
      const float* xin2 = in + (size_t)(ic + 2) * HW;
      #pragma unroll
      for (int k = 0; k < 9; k++) xa[k] = xin2[off[k]] * msk[k];
    }
    const float* wr1 = wt2 + (ic + 1) * 288 + obase * 9;
    #pragma unroll
    for (int o = 0; o < 4; o++){
      float a = acc[o];
      #pragma unroll
      for (int k = 0; k < 9; k++) a += wr1[o * 9 + k] * xb[k];
      acc[o] = a;
    }
  }
  #pragma unroll
  for (int o = 0; o < 4; o++){
    float v = acc[o];
    bdpre[(b * 32 + obase + o) * HW + pix] = v;
    float S = wredsum(v), Q = wredsum(v * v);
    if (tid == 0){
      bnpart[(obase + o) * 400 + (b * 100 + blockIdx.x) * 2]     = S;
      bnpart[(obase + o) * 400 + (b * 100 + blockIdx.x) * 2 + 1] = Q;
    }
  }
}

// ---------------- K13: fused BN+relu+sum + 1x1 conv 16->256 + relu -> out ----------------
__global__ __launch_bounds__(256) void k_c6(
    const float* __restrict__ bdpre, const float* __restrict__ bnsc,
    const float* __restrict__ w6, const float* __restrict__ b6,
    float* __restrict__ out){
  int tid = threadIdx.x; int og = blockIdx.y * 32, b = blockIdx.z;
  int n = blockIdx.x * 256 + tid;
  float x[16];
  #pragma unroll
  for (int c = 0; c < 16; c++){
    float v1 = bdpre[(b * 32 + c) * HW + n] * bnsc[c * 2] + bnsc[c * 2 + 1];
    float v2 = bdpre[(b * 32 + 16 + c) * HW + n] * bnsc[(16 + c) * 2] + bnsc[(16 + c) * 2 + 1];
    x[c] = fmaxf(v1, 0.f) + fmaxf(v2, 0.f);
  }
  #pragma unroll
  for (int o = 0; o < 32; o++){
    float a = b6[og + o];
    #pragma unroll
    for (int c = 0; c < 16; c++) a += w6[(og + o) * 16 + c] * x[c];
    out[(b * 256 + og + o) * HW + n] = fmaxf(a, 0.f);
  }
}

extern "C" void kernel_launch(void* const* d_in, const int* in_sizes, int n_in,
                              void* d_out, int out_size, void* d_ws, size_t ws_size,
                              hipStream_t stream){
  const float* z      = (const float*)d_in[0];
  const float* w_at0  = (const float*)d_in[1];
  const float* b_at0  = (const float*)d_in[2];
  const float* w_at1  = (const float*)d_in[3];
  const float* b_at1  = (const float*)d_in[4];
  const float* w_at2  = (const float*)d_in[5];
  const float* b_at2  = (const float*)d_in[6];
  const float* w_at3  = (const float*)d_in[7];
  const float* b_at3  = (const float*)d_in[8];
  const float* gn_w   = (const float*)d_in[9];
  const float* gn_b   = (const float*)d_in[10];
  const float* conv_w = (const float*)d_in[11];
  const float* conv_b = (const float*)d_in[12];
  const float* c5a_w  = (const float*)d_in[13];
  const float* bn5a_w = (const float*)d_in[14];
  const float* bn5a_b = (const float*)d_in[15];
  const float* c5c_w  = (const float*)d_in[16];
  const float* bn5c_w = (const float*)d_in[17];
  const float* bn5c_b = (const float*)d_in[18];
  const float* pq_w   = (const float*)d_in[19];
  const float* pq_b   = (const float*)d_in[20];
  const float* pk_w   = (const float*)d_in[21];
  const float* pk_b   = (const float*)d_in[22];
  const float* pv_w   = (const float*)d_in[23];
  const float* pv_b   = (const float*)d_in[24];
  const float* pa_g   = (const float*)d_in[25];
  const float* ca_g   = (const float*)d_in[26];
  const float* c5b_w  = (const float*)d_in[27];
  const float* bn5b_w = (const float*)d_in[28];
  const float* bn5b_b = (const float*)d_in[29];
  const float* c5d_w  = (const float*)d_in[30];
  const float* bn5d_w = (const float*)d_in[31];
  const float* bn5d_b = (const float*)d_in[32];
  const float* c6_w   = (const float*)d_in[33];
  const float* c6_b   = (const float*)d_in[34];

  float* ws = (float*)d_ws;
  float* ZC      = ws;                    // 3,276,800 fp32 (k_dw out, k_zbf in)
  float* ZC2     = ZC + 3276800;          // 3,276,800 region
  float* FPRE    = ZC2 + 3276800;         // 409,600
  float* FEAT    = FPRE + 409600;         // 409,600
  float* QKVT    = FEAT + 409600;         // 256,000
  float* PAM_IN  = QKVT + 256000;         // 204,800
  float* CAM_IN  = PAM_IN + 204800;       // 204,800
  float* BDPRE   = CAM_IN + 204800;       // 409,600
  float* ST      = BDPRE + 409600;
  float* GN_SC    = ST;                   // 1024
  float* BNA_SC   = ST + 1024;            // 64
  float* BNB_SC   = ST + 1088;            // 64
  float* CAM_ATT  = ST + 1152;            // 512
  float* CAM_E    = ST + 1664;            // 512
  float* GN_PART  = ST + 2176;            // 25,600
  float* BNA_PART = ST + 27776;           // 3,200
  float* BNB_PART = ST + 30976;           // 12,800
  float* WT2      = ST + 43776;           // 4,608
  unsigned short* WBBF = (unsigned short*)(ST + 48384);  // 73,728 bf16 (36,864 f32)
  // Time-multiplexed aliases:
  //  - ZBF (bf16 raw-z transposed [b][pix][ic]) at f32 [3,276,800..4,915,200):
  //    written by k_zbf (after which ZC fp32 is dead), read by k_conv1_mfma.
  //  - ZC2BFT (bf16 zc2^T) at f32 [4,915,200..6,553,600): conv1 out, conv5ac in.
  //  - CWBF (262,144 bf16 = 131,072 f32) + CBP (512 f32) live in dead-ZC [0..131,584):
  //    written after k_zbf, dead after k_conv1_mfma.
  //  - PARTIAL (9*2*32*HW = 3,686,400 f32) at [0..3,686,400): written by conv5ac
  //    (CWBF/CBP/ZBF dead by then... ZBF dies when conv1 completes; PARTIAL's tail
  //    [3,276,800..3,686,400) overlaps ZBF, which is dead).
  //  - PART (PAM, 8*18*2*HW = 1,843,200 f32) at [0..1,843,200).
  unsigned short* ZBF    = (unsigned short*)(ws + 3276800);
  unsigned short* ZC2BFT = (unsigned short*)(ws + 4915200);
  unsigned short* CWBF   = (unsigned short*)ws;
  float* CBP     = ws + 131072;
  float* PARTIAL = ZC;
  float* PART    = ZC;

  k_wprep<<<288, 256, 0, stream>>>(c5a_w, c5c_w, c5b_w, c5d_w, WT2, WBBF);
  k_dw<<<dim3(25, 256, 2), 256, 0, stream>>>(z, w_at0, b_at0, w_at1, b_at1,
                                             w_at2, b_at2, w_at3, b_at3, ZC, GN_PART);
  k_gnfin<<<8, 256, 0, stream>>>(GN_PART, gn_w, gn_b, GN_SC);
  k_zbf<<<dim3(50, 4, 2), 256, 0, stream>>>(ZC, ZBF);
  k_gnw<<<512, 256, 0, stream>>>(conv_w, GN_SC, CWBF);
  k_cbp<<<dim3(16, 2), 256, 0, stream>>>(conv_w, GN_SC, conv_b, CBP);
  k_conv1_mfma<<<dim3(100, 4, 2), 256, 0, stream>>>(ZBF, CWBF, CBP, ZC2BFT);
  k_conv5ac_mfma<<<dim3(100, 9, 2), 256, 0, stream>>>(ZC2BFT, WBBF, PARTIAL);
  k_conv5ac_red<<<dim3(25, 32, 2), 256, 0, stream>>>(PARTIAL, FPRE, BNA_PART);
  k_bnfin<<<1, 256, 0, stream>>>(BNA_PART, 50, bn5a_w, bn5a_b, bn5c_w, bn5c_b, BNA_SC);
  k_featqkv<<<dim3(25, 2), 256, 0, stream>>>(FPRE, BNA_SC, pq_w, pq_b, pk_w, pk_b,
                                             pv_w, pv_b, FEAT, QKVT);
  k_pam_a<<<dim3(100, 8, 2), 256, 0, stream>>>(QKVT, PART);
  k_pam_b<<<dim3(25, 8, 2), 256, 0, stream>>>(PART, FEAT, pa_g, PAM_IN);
  k_cam_gram<<<dim3(16, 16, 2), 256, 0, stream>>>(FEAT, CAM_E);
  k_cam_soft<<<1, 64, 0, stream>>>(CAM_E, CAM_ATT);
  k_cam_apply<<<dim3(25, 16, 2), 256, 0, stream>>>(CAM_ATT, FEAT, ca_g, CAM_IN);
  k_conv5bd2<<<dim3(100, 8, 2), 64, 0, stream>>>(PAM_IN, CAM_IN, WT2, BDPRE, BNB_PART);
  k_bnfin<<<1, 256, 0, stream>>>(BNB_PART, 200, bn5b_w, bn5b_b, bn5d_w, bn5d_b, BNB_SC);
  k_c6<<<dim3(25, 8, 2), 256, 0, stream>>>(BDPRE, BNB_SC, c6_w, c6_b, (float*)d_out);
}

// Round 12
// 164.306 us; speedup vs baseline: 3.7185x; 1.0783x over previous
//
#include <hip/hip_runtime.h>
#include <math.h>

#define HW 6400

typedef __attribute__((ext_vector_type(8))) short bf16x8;
typedef __attribute__((ext_vector_type(4))) float f32x4;

__device__ __forceinline__ float wredsum(float v){
  #pragma unroll
  for (int o = 32; o; o >>= 1) v += __shfl_xor(v, o);
  return v;
}

__device__ __forceinline__ unsigned short f2bf(float f){
  unsigned int u = __float_as_uint(f);
  u += 0x7FFF + ((u >> 16) & 1);   // RNE
  return (unsigned short)(u >> 16);
}

__device__ __forceinline__ unsigned int cvt_pk_bf16(float lo, float hi){
  unsigned int r;
  asm("v_cvt_pk_bf16_f32 %0, %1, %2" : "=v"(r) : "v"(lo), "v"(hi));
  return r;
}

__device__ __forceinline__ float gelu(float v){
  return 0.5f * v * (1.f + erff(v * 0.70710678118f));
}

// ---------------- K0: weight re-layout prep (conv5 weights) ----------------
__global__ __launch_bounds__(256) void k_wprep(
    const float* __restrict__ wa, const float* __restrict__ wc,
    const float* __restrict__ wb, const float* __restrict__ wd,
    float* __restrict__ wt2, unsigned short* __restrict__ wbbf){
  int i = blockIdx.x * 256 + threadIdx.x;
  if (i < 16 * 288){
    int ic = i / 288, r = i - ic * 288;
    int o = r / 9, k = r - o * 9;
    float v = (o < 16) ? wb[(o * 16 + ic) * 9 + k] : wd[((o - 16) * 16 + ic) * 9 + k];
    wt2[i] = v;
  }
  if (i < 73728){
    int j = i & 7, l = (i >> 3) & 63, f = (i >> 9) & 1, ss = i >> 10;
    int k = ss * 32 + (l >> 4) * 8 + j;
    int off = k >> 8, ic = k & 255;
    int oc = f * 16 + (l & 15);
    float v = (oc < 16) ? wa[(oc * 256 + ic) * 9 + off]
                        : wc[((oc - 16) * 256 + ic) * 9 + off];
    wbbf[i] = f2bf(v);
  }
}

// ---------------- K0b: conv1 weight (GN-scale folded) + bias (GN-shift folded) ----
__global__ __launch_bounds__(256) void k_prep1(
    const float* __restrict__ cw, const float* __restrict__ gn_sc,
    const float* __restrict__ cb,
    unsigned short* __restrict__ cwbf, float* __restrict__ cbp){
  int bx = blockIdx.x;
  int tid = threadIdx.x;
  if (bx < 512){
    int i = bx * 256 + tid;
    int b = i >> 16, r = i & 65535;
    int j = r & 7, l = (r >> 3) & 63, f = (r >> 9) & 15, ss = r >> 13;
    int ic = ss * 32 + (l >> 4) * 8 + j;
    int oc = f * 16 + (l & 15);
    cwbf[i] = f2bf(cw[oc * 256 + ic] * gn_sc[(b * 256 + ic) * 2]);
  } else {
    int bb = bx - 512;           // 0..31
    int b = bb >> 4;
    int oc = (bb & 15) * 16 + (tid >> 4);
    int cp = tid & 15;
    float s2 = 0.f;
    #pragma unroll
    for (int k = 0; k < 16; k++){
      int c = cp * 16 + k;
      s2 += cw[oc * 256 + c] * gn_sc[(b * 256 + c) * 2 + 1];
    }
    s2 += __shfl_xor(s2, 1); s2 += __shfl_xor(s2, 2);
    s2 += __shfl_xor(s2, 4); s2 += __shfl_xor(s2, 8);
    if (cp == 0) cbp[b * 256 + oc] = cb[oc] + s2;
  }
}

// ---------------- K1: depthwise dilated convs -> bf16 [pix][c] + GN partials ----
// grid (100 pixblocks, 4 cgroups, 2 b), block 256 = 4 waves.
// Wave s handles channels g*64+s*16..+15 for 64 pixels (lane = pixel).
__global__ __launch_bounds__(256) void k_dwt(
    const float* __restrict__ z,
    const float* __restrict__ w0, const float* __restrict__ b0,
    const float* __restrict__ w1, const float* __restrict__ b1,
    const float* __restrict__ w2, const float* __restrict__ b2,
    const float* __restrict__ w3, const float* __restrict__ b3,
    unsigned short* __restrict__ zbf, float* __restrict__ gnpart){
  __shared__ unsigned short lt[64][66];   // stride 33 words -> conflict-free b16 writes
  int tid = threadIdx.x;
  int g = blockIdx.y, b = blockIdx.z;
  int p0 = blockIdx.x * 64;
  int lane = tid & 63, s = tid >> 6;
  int pix = p0 + lane;
  int h = pix / 80, w = pix % 80;
  const float* wp; const float* bp; int d;
  if (g == 0){ wp = w0; bp = b0; d = 7; }
  else if (g == 1){ wp = w1; bp = b1; d = 5; }
  else if (g == 2){ wp = w2; bp = b2; d = 2; }
  else            { wp = w3; bp = b3; d = 1; }
  int offr[9]; float msk[9];
  #pragma unroll
  for (int kh = 0; kh < 3; kh++){
    #pragma unroll
    for (int kw = 0; kw < 3; kw++){
      bool ok = ((unsigned)(h + (kh - 1) * d) < 80u) && ((unsigned)(w + (kw - 1) * d) < 80u);
      offr[kh * 3 + kw] = ok ? ((kh - 1) * d * 80 + (kw - 1) * d) : 0;
      msk[kh * 3 + kw] = ok ? 1.f : 0.f;
    }
  }
  const float* zb = z + (size_t)(b * 256 + g * 64) * HW + pix;
  for (int j = 0; j < 16; j++){
    int cl = s * 16 + j;
    const float* zin = zb + (size_t)cl * HW;
    const float* wr = wp + cl * 9;           // wave-uniform -> s_load
    float acc = bp[cl];
    #pragma unroll
    for (int k = 0; k < 9; k++) acc = fmaf(wr[k], zin[offr[k]] * msk[k], acc);
    float S = wredsum(acc), Q = wredsum(acc * acc);
    if (lane == 0){
      int cg = b * 256 + g * 64 + cl;
      gnpart[(cg * 100 + blockIdx.x) * 2]     = S;
      gnpart[(cg * 100 + blockIdx.x) * 2 + 1] = Q;
    }
    lt[lane][cl] = f2bf(acc);
  }
  __syncthreads();
  int pr = tid >> 2, q = tid & 3;
  const unsigned short* src = &lt[pr][q * 16];
  unsigned int tmp[8];
  #pragma unroll
  for (int u = 0; u < 8; u++) tmp[u] = *(const unsigned int*)(src + u * 2);
  uint4 v0 = make_uint4(tmp[0], tmp[1], tmp[2], tmp[3]);
  uint4 v1 = make_uint4(tmp[4], tmp[5], tmp[6], tmp[7]);
  unsigned short* dst = zbf + ((size_t)b * HW + p0 + pr) * 256 + g * 64 + q * 16;
  *(uint4*)dst = v0;
  *(uint4*)(dst + 8) = v1;
}

// ---------------- K2: GN stats finalize -> per (b,c) scale/shift ----------------
__global__ __launch_bounds__(256) void k_gnfin(
    const float* __restrict__ gnpart, const float* __restrict__ gn_w,
    const float* __restrict__ gn_b, float* __restrict__ gn_sc){
  int tid = threadIdx.x; int bg = blockIdx.x; // b*4+g
  int b = bg >> 2, g = bg & 3;
  size_t base = (size_t)(b * 256 + g * 64) * 200;
  float S = 0.f, Q = 0.f;
  for (int i = tid; i < 6400; i += 256){
    S += gnpart[base + 2 * i];
    Q += gnpart[base + 2 * i + 1];
  }
  S = wredsum(S); Q = wredsum(Q);
  __shared__ float l[8];
  int lane = tid & 63, wid = tid >> 6;
  if (lane == 0){ l[wid] = S; l[4 + wid] = Q; }
  __syncthreads();
  float SS = l[0] + l[1] + l[2] + l[3];
  float QQ = l[4] + l[5] + l[6] + l[7];
  float M = 64.f * HW;
  float mean = SS / M;
  float var = QQ / M - mean * mean;
  float rstd = rsqrtf(var + 1e-5f);
  if (tid < 64){
    int c = g * 64 + tid;
    float sc = gn_w[c] * rstd;
    float sh = gn_b[c] - mean * sc;
    gn_sc[(b * 256 + c) * 2] = sc;
    gn_sc[(b * 256 + c) * 2 + 1] = sh;
  }
}

// ---------------- K3: 1x1 conv 256->256 (GN folded) via bf16 MFMA + GELU ----------------
__global__ __launch_bounds__(256) void k_conv1_mfma(
    const unsigned short* __restrict__ zbf,
    const unsigned short* __restrict__ cwbf,
    const float* __restrict__ cbp,
    unsigned short* __restrict__ zbfT){
  __shared__ __align__(16) unsigned char lmem[64 * 512];   // 32KB
  unsigned short* lda = (unsigned short*)lmem;
  unsigned short* lout = (unsigned short*)lmem;
  int tid = threadIdx.x;
  int p0 = blockIdx.x * 64, ocg = blockIdx.y, b = blockIdx.z;
  #pragma unroll
  for (int k = 0; k < 8; k++){
    int m = tid + k * 256;
    int i = m >> 5, c = m & 31;
    bf16x8 val = *(const bf16x8*)(zbf + ((size_t)b * HW + p0 + i) * 256 + c * 8);
    *(bf16x8*)(lda + i * 256 + (c ^ (i & 7)) * 8) = val;
  }
  __syncthreads();
  int wv = tid >> 6, l = tid & 63;
  int row = l & 15, kg = l >> 4;
  int i = wv * 16 + row;
  f32x4 acc0 = {0.f,0.f,0.f,0.f}, acc1 = {0.f,0.f,0.f,0.f};
  f32x4 acc2 = {0.f,0.f,0.f,0.f}, acc3 = {0.f,0.f,0.f,0.f};
  const unsigned short* wp = cwbf + (size_t)b * 65536 + (ocg * 4) * 512 + l * 8;
  #pragma unroll
  for (int s = 0; s < 8; s++){
    int c = s * 4 + kg;
    bf16x8 a = *(const bf16x8*)(lda + i * 256 + (c ^ (i & 7)) * 8);
    const unsigned short* wps = wp + s * 8192;
    bf16x8 b0 = *(const bf16x8*)(wps);
    bf16x8 b1 = *(const bf16x8*)(wps + 512);
    bf16x8 b2 = *(const bf16x8*)(wps + 1024);
    bf16x8 b3 = *(const bf16x8*)(wps + 1536);
    acc0 = __builtin_amdgcn_mfma_f32_16x16x32_bf16(a, b0, acc0, 0, 0, 0);
    acc1 = __builtin_amdgcn_mfma_f32_16x16x32_bf16(a, b1, acc1, 0, 0, 0);
    acc2 = __builtin_amdgcn_mfma_f32_16x16x32_bf16(a, b2, acc2, 0, 0, 0);
    acc3 = __builtin_amdgcn_mfma_f32_16x16x32_bf16(a, b3, acc3, 0, 0, 0);
  }
  __syncthreads();
  const float* cbb = cbp + b * 256 + ocg * 64;
  int oc_l = l & 15;
  int pl = wv * 16 + kg * 4;
  float bs0 = cbb[oc_l], bs1 = cbb[16 + oc_l], bs2 = cbb[32 + oc_l], bs3 = cbb[48 + oc_l];
  #pragma unroll
  for (int r = 0; r < 4; r++){
    lout[(pl + r) * 72 + oc_l]      = f2bf(gelu(acc0[r] + bs0));
    lout[(pl + r) * 72 + 16 + oc_l] = f2bf(gelu(acc1[r] + bs1));
    lout[(pl + r) * 72 + 32 + oc_l] = f2bf(gelu(acc2[r] + bs2));
    lout[(pl + r) * 72 + 48 + oc_l] = f2bf(gelu(acc3[r] + bs3));
  }
  __syncthreads();
  int pix = tid >> 2, q = tid & 3;
  unsigned short* dst = zbfT + ((size_t)b * HW + p0 + pix) * 256 + ocg * 64 + q * 16;
  const unsigned short* src = lout + pix * 72 + q * 16;
  *(uint4*)dst       = *(const uint4*)src;
  *(uint4*)(dst + 8) = *(const uint4*)(src + 8);
}

// ---------------- K4 helper: masked global load of one halo offset ----------------
__device__ __forceinline__ void c5_gload(bf16x8* r, const unsigned short* zbase,
    int p0, int irow, int c31, const int* hh, const int* ww, int off){
  int dy = off / 3 - 1, dx = off % 3 - 1;
  int doff = dy * 80 + dx;
  #pragma unroll
  for (int k = 0; k < 8; k++){
    int op = p0 + irow + k * 8;
    bool v = ((unsigned)(hh[k] + dy) < 80u) && ((unsigned)(ww[k] + dx) < 80u);
    int sp = v ? (op + doff) : op;
    bf16x8 val = *(const bf16x8*)(zbase + (size_t)sp * 256 + c31 * 8);
    if (!v) val = (bf16x8){0, 0, 0, 0, 0, 0, 0, 0};
    r[k] = val;
  }
}

// ---------------- K4: 3x3 conv 256->32 via bf16 MFMA, single pass over 9 offsets ----
// grid (100 pixtiles, 2 oc-halves, 2 b), block 256 = 4 waves; double-buffered LDS,
// register accumulation across offsets; writes fpre + BN partials directly.
__global__ __launch_bounds__(256) void k_conv5ac2(
    const unsigned short* __restrict__ zbfT,
    const unsigned short* __restrict__ wbbf,
    float* __restrict__ fpre, float* __restrict__ bnpart){
  __shared__ __align__(16) unsigned short lda[2][64 * 256];   // 2 x 32KB
  int tid = threadIdx.x;
  int och = blockIdx.y, b = blockIdx.z;
  int p0 = blockIdx.x * 64;
  int irow = tid >> 5, c31 = tid & 31;
  int hh[8], ww[8];
  #pragma unroll
  for (int k = 0; k < 8; k++){
    int op = p0 + irow + k * 8;
    hh[k] = op / 80; ww[k] = op % 80;
  }
  const unsigned short* zbase = zbfT + (size_t)b * HW * 256;
  bf16x8 r[8];
  c5_gload(r, zbase, p0, irow, c31, hh, ww, 0);
  #pragma unroll
  for (int k = 0; k < 8; k++){
    int i = irow + k * 8;
    *(bf16x8*)(lda[0] + i * 256 + (c31 ^ (i & 7)) * 8) = r[k];
  }
  c5_gload(r, zbase, p0, irow, c31, hh, ww, 1);
  int wv = tid >> 6, l = tid & 63;
  int lrow = l & 15, kg = l >> 4;
  int li = wv * 16 + lrow;
  f32x4 acc = {0.f, 0.f, 0.f, 0.f};
  for (int off = 0; off < 9; off++){
    __syncthreads();
    int buf = off & 1;
    const unsigned short* wp = wbbf + (size_t)off * 8192 + och * 512 + l * 8;
    #pragma unroll
    for (int s = 0; s < 8; s++){
      int cc = s * 4 + kg;
      bf16x8 a = *(const bf16x8*)(lda[buf] + li * 256 + (cc ^ (li & 7)) * 8);
      bf16x8 bb = *(const bf16x8*)(wp + s * 1024);
      acc = __builtin_amdgcn_mfma_f32_16x16x32_bf16(a, bb, acc, 0, 0, 0);
    }
    if (off + 1 < 9){
      #pragma unroll
      for (int k = 0; k < 8; k++){
        int i = irow + k * 8;
        *(bf16x8*)(lda[buf ^ 1] + i * 256 + (c31 ^ (i & 7)) * 8) = r[k];
      }
      if (off + 2 < 9) c5_gload(r, zbase, p0, irow, c31, hh, ww, off + 2);
    }
  }
  __syncthreads();   // all lda reads done -> reuse as float lout [16][68]
  float* lout = (float*)lda;
  int ocl = l & 15;
  int pl = wv * 16 + kg * 4;
  #pragma unroll
  for (int rr = 0; rr < 4; rr++) lout[ocl * 68 + pl + rr] = acc[rr];
  __syncthreads();
  int oc = tid >> 4, px = (tid & 15) * 4;
  float4 v = *(float4*)(lout + oc * 68 + px);
  *(float4*)(fpre + ((size_t)(b * 32 + och * 16 + oc)) * HW + p0 + px) = v;
  float S = v.x + v.y + v.z + v.w;
  float Q = v.x * v.x + v.y * v.y + v.z * v.z + v.w * v.w;
  #pragma unroll
  for (int o2 = 1; o2 < 16; o2 <<= 1){ S += __shfl_xor(S, o2); Q += __shfl_xor(Q, o2); }
  if ((tid & 15) == 0){
    int ocg = och * 16 + oc;
    bnpart[ocg * 400 + (b * 100 + blockIdx.x) * 2]     = S;
    bnpart[ocg * 400 + (b * 100 + blockIdx.x) * 2 + 1] = Q;
  }
}

// ---------------- K5/K12: BN finalize (32 channels), parallel reduce ----------------
__global__ __launch_bounds__(256) void k_bnfin(
    const float* __restrict__ part, int nent,
    const float* __restrict__ w1, const float* __restrict__ b1,
    const float* __restrict__ w2, const float* __restrict__ b2,
    float* __restrict__ sc_out){
  __shared__ float lS[8][32], lQ[8][32];
  int tid = threadIdx.x;
  int oc = tid & 31, sl = tid >> 5;
  float S = 0.f, Q = 0.f;
  for (int i = sl; i < nent; i += 8){
    S += part[oc * 2 * nent + i * 2];
    Q += part[oc * 2 * nent + i * 2 + 1];
  }
  lS[sl][oc] = S; lQ[sl][oc] = Q;
  __syncthreads();
  if (tid < 32){
    float SS = 0.f, QQ = 0.f;
    #pragma unroll
    for (int s = 0; s < 8; s++){ SS += lS[s][oc]; QQ += lQ[s][oc]; }
    float M = 2.f * HW;
    float mean = SS / M, var = QQ / M - mean * mean;
    float rstd = rsqrtf(var + 1e-3f);
    float w  = (oc < 16) ? w1[oc] : w2[oc - 16];
    float bb = (oc < 16) ? b1[oc] : b2[oc - 16];
    float sc = w * rstd, sh = bb - mean * sc;
    sc_out[oc * 2] = sc; sc_out[oc * 2 + 1] = sh;
  }
}

// ---------------- K6: BN+relu apply -> feat1/feat2, and q,k,v 1x1 convs ----------------
__global__ __launch_bounds__(256) void k_featqkv(
    const float* __restrict__ fpre, const float* __restrict__ bnsc,
    const float* __restrict__ pqw, const float* __restrict__ pqb,
    const float* __restrict__ pkw, const float* __restrict__ pkb,
    const float* __restrict__ pvw, const float* __restrict__ pvb,
    float* __restrict__ feat, float* __restrict__ qkvT){
  int tid = threadIdx.x; int b = blockIdx.y;
  int n = blockIdx.x * 256 + tid;
  float f1[16], f2[16];
  #pragma unroll
  for (int c = 0; c < 16; c++){
    float v1 = fpre[(b * 32 + c) * HW + n] * bnsc[c * 2] + bnsc[c * 2 + 1];
    f1[c] = fmaxf(v1, 0.f);
    float v2 = fpre[(b * 32 + 16 + c) * HW + n] * bnsc[(16 + c) * 2] + bnsc[(16 + c) * 2 + 1];
    f2[c] = fmaxf(v2, 0.f);
    feat[(b * 32 + c) * HW + n] = f1[c];
    feat[(b * 32 + 16 + c) * HW + n] = f2[c];
  }
  float* o = qkvT + ((size_t)b * HW + n) * 20;
  #pragma unroll
  for (int j = 0; j < 2; j++){
    float q = pqb[j], k = pkb[j];
    #pragma unroll
    for (int c = 0; c < 16; c++){ q += pqw[j * 16 + c] * f1[c]; k += pkw[j * 16 + c] * f1[c]; }
    o[j] = q; o[2 + j] = k;
  }
  #pragma unroll
  for (int j = 0; j < 16; j++){
    float v = pvb[j];
    #pragma unroll
    for (int c = 0; c < 16; c++) v += pvw[j * 16 + c] * f1[c];
    o[4 + j] = v;
  }
}

// ---------------- K7a: PAM flash partials via MFMA PV, 8 m-chunks of 800 ----------------
__global__ __launch_bounds__(256) void k_pam_a(
    const float* __restrict__ qkvT, float* __restrict__ part){
  __shared__ __align__(16) float lk0[800];
  __shared__ __align__(16) float lk1[800];
  __shared__ __align__(16) unsigned short lvb[16][808];
  __shared__ float lred[4];
  int tid = threadIdx.x;
  int mc = blockIdx.y, b = blockIdx.z;
  float sqm = 0.f;
  for (int m = tid; m < 800; m += 256){
    const float* kv = qkvT + ((size_t)b * HW + mc * 800 + m) * 20;
    float4 a0 = *(const float4*)kv;
    lk0[m] = a0.z; lk1[m] = a0.w;
    sqm = fmaxf(sqm, a0.z * a0.z + a0.w * a0.w);
    float4 v0 = *(const float4*)(kv + 4);
    float4 v1 = *(const float4*)(kv + 8);
    float4 v2 = *(const float4*)(kv + 12);
    float4 v3 = *(const float4*)(kv + 16);
    lvb[0][m]  = f2bf(v0.x); lvb[1][m]  = f2bf(v0.y);
    lvb[2][m]  = f2bf(v0.z); lvb[3][m]  = f2bf(v0.w);
    lvb[4][m]  = f2bf(v1.x); lvb[5][m]  = f2bf(v1.y);
    lvb[6][m]  = f2bf(v1.z); lvb[7][m]  = f2bf(v1.w);
    lvb[8][m]  = f2bf(v2.x); lvb[9][m]  = f2bf(v2.y);
    lvb[10][m] = f2bf(v2.z); lvb[11][m] = f2bf(v2.w);
    lvb[12][m] = f2bf(v3.x); lvb[13][m] = f2bf(v3.y);
    lvb[14][m] = f2bf(v3.z); lvb[15][m] = f2bf(v3.w);
  }
  #pragma unroll
  for (int o = 32; o; o >>= 1) sqm = fmaxf(sqm, __shfl_xor(sqm, o));
  int lane = tid & 63, wid = tid >> 6;
  if (lane == 0) lred[wid] = sqm;
  __syncthreads();
  float kmax = sqrtf(fmaxf(fmaxf(lred[0], lred[1]), fmaxf(lred[2], lred[3])));
  int wv = tid >> 6, l = tid & 63;
  int row = l & 15, kg = l >> 4;
  int n = blockIdx.x * 64 + wv * 16 + row;
  const float* qp = qkvT + ((size_t)b * HW + n) * 20;
  float q0 = qp[0], q1 = qp[1];
  float mxr = sqrtf(q0 * q0 + q1 * q1) * kmax;
  f32x4 acc = {0.f, 0.f, 0.f, 0.f};
  float zp = 0.f;
  for (int t = 0; t < 25; t++){
    int m0 = t * 32 + kg * 8;
    float4 k0a = *(const float4*)&lk0[m0];
    float4 k0b = *(const float4*)&lk0[m0 + 4];
    float4 k1a = *(const float4*)&lk1[m0];
    float4 k1b = *(const float4*)&lk1[m0 + 4];
    float p0 = __expf(fmaf(q0, k0a.x, q1 * k1a.x) - mxr);
    float p1 = __expf(fmaf(q0, k0a.y, q1 * k1a.y) - mxr);
    float p2 = __expf(fmaf(q0, k0a.z, q1 * k1a.z) - mxr);
    float p3 = __expf(fmaf(q0, k0a.w, q1 * k1a.w) - mxr);
    float p4 = __expf(fmaf(q0, k0b.x, q1 * k1b.x) - mxr);
    float p5 = __expf(fmaf(q0, k0b.y, q1 * k1b.y) - mxr);
    float p6 = __expf(fmaf(q0, k0b.z, q1 * k1b.z) - mxr);
    float p7 = __expf(fmaf(q0, k0b.w, q1 * k1b.w) - mxr);
    zp += ((p0 + p1) + (p2 + p3)) + ((p4 + p5) + (p6 + p7));
    union { unsigned int u[4]; bf16x8 v; } pk;
    pk.u[0] = cvt_pk_bf16(p0, p1);
    pk.u[1] = cvt_pk_bf16(p2, p3);
    pk.u[2] = cvt_pk_bf16(p4, p5);
    pk.u[3] = cvt_pk_bf16(p6, p7);
    bf16x8 vb = *(const bf16x8*)&lvb[row][m0];
    acc = __builtin_amdgcn_mfma_f32_16x16x32_bf16(pk.v, vb, acc, 0, 0, 0);
  }
  zp += __shfl_xor(zp, 16);
  zp += __shfl_xor(zp, 32);
  float* pp = part + ((size_t)(b * 8 + mc) * 18) * HW;
  if (kg == 0){ pp[n] = mxr; pp[HW + n] = zp; }
  int c = l & 15;
  int nr = blockIdx.x * 64 + wv * 16 + (l >> 4) * 4;
  *(f32x4*)&pp[(size_t)(2 + c) * HW + nr] = acc;
}

// ---------------- K7b: merge 8 PAM partials (2 channels/block), residual ----------------
__global__ __launch_bounds__(256) void k_pam_b(
    const float* __restrict__ part, const float* __restrict__ feat,
    const float* __restrict__ gammap, float* __restrict__ pam_in){
  int tid = threadIdx.x; int cg = blockIdx.y, b = blockIdx.z;
  int n = blockIdx.x * 256 + tid;
  float gamma = gammap[0];
  float mxs[8]; float mx = -1e30f;
  #pragma unroll
  for (int mc = 0; mc < 8; mc++){
    mxs[mc] = part[((size_t)(b * 8 + mc) * 18) * HW + n];
    mx = fmaxf(mx, mxs[mc]);
  }
  float Z = 0.f, a0 = 0.f, a1 = 0.f;
  #pragma unroll
  for (int mc = 0; mc < 8; mc++){
    const float* pp = part + ((size_t)(b * 8 + mc) * 18) * HW + n;
    float r = __expf(mxs[mc] - mx);
    Z += pp[HW] * r;
    a0 += pp[(size_t)(2 + cg * 2) * HW] * r;
    a1 += pp[(size_t)(3 + cg * 2) * HW] * r;
  }
  float inv = gamma / Z;
  int c0 = cg * 2;
  pam_in[(b * 16 + c0) * HW + n]     = a0 * inv + feat[(b * 32 + c0) * HW + n];
  pam_in[(b * 16 + c0 + 1) * HW + n] = a1 * inv + feat[(b * 32 + c0 + 1) * HW + n];
}

// ---------------- K8: CAM gram matrix e[b,c,d] ----------------
__global__ __launch_bounds__(256) void k_cam_gram(
    const float* __restrict__ feat, float* __restrict__ e){
  int tid = threadIdx.x;
  int dd = blockIdx.x, c = blockIdx.y, b = blockIdx.z;
  const float* fc = feat + (b * 32 + 16 + c) * HW;
  const float* fd = feat + (b * 32 + 16 + dd) * HW;
  float S = 0.f;
  for (int i = tid; i < HW; i += 256) S += fc[i] * fd[i];
  S = wredsum(S);
  __shared__ float l[4];
  int lane = tid & 63, wid = tid >> 6;
  if (lane == 0) l[wid] = S;
  __syncthreads();
  if (tid == 0) e[(b * 16 + c) * 16 + dd] = l[0] + l[1] + l[2] + l[3];
}

// ---------------- K9: CAM softmax of (max - e) rows ----------------
__global__ void k_cam_soft(const float* __restrict__ e, float* __restrict__ att){
  int tid = threadIdx.x; if (tid >= 32) return;
  int b = tid >> 4, c = tid & 15;
  const float* row = e + (b * 16 + c) * 16;
  float r[16]; float mn = 1e30f;
  #pragma unroll
  for (int d = 0; d < 16; d++){ r[d] = row[d]; mn = fminf(mn, r[d]); }
  float p[16]; float s = 0.f;
  #pragma unroll
  for (int d = 0; d < 16; d++){ p[d] = __expf(mn - r[d]); s += p[d]; }
  float inv = 1.f / s;
  #pragma unroll
  for (int d = 0; d < 16; d++) att[(b * 16 + c) * 16 + d] = p[d] * inv;
}

// ---------------- K10: CAM apply + residual ----------------
__global__ __launch_bounds__(256) void k_cam_apply(
    const float* __restrict__ att, const float* __restrict__ feat,
    const float* __restrict__ gammap, float* __restrict__ cam_in){
  int tid = threadIdx.x; int c = blockIdx.y, b = blockIdx.z;
  int n = blockIdx.x * 256 + tid;
  const float* arow = att + (b * 16 + c) * 16;
  float s = 0.f;
  #pragma unroll
  for (int d = 0; d < 16; d++) s += arow[d] * feat[(b * 32 + 16 + d) * HW + n];
  cam_in[(b * 16 + c) * HW + n] = gammap[0] * s + feat[(b * 32 + 16 + c) * HW + n];
}

// ---------------- K11: 3x3 conv 16->32 (c5b|c5d), 4 outputs/thread + BN stats ----------------
__global__ __launch_bounds__(64) void k_conv5bd2(
    const float* __restrict__ pam_in, const float* __restrict__ cam_in,
    const float* __restrict__ wt2,
    float* __restrict__ bdpre, float* __restrict__ bnpart){
  int tid = threadIdx.x;
  int pix = blockIdx.x * 64 + tid;
  int ocg = blockIdx.y, b = blockIdx.z;
  int half = ocg >> 2, oq = (ocg & 3) * 4;
  int h = pix / 80, w = pix % 80;
  int off[9]; float msk[9];
  #pragma unroll
  for (int dy = 0; dy < 3; dy++){
    #pragma unroll
    for (int dx = 0; dx < 3; dx++){
      int hh = h + dy - 1, ww = w + dx - 1;
      bool ok = ((unsigned)hh < 80u) && ((unsigned)ww < 80u);
      off[dy * 3 + dx] = ok ? hh * 80 + ww : 0;
      msk[dy * 3 + dx] = ok ? 1.f : 0.f;
    }
  }
  const float* in = (half ? cam_in : pam_in) + (size_t)b * 16 * HW;
  int obase = half * 16 + oq;
  float acc[4];
  #pragma unroll
  for (int o = 0; o < 4; o++) acc[o] = 0.f;
  float xa[9], xb[9];
  #pragma unroll
  for (int k = 0; k < 9; k++) xa[k] = in[off[k]] * msk[k];
  #pragma unroll
  for (int ic = 0; ic < 16; ic += 2){
    const float* xin1 = in + (size_t)(ic + 1) * HW;
    #pragma unroll
    for (int k = 0; k < 9; k++) xb[k] = xin1[off[k]] * msk[k];
    const float* wr0 = wt2 + ic * 288 + obase * 9;
    #pragma unroll
    for (int o = 0; o < 4; o++){
      float a = acc[o];
      #pragma unroll
      for (int k = 0; k < 9; k++) a += wr0[o * 9 + k] * xa[k];
      acc[o] = a;
    }
    if (ic + 2 < 16){
      const float* xin2 = in + (size_t)(ic + 2) * HW;
      #pragma unroll
      for (int k = 0; k < 9; k++) xa[k] = xin2[off[k]] * msk[k];
    }
    const float* wr1 = wt2 + (ic + 1) * 288 + obase * 9;
    #pragma unroll
    for (int o = 0; o < 4; o++){
      float a = acc[o];
      #pragma unroll
      for (int k = 0; k < 9; k++) a += wr1[o * 9 + k] * xb[k];
      acc[o] = a;
    }
  }
  #pragma unroll
  for (int o = 0; o < 4; o++){
    float v = acc[o];
    bdpre[(b * 32 + obase + o) * HW + pix] = v;
    float S = wredsum(v), Q = wredsum(v * v);
    if (tid == 0){
      bnpart[(obase + o) * 400 + (b * 100 + blockIdx.x) * 2]     = S;
      bnpart[(obase + o) * 400 + (b * 100 + blockIdx.x) * 2 + 1] = Q;
    }
  }
}

// ---------------- K13: fused BN+relu+sum + 1x1 conv 16->256 + relu -> out ----------------
__global__ __launch_bounds__(256) void k_c6(
    const float* __restrict__ bdpre, const float* __restrict__ bnsc,
    const float* __restrict__ w6, const float* __restrict__ b6,
    float* __restrict__ out){
  int tid = threadIdx.x; int og = blockIdx.y * 32, b = blockIdx.z;
  int n = blockIdx.x * 256 + tid;
  float x[16];
  #pragma unroll
  for (int c = 0; c < 16; c++){
    float v1 = bdpre[(b * 32 + c) * HW + n] * bnsc[c * 2] + bnsc[c * 2 + 1];
    float v2 = bdpre[(b * 32 + 16 + c) * HW + n] * bnsc[(16 + c) * 2] + bnsc[(16 + c) * 2 + 1];
    x[c] = fmaxf(v1, 0.f) + fmaxf(v2, 0.f);
  }
  #pragma unroll
  for (int o = 0; o < 32; o++){
    float a = b6[og + o];
    #pragma unroll
    for (int c = 0; c < 16; c++) a += w6[(og + o) * 16 + c] * x[c];
    out[(b * 256 + og + o) * HW + n] = fmaxf(a, 0.f);
  }
}

extern "C" void kernel_launch(void* const* d_in, const int* in_sizes, int n_in,
                              void* d_out, int out_size, void* d_ws, size_t ws_size,
                              hipStream_t stream){
  const float* z      = (const float*)d_in[0];
  const float* w_at0  = (const float*)d_in[1];
  const float* b_at0  = (const float*)d_in[2];
  const float* w_at1  = (const float*)d_in[3];
  const float* b_at1  = (const float*)d_in[4];
  const float* w_at2  = (const float*)d_in[5];
  const float* b_at2  = (const float*)d_in[6];
  const float* w_at3  = (const float*)d_in[7];
  const float* b_at3  = (const float*)d_in[8];
  const float* gn_w   = (const float*)d_in[9];
  const float* gn_b   = (const float*)d_in[10];
  const float* conv_w = (const float*)d_in[11];
  const float* conv_b = (const float*)d_in[12];
  const float* c5a_w  = (const float*)d_in[13];
  const float* bn5a_w = (const float*)d_in[14];
  const float* bn5a_b = (const float*)d_in[15];
  const float* c5c_w  = (const float*)d_in[16];
  const float* bn5c_w = (const float*)d_in[17];
  const float* bn5c_b = (const float*)d_in[18];
  const float* pq_w   = (const float*)d_in[19];
  const float* pq_b   = (const float*)d_in[20];
  const float* pk_w   = (const float*)d_in[21];
  const float* pk_b   = (const float*)d_in[22];
  const float* pv_w   = (const float*)d_in[23];
  const float* pv_b   = (const float*)d_in[24];
  const float* pa_g   = (const float*)d_in[25];
  const float* ca_g   = (const float*)d_in[26];
  const float* c5b_w  = (const float*)d_in[27];
  const float* bn5b_w = (const float*)d_in[28];
  const float* bn5b_b = (const float*)d_in[29];
  const float* c5d_w  = (const float*)d_in[30];
  const float* bn5d_w = (const float*)d_in[31];
  const float* bn5d_b = (const float*)d_in[32];
  const float* c6_w   = (const float*)d_in[33];
  const float* c6_b   = (const float*)d_in[34];

  float* ws = (float*)d_ws;
  // Layout (f32 units):
  //  ZBF    bf16 [0 .. 1,638,400)        raw dw-conv output, [b][pix][c]
  //  ZC2BFT bf16 [1,638,400 .. 3,276,800) conv1 output, [b][pix][oc]
  //  CWBF   bf16 [3,276,800 .. 3,407,872) GN-folded conv1 weights
  //  CBP         [3,407,872 .. 3,408,384)
  //  FPRE        [3,408,384 .. 3,817,984)
  //  FEAT        [3,817,984 .. 4,227,584)
  //  QKVT        [4,227,584 .. 4,483,584)
  //  PAM_IN      [4,483,584 .. 4,688,384)
  //  CAM_IN      [4,688,384 .. 4,893,184)
  //  BDPRE       [4,893,184 .. 5,302,784)
  //  ST          [5,302,784 .. )
  //  PART (PAM partials, 1,843,200 f32) aliases [0 .. 1,843,200): ZBF+head of
  //  ZC2BFT, both dead before k_pam_a runs.
  unsigned short* ZBF    = (unsigned short*)ws;
  unsigned short* ZC2BFT = (unsigned short*)(ws + 1638400);
  unsigned short* CWBF   = (unsigned short*)(ws + 3276800);
  float* CBP     = ws + 3407872;
  float* FPRE    = ws + 3408384;
  float* FEAT    = FPRE + 409600;
  float* QKVT    = FEAT + 409600;
  float* PAM_IN  = QKVT + 256000;
  float* CAM_IN  = PAM_IN + 204800;
  float* BDPRE   = CAM_IN + 204800;
  float* ST      = BDPRE + 409600;
  float* GN_SC    = ST;                   // 1024
  float* BNA_SC   = ST + 1024;            // 64
  float* BNB_SC   = ST + 1088;            // 64
  float* CAM_ATT  = ST + 1152;            // 512
  float* CAM_E    = ST + 1664;            // 512
  float* GN_PART  = ST + 2176;            // 102,400
  float* BNA_PART = ST + 104576;          // 12,800
  float* BNB_PART = ST + 117376;          // 12,800
  float* WT2      = ST + 130176;          // 4,608
  unsigned short* WBBF = (unsigned short*)(ST + 134784);  // 73,728 bf16
  float* PART = ws;

  k_wprep<<<288, 256, 0, stream>>>(c5a_w, c5c_w, c5b_w, c5d_w, WT2, WBBF);
  k_dwt<<<dim3(100, 4, 2), 256, 0, stream>>>(z, w_at0, b_at0, w_at1, b_at1,
                                             w_at2, b_at2, w_at3, b_at3, ZBF, GN_PART);
  k_gnfin<<<8, 256, 0, stream>>>(GN_PART, gn_w, gn_b, GN_SC);
  k_prep1<<<544, 256, 0, stream>>>(conv_w, GN_SC, conv_b, CWBF, CBP);
  k_conv1_mfma<<<dim3(100, 4, 2), 256, 0, stream>>>(ZBF, CWBF, CBP, ZC2BFT);
  k_conv5ac2<<<dim3(100, 2, 2), 256, 0, stream>>>(ZC2BFT, WBBF, FPRE, BNA_PART);
  k_bnfin<<<1, 256, 0, stream>>>(BNA_PART, 200, bn5a_w, bn5a_b, bn5c_w, bn5c_b, BNA_SC);
  k_featqkv<<<dim3(25, 2), 256, 0, stream>>>(FPRE, BNA_SC, pq_w, pq_b, pk_w, pk_b,
                                             pv_w, pv_b, FEAT, QKVT);
  k_pam_a<<<dim3(100, 8, 2), 256, 0, stream>>>(QKVT, PART);
  k_pam_b<<<dim3(25, 8, 2), 256, 0, stream>>>(PART, FEAT, pa_g, PAM_IN);
  k_cam_gram<<<dim3(16, 16, 2), 256, 0, stream>>>(FEAT, CAM_E);
  k_cam_soft<<<1, 64, 0, stream>>>(CAM_E, CAM_ATT);
  k_cam_apply<<<dim3(25, 16, 2), 256, 0, stream>>>(CAM_ATT, FEAT, ca_g, CAM_IN);
  k_conv5bd2<<<dim3(100, 8, 2), 64, 0, stream>>>(PAM_IN, CAM_IN, WT2, BDPRE, BNB_PART);
  k_bnfin<<<1, 256, 0, stream>>>(BNB_PART, 200, bn5b_w, bn5b_b, bn5d_w, bn5d_b, BNB_SC);
  k_c6<<<dim3(25, 8, 2), 256, 0, stream>>>(BDPRE, BNB_SC, c6_w, c6_b, (float*)d_out);
}

// Round 13
// 150.588 us; speedup vs baseline: 4.0572x; 1.0911x over previous
//
#include <hip/hip_runtime.h>
#include <math.h>

#define HW 6400

typedef __attribute__((ext_vector_type(8))) short bf16x8;
typedef __attribute__((ext_vector_type(4))) float f32x4;

__device__ __forceinline__ float wredsum(float v){
  #pragma unroll
  for (int o = 32; o; o >>= 1) v += __shfl_xor(v, o);
  return v;
}

__device__ __forceinline__ unsigned short f2bf(float f){
  unsigned int u = __float_as_uint(f);
  u += 0x7FFF + ((u >> 16) & 1);   // RNE
  return (unsigned short)(u >> 16);
}

__device__ __forceinline__ unsigned int cvt_pk_bf16(float lo, float hi){
  unsigned int r;
  asm("v_cvt_pk_bf16_f32 %0, %1, %2" : "=v"(r) : "v"(lo), "v"(hi));
  return r;
}

__device__ __forceinline__ float gelu(float v){
  return 0.5f * v * (1.f + erff(v * 0.70710678118f));
}

// ---------------- K0: ALL weight prep in one launch (after k_gnfin) ----------------
// bx <  288: WT2 + WBBF (conv5 weights, frag-ready)
// 288..799 : CWBF (GN-scale-folded conv1 weights, frag-ready bf16)
// 800..831 : CBP  (GN-shift-folded conv1 bias)
__global__ __launch_bounds__(256) void k_prep(
    const float* __restrict__ wa, const float* __restrict__ wc,
    const float* __restrict__ wb, const float* __restrict__ wd,
    const float* __restrict__ cw, const float* __restrict__ gn_sc,
    const float* __restrict__ cb,
    float* __restrict__ wt2, unsigned short* __restrict__ wbbf,
    unsigned short* __restrict__ cwbf, float* __restrict__ cbp){
  int bx = blockIdx.x;
  int tid = threadIdx.x;
  if (bx < 288){
    int i = bx * 256 + tid;
    if (i < 16 * 288){
      int ic = i / 288, r = i - ic * 288;
      int o = r / 9, k = r - o * 9;
      float v = (o < 16) ? wb[(o * 16 + ic) * 9 + k] : wd[((o - 16) * 16 + ic) * 9 + k];
      wt2[i] = v;
    }
    if (i < 73728){
      int j = i & 7, l = (i >> 3) & 63, f = (i >> 9) & 1, ss = i >> 10;
      int k = ss * 32 + (l >> 4) * 8 + j;
      int off = k >> 8, ic = k & 255;
      int oc = f * 16 + (l & 15);
      float v = (oc < 16) ? wa[(oc * 256 + ic) * 9 + off]
                          : wc[((oc - 16) * 256 + ic) * 9 + off];
      wbbf[i] = f2bf(v);
    }
  } else if (bx < 800){
    int i = (bx - 288) * 256 + tid;
    int b = i >> 16, r = i & 65535;
    int j = r & 7, l = (r >> 3) & 63, f = (r >> 9) & 15, ss = r >> 13;
    int ic = ss * 32 + (l >> 4) * 8 + j;
    int oc = f * 16 + (l & 15);
    cwbf[i] = f2bf(cw[oc * 256 + ic] * gn_sc[(b * 256 + ic) * 2]);
  } else {
    int bb = bx - 800;           // 0..31
    int b = bb >> 4;
    int oc = (bb & 15) * 16 + (tid >> 4);
    int cp = tid & 15;
    float s2 = 0.f;
    #pragma unroll
    for (int k = 0; k < 16; k++){
      int c = cp * 16 + k;
      s2 += cw[oc * 256 + c] * gn_sc[(b * 256 + c) * 2 + 1];
    }
    s2 += __shfl_xor(s2, 1); s2 += __shfl_xor(s2, 2);
    s2 += __shfl_xor(s2, 4); s2 += __shfl_xor(s2, 8);
    if (cp == 0) cbp[b * 256 + oc] = cb[oc] + s2;
  }
}

// ---------------- K1: depthwise dilated convs -> bf16 [pix][c] + GN partials ----
__global__ __launch_bounds__(256) void k_dwt(
    const float* __restrict__ z,
    const float* __restrict__ w0, const float* __restrict__ b0,
    const float* __restrict__ w1, const float* __restrict__ b1,
    const float* __restrict__ w2, const float* __restrict__ b2,
    const float* __restrict__ w3, const float* __restrict__ b3,
    unsigned short* __restrict__ zbf, float* __restrict__ gnpart){
  __shared__ unsigned short lt[64][66];
  int tid = threadIdx.x;
  int g = blockIdx.y, b = blockIdx.z;
  int p0 = blockIdx.x * 64;
  int lane = tid & 63, s = tid >> 6;
  int pix = p0 + lane;
  int h = pix / 80, w = pix % 80;
  const float* wp; const float* bp; int d;
  if (g == 0){ wp = w0; bp = b0; d = 7; }
  else if (g == 1){ wp = w1; bp = b1; d = 5; }
  else if (g == 2){ wp = w2; bp = b2; d = 2; }
  else            { wp = w3; bp = b3; d = 1; }
  int offr[9]; float msk[9];
  #pragma unroll
  for (int kh = 0; kh < 3; kh++){
    #pragma unroll
    for (int kw = 0; kw < 3; kw++){
      bool ok = ((unsigned)(h + (kh - 1) * d) < 80u) && ((unsigned)(w + (kw - 1) * d) < 80u);
      offr[kh * 3 + kw] = ok ? ((kh - 1) * d * 80 + (kw - 1) * d) : 0;
      msk[kh * 3 + kw] = ok ? 1.f : 0.f;
    }
  }
  const float* zb = z + (size_t)(b * 256 + g * 64) * HW + pix;
  for (int j = 0; j < 16; j++){
    int cl = s * 16 + j;
    const float* zin = zb + (size_t)cl * HW;
    const float* wr = wp + cl * 9;           // wave-uniform -> s_load
    float acc = bp[cl];
    #pragma unroll
    for (int k = 0; k < 9; k++) acc = fmaf(wr[k], zin[offr[k]] * msk[k], acc);
    float S = wredsum(acc), Q = wredsum(acc * acc);
    if (lane == 0){
      int cg = b * 256 + g * 64 + cl;
      gnpart[(cg * 100 + blockIdx.x) * 2]     = S;
      gnpart[(cg * 100 + blockIdx.x) * 2 + 1] = Q;
    }
    lt[lane][cl] = f2bf(acc);
  }
  __syncthreads();
  int pr = tid >> 2, q = tid & 3;
  const unsigned short* src = &lt[pr][q * 16];
  unsigned int tmp[8];
  #pragma unroll
  for (int u = 0; u < 8; u++) tmp[u] = *(const unsigned int*)(src + u * 2);
  uint4 v0 = make_uint4(tmp[0], tmp[1], tmp[2], tmp[3]);
  uint4 v1 = make_uint4(tmp[4], tmp[5], tmp[6], tmp[7]);
  unsigned short* dst = zbf + ((size_t)b * HW + p0 + pr) * 256 + g * 64 + q * 16;
  *(uint4*)dst = v0;
  *(uint4*)(dst + 8) = v1;
}

// ---------------- K2: GN stats finalize -> per (b,c) scale/shift ----------------
__global__ __launch_bounds__(256) void k_gnfin(
    const float* __restrict__ gnpart, const float* __restrict__ gn_w,
    const float* __restrict__ gn_b, float* __restrict__ gn_sc){
  int tid = threadIdx.x; int bg = blockIdx.x; // b*4+g
  int b = bg >> 2, g = bg & 3;
  size_t base = (size_t)(b * 256 + g * 64) * 200;
  float S = 0.f, Q = 0.f;
  for (int i = tid; i < 6400; i += 256){
    S += gnpart[base + 2 * i];
    Q += gnpart[base + 2 * i + 1];
  }
  S = wredsum(S); Q = wredsum(Q);
  __shared__ float l[8];
  int lane = tid & 63, wid = tid >> 6;
  if (lane == 0){ l[wid] = S; l[4 + wid] = Q; }
  __syncthreads();
  float SS = l[0] + l[1] + l[2] + l[3];
  float QQ = l[4] + l[5] + l[6] + l[7];
  float M = 64.f * HW;
  float mean = SS / M;
  float var = QQ / M - mean * mean;
  float rstd = rsqrtf(var + 1e-5f);
  if (tid < 64){
    int c = g * 64 + tid;
    float sc = gn_w[c] * rstd;
    float sh = gn_b[c] - mean * sc;
    gn_sc[(b * 256 + c) * 2] = sc;
    gn_sc[(b * 256 + c) * 2 + 1] = sh;
  }
}

// ---------------- K3: 1x1 conv 256->256 (GN folded) via bf16 MFMA + GELU ----------------
__global__ __launch_bounds__(256) void k_conv1_mfma(
    const unsigned short* __restrict__ zbf,
    const unsigned short* __restrict__ cwbf,
    const float* __restrict__ cbp,
    unsigned short* __restrict__ zbfT){
  __shared__ __align__(16) unsigned char lmem[64 * 512];   // 32KB
  unsigned short* lda = (unsigned short*)lmem;
  unsigned short* lout = (unsigned short*)lmem;
  int tid = threadIdx.x;
  int p0 = blockIdx.x * 64, ocg = blockIdx.y, b = blockIdx.z;
  #pragma unroll
  for (int k = 0; k < 8; k++){
    int m = tid + k * 256;
    int i = m >> 5, c = m & 31;
    bf16x8 val = *(const bf16x8*)(zbf + ((size_t)b * HW + p0 + i) * 256 + c * 8);
    *(bf16x8*)(lda + i * 256 + (c ^ (i & 7)) * 8) = val;
  }
  __syncthreads();
  int wv = tid >> 6, l = tid & 63;
  int row = l & 15, kg = l >> 4;
  int i = wv * 16 + row;
  f32x4 acc0 = {0.f,0.f,0.f,0.f}, acc1 = {0.f,0.f,0.f,0.f};
  f32x4 acc2 = {0.f,0.f,0.f,0.f}, acc3 = {0.f,0.f,0.f,0.f};
  const unsigned short* wp = cwbf + (size_t)b * 65536 + (ocg * 4) * 512 + l * 8;
  #pragma unroll
  for (int s = 0; s < 8; s++){
    int c = s * 4 + kg;
    bf16x8 a = *(const bf16x8*)(lda + i * 256 + (c ^ (i & 7)) * 8);
    const unsigned short* wps = wp + s * 8192;
    bf16x8 b0 = *(const bf16x8*)(wps);
    bf16x8 b1 = *(const bf16x8*)(wps + 512);
    bf16x8 b2 = *(const bf16x8*)(wps + 1024);
    bf16x8 b3 = *(const bf16x8*)(wps + 1536);
    acc0 = __builtin_amdgcn_mfma_f32_16x16x32_bf16(a, b0, acc0, 0, 0, 0);
    acc1 = __builtin_amdgcn_mfma_f32_16x16x32_bf16(a, b1, acc1, 0, 0, 0);
    acc2 = __builtin_amdgcn_mfma_f32_16x16x32_bf16(a, b2, acc2, 0, 0, 0);
    acc3 = __builtin_amdgcn_mfma_f32_16x16x32_bf16(a, b3, acc3, 0, 0, 0);
  }
  __syncthreads();
  const float* cbb = cbp + b * 256 + ocg * 64;
  int oc_l = l & 15;
  int pl = wv * 16 + kg * 4;
  float bs0 = cbb[oc_l], bs1 = cbb[16 + oc_l], bs2 = cbb[32 + oc_l], bs3 = cbb[48 + oc_l];
  #pragma unroll
  for (int r = 0; r < 4; r++){
    lout[(pl + r) * 72 + oc_l]      = f2bf(gelu(acc0[r] + bs0));
    lout[(pl + r) * 72 + 16 + oc_l] = f2bf(gelu(acc1[r] + bs1));
    lout[(pl + r) * 72 + 32 + oc_l] = f2bf(gelu(acc2[r] + bs2));
    lout[(pl + r) * 72 + 48 + oc_l] = f2bf(gelu(acc3[r] + bs3));
  }
  __syncthreads();
  int pix = tid >> 2, q = tid & 3;
  unsigned short* dst = zbfT + ((size_t)b * HW + p0 + pix) * 256 + ocg * 64 + q * 16;
  const unsigned short* src = lout + pix * 72 + q * 16;
  *(uint4*)dst       = *(const uint4*)src;
  *(uint4*)(dst + 8) = *(const uint4*)(src + 8);
}

// ---------------- K4 helper: masked global load of one halo offset ----------------
__device__ __forceinline__ void c5_gload(bf16x8* r, const unsigned short* zbase,
    int p0, int irow, int c31, const int* hh, const int* ww, int off){
  int dy = off / 3 - 1, dx = off % 3 - 1;
  int doff = dy * 80 + dx;
  #pragma unroll
  for (int k = 0; k < 8; k++){
    int op = p0 + irow + k * 8;
    bool v = ((unsigned)(hh[k] + dy) < 80u) && ((unsigned)(ww[k] + dx) < 80u);
    int sp = v ? (op + doff) : op;
    bf16x8 val = *(const bf16x8*)(zbase + (size_t)sp * 256 + c31 * 8);
    if (!v) val = (bf16x8){0, 0, 0, 0, 0, 0, 0, 0};
    r[k] = val;
  }
}

// ---------------- K4: 3x3 conv 256->32 via bf16 MFMA, single pass over 9 offsets ----
__global__ __launch_bounds__(256) void k_conv5ac2(
    const unsigned short* __restrict__ zbfT,
    const unsigned short* __restrict__ wbbf,
    float* __restrict__ fpre, float* __restrict__ bnpart){
  __shared__ __align__(16) unsigned short lda[2][64 * 256];   // 2 x 32KB
  int tid = threadIdx.x;
  int och = blockIdx.y, b = blockIdx.z;
  int p0 = blockIdx.x * 64;
  int irow = tid >> 5, c31 = tid & 31;
  int hh[8], ww[8];
  #pragma unroll
  for (int k = 0; k < 8; k++){
    int op = p0 + irow + k * 8;
    hh[k] = op / 80; ww[k] = op % 80;
  }
  const unsigned short* zbase = zbfT + (size_t)b * HW * 256;
  bf16x8 r[8];
  c5_gload(r, zbase, p0, irow, c31, hh, ww, 0);
  #pragma unroll
  for (int k = 0; k < 8; k++){
    int i = irow + k * 8;
    *(bf16x8*)(lda[0] + i * 256 + (c31 ^ (i & 7)) * 8) = r[k];
  }
  c5_gload(r, zbase, p0, irow, c31, hh, ww, 1);
  int wv = tid >> 6, l = tid & 63;
  int lrow = l & 15, kg = l >> 4;
  int li = wv * 16 + lrow;
  f32x4 acc = {0.f, 0.f, 0.f, 0.f};
  for (int off = 0; off < 9; off++){
    __syncthreads();
    int buf = off & 1;
    const unsigned short* wp = wbbf + (size_t)off * 8192 + och * 512 + l * 8;
    #pragma unroll
    for (int s = 0; s < 8; s++){
      int cc = s * 4 + kg;
      bf16x8 a = *(const bf16x8*)(lda[buf] + li * 256 + (cc ^ (li & 7)) * 8);
      bf16x8 bb = *(const bf16x8*)(wp + s * 1024);
      acc = __builtin_amdgcn_mfma_f32_16x16x32_bf16(a, bb, acc, 0, 0, 0);
    }
    if (off + 1 < 9){
      #pragma unroll
      for (int k = 0; k < 8; k++){
        int i = irow + k * 8;
        *(bf16x8*)(lda[buf ^ 1] + i * 256 + (c31 ^ (i & 7)) * 8) = r[k];
      }
      if (off + 2 < 9) c5_gload(r, zbase, p0, irow, c31, hh, ww, off + 2);
    }
  }
  __syncthreads();
  float* lout = (float*)lda;
  int ocl = l & 15;
  int pl = wv * 16 + kg * 4;
  #pragma unroll
  for (int rr = 0; rr < 4; rr++) lout[ocl * 68 + pl + rr] = acc[rr];
  __syncthreads();
  int oc = tid >> 4, px = (tid & 15) * 4;
  float4 v = *(float4*)(lout + oc * 68 + px);
  *(float4*)(fpre + ((size_t)(b * 32 + och * 16 + oc)) * HW + p0 + px) = v;
  float S = v.x + v.y + v.z + v.w;
  float Q = v.x * v.x + v.y * v.y + v.z * v.z + v.w * v.w;
  #pragma unroll
  for (int o2 = 1; o2 < 16; o2 <<= 1){ S += __shfl_xor(S, o2); Q += __shfl_xor(Q, o2); }
  if ((tid & 15) == 0){
    int ocg = och * 16 + oc;
    bnpart[ocg * 400 + (b * 100 + blockIdx.x) * 2]     = S;
    bnpart[ocg * 400 + (b * 100 + blockIdx.x) * 2 + 1] = Q;
  }
}

// ---------------- K6: inline BN-A + relu -> feat1/feat2, q,k,v 1x1 convs ----------------
__global__ __launch_bounds__(256) void k_featqkv(
    const float* __restrict__ fpre, const float* __restrict__ bnpart,
    const float* __restrict__ w1, const float* __restrict__ b1,
    const float* __restrict__ w2, const float* __restrict__ b2,
    const float* __restrict__ pqw, const float* __restrict__ pqb,
    const float* __restrict__ pkw, const float* __restrict__ pkb,
    const float* __restrict__ pvw, const float* __restrict__ pvb,
    float* __restrict__ feat, float* __restrict__ qkvT){
  __shared__ float lS[8][32], lQ[8][32], lsc[64];
  int tid = threadIdx.x; int b = blockIdx.y;
  {
    int oc = tid & 31, sl = tid >> 5;
    float S = 0.f, Q = 0.f;
    for (int i = sl; i < 200; i += 8){
      S += bnpart[oc * 400 + i * 2];
      Q += bnpart[oc * 400 + i * 2 + 1];
    }
    lS[sl][oc] = S; lQ[sl][oc] = Q;
    __syncthreads();
    if (tid < 32){
      float SS = 0.f, QQ = 0.f;
      #pragma unroll
      for (int s = 0; s < 8; s++){ SS += lS[s][tid]; QQ += lQ[s][tid]; }
      float M = 2.f * HW;
      float mean = SS / M, var = QQ / M - mean * mean;
      float rstd = rsqrtf(var + 1e-3f);
      float w  = (tid < 16) ? w1[tid] : w2[tid - 16];
      float bb = (tid < 16) ? b1[tid] : b2[tid - 16];
      float sc = w * rstd;
      lsc[tid * 2] = sc; lsc[tid * 2 + 1] = bb - mean * sc;
    }
    __syncthreads();
  }
  int n = blockIdx.x * 256 + tid;
  float f1[16], f2[16];
  #pragma unroll
  for (int c = 0; c < 16; c++){
    float v1 = fpre[(b * 32 + c) * HW + n] * lsc[c * 2] + lsc[c * 2 + 1];
    f1[c] = fmaxf(v1, 0.f);
    float v2 = fpre[(b * 32 + 16 + c) * HW + n] * lsc[(16 + c) * 2] + lsc[(16 + c) * 2 + 1];
    f2[c] = fmaxf(v2, 0.f);
    feat[(b * 32 + c) * HW + n] = f1[c];
    feat[(b * 32 + 16 + c) * HW + n] = f2[c];
  }
  float* o = qkvT + ((size_t)b * HW + n) * 20;
  #pragma unroll
  for (int j = 0; j < 2; j++){
    float q = pqb[j], k = pkb[j];
    #pragma unroll
    for (int c = 0; c < 16; c++){ q += pqw[j * 16 + c] * f1[c]; k += pkw[j * 16 + c] * f1[c]; }
    o[j] = q; o[2 + j] = k;
  }
  #pragma unroll
  for (int j = 0; j < 16; j++){
    float v = pvb[j];
    #pragma unroll
    for (int c = 0; c < 16; c++) v += pvw[j * 16 + c] * f1[c];
    o[4 + j] = v;
  }
}

// ---------------- K7a: PAM flash partials via MFMA PV, 8 m-chunks of 800 ----------------
__global__ __launch_bounds__(256) void k_pam_a(
    const float* __restrict__ qkvT, float* __restrict__ part){
  __shared__ __align__(16) float lk0[800];
  __shared__ __align__(16) float lk1[800];
  __shared__ __align__(16) unsigned short lvb[16][808];
  __shared__ float lred[4];
  int tid = threadIdx.x;
  int mc = blockIdx.y, b = blockIdx.z;
  float sqm = 0.f;
  for (int m = tid; m < 800; m += 256){
    const float* kv = qkvT + ((size_t)b * HW + mc * 800 + m) * 20;
    float4 a0 = *(const float4*)kv;
    lk0[m] = a0.z; lk1[m] = a0.w;
    sqm = fmaxf(sqm, a0.z * a0.z + a0.w * a0.w);
    float4 v0 = *(const float4*)(kv + 4);
    float4 v1 = *(const float4*)(kv + 8);
    float4 v2 = *(const float4*)(kv + 12);
    float4 v3 = *(const float4*)(kv + 16);
    lvb[0][m]  = f2bf(v0.x); lvb[1][m]  = f2bf(v0.y);
    lvb[2][m]  = f2bf(v0.z); lvb[3][m]  = f2bf(v0.w);
    lvb[4][m]  = f2bf(v1.x); lvb[5][m]  = f2bf(v1.y);
    lvb[6][m]  = f2bf(v1.z); lvb[7][m]  = f2bf(v1.w);
    lvb[8][m]  = f2bf(v2.x); lvb[9][m]  = f2bf(v2.y);
    lvb[10][m] = f2bf(v2.z); lvb[11][m] = f2bf(v2.w);
    lvb[12][m] = f2bf(v3.x); lvb[13][m] = f2bf(v3.y);
    lvb[14][m] = f2bf(v3.z); lvb[15][m] = f2bf(v3.w);
  }
  #pragma unroll
  for (int o = 32; o; o >>= 1) sqm = fmaxf(sqm, __shfl_xor(sqm, o));
  int lane = tid & 63, wid = tid >> 6;
  if (lane == 0) lred[wid] = sqm;
  __syncthreads();
  float kmax = sqrtf(fmaxf(fmaxf(lred[0], lred[1]), fmaxf(lred[2], lred[3])));
  int wv = tid >> 6, l = tid & 63;
  int row = l & 15, kg = l >> 4;
  int n = blockIdx.x * 64 + wv * 16 + row;
  const float* qp = qkvT + ((size_t)b * HW + n) * 20;
  float q0 = qp[0], q1 = qp[1];
  float mxr = sqrtf(q0 * q0 + q1 * q1) * kmax;
  f32x4 acc = {0.f, 0.f, 0.f, 0.f};
  float zp = 0.f;
  for (int t = 0; t < 25; t++){
    int m0 = t * 32 + kg * 8;
    float4 k0a = *(const float4*)&lk0[m0];
    float4 k0b = *(const float4*)&lk0[m0 + 4];
    float4 k1a = *(const float4*)&lk1[m0];
    float4 k1b = *(const float4*)&lk1[m0 + 4];
    float p0 = __expf(fmaf(q0, k0a.x, q1 * k1a.x) - mxr);
    float p1 = __expf(fmaf(q0, k0a.y, q1 * k1a.y) - mxr);
    float p2 = __expf(fmaf(q0, k0a.z, q1 * k1a.z) - mxr);
    float p3 = __expf(fmaf(q0, k0a.w, q1 * k1a.w) - mxr);
    float p4 = __expf(fmaf(q0, k0b.x, q1 * k1b.x) - mxr);
    float p5 = __expf(fmaf(q0, k0b.y, q1 * k1b.y) - mxr);
    float p6 = __expf(fmaf(q0, k0b.z, q1 * k1b.z) - mxr);
    float p7 = __expf(fmaf(q0, k0b.w, q1 * k1b.w) - mxr);
    zp += ((p0 + p1) + (p2 + p3)) + ((p4 + p5) + (p6 + p7));
    union { unsigned int u[4]; bf16x8 v; } pk;
    pk.u[0] = cvt_pk_bf16(p0, p1);
    pk.u[1] = cvt_pk_bf16(p2, p3);
    pk.u[2] = cvt_pk_bf16(p4, p5);
    pk.u[3] = cvt_pk_bf16(p6, p7);
    bf16x8 vb = *(const bf16x8*)&lvb[row][m0];
    acc = __builtin_amdgcn_mfma_f32_16x16x32_bf16(pk.v, vb, acc, 0, 0, 0);
  }
  zp += __shfl_xor(zp, 16);
  zp += __shfl_xor(zp, 32);
  float* pp = part + ((size_t)(b * 8 + mc) * 18) * HW;
  if (kg == 0){ pp[n] = mxr; pp[HW + n] = zp; }
  int c = l & 15;
  int nr = blockIdx.x * 64 + wv * 16 + (l >> 4) * 4;
  *(f32x4*)&pp[(size_t)(2 + c) * HW + nr] = acc;
}

// ---------------- K8: CAM gram matrix e[b,c,d] ----------------
__global__ __launch_bounds__(256) void k_cam_gram(
    const float* __restrict__ feat, float* __restrict__ e){
  int tid = threadIdx.x;
  int dd = blockIdx.x, c = blockIdx.y, b = blockIdx.z;
  const float* fc = feat + (b * 32 + 16 + c) * HW;
  const float* fd = feat + (b * 32 + 16 + dd) * HW;
  float S = 0.f;
  for (int i = tid; i < HW; i += 256) S += fc[i] * fd[i];
  S = wredsum(S);
  __shared__ float l[4];
  int lane = tid & 63, wid = tid >> 6;
  if (lane == 0) l[wid] = S;
  __syncthreads();
  if (tid == 0) e[(b * 16 + c) * 16 + dd] = l[0] + l[1] + l[2] + l[3];
}

// ---------------- K9: merged PAM-merge (y<8) + CAM softmax+apply (y>=8) ----------------
// grid (25, 24, 2), block 256
__global__ __launch_bounds__(256) void k_merge(
    const float* __restrict__ part, const float* __restrict__ feat,
    const float* __restrict__ cam_e,
    const float* __restrict__ pa_g, const float* __restrict__ ca_g,
    float* __restrict__ pam_in, float* __restrict__ cam_in){
  int tid = threadIdx.x; int y = blockIdx.y, b = blockIdx.z;
  int n = blockIdx.x * 256 + tid;
  if (y < 8){
    int cg = y;
    float gamma = pa_g[0];
    float mxs[8]; float mx = -1e30f;
    #pragma unroll
    for (int mc = 0; mc < 8; mc++){
      mxs[mc] = part[((size_t)(b * 8 + mc) * 18) * HW + n];
      mx = fmaxf(mx, mxs[mc]);
    }
    float Z = 0.f, a0 = 0.f, a1 = 0.f;
    #pragma unroll
    for (int mc = 0; mc < 8; mc++){
      const float* pp = part + ((size_t)(b * 8 + mc) * 18) * HW + n;
      float r = __expf(mxs[mc] - mx);
      Z += pp[HW] * r;
      a0 += pp[(size_t)(2 + cg * 2) * HW] * r;
      a1 += pp[(size_t)(3 + cg * 2) * HW] * r;
    }
    float inv = gamma / Z;
    int c0 = cg * 2;
    pam_in[(b * 16 + c0) * HW + n]     = a0 * inv + feat[(b * 32 + c0) * HW + n];
    pam_in[(b * 16 + c0 + 1) * HW + n] = a1 * inv + feat[(b * 32 + c0 + 1) * HW + n];
  } else {
    int c = y - 8;
    const float* row = cam_e + (b * 16 + c) * 16;
    float r[16]; float mn = 1e30f;
    #pragma unroll
    for (int dd = 0; dd < 16; dd++){ r[dd] = row[dd]; mn = fminf(mn, r[dd]); }
    float p[16]; float ssum = 0.f;
    #pragma unroll
    for (int dd = 0; dd < 16; dd++){ p[dd] = __expf(mn - r[dd]); ssum += p[dd]; }
    float inv = ca_g[0] / ssum;
    float s = 0.f;
    #pragma unroll
    for (int dd = 0; dd < 16; dd++) s += p[dd] * feat[(b * 32 + 16 + dd) * HW + n];
    cam_in[(b * 16 + c) * HW + n] = s * inv + feat[(b * 32 + 16 + c) * HW + n];
  }
}

// ---------------- K11: 3x3 conv 16->32 (c5b|c5d), 4 outputs/thread + BN stats ----------------
__global__ __launch_bounds__(64) void k_conv5bd2(
    const float* __restrict__ pam_in, const float* __restrict__ cam_in,
    const float* __restrict__ wt2,
    float* __restrict__ bdpre, float* __restrict__ bnpart){
  int tid = threadIdx.x;
  int pix = blockIdx.x * 64 + tid;
  int ocg = blockIdx.y, b = blockIdx.z;
  int half = ocg >> 2, oq = (ocg & 3) * 4;
  int h = pix / 80, w = pix % 80;
  int off[9]; float msk[9];
  #pragma unroll
  for (int dy = 0; dy < 3; dy++){
    #pragma unroll
    for (int dx = 0; dx < 3; dx++){
      int hh = h + dy - 1, ww = w + dx - 1;
      bool ok = ((unsigned)hh < 80u) && ((unsigned)ww < 80u);
      off[dy * 3 + dx] = ok ? hh * 80 + ww : 0;
      msk[dy * 3 + dx] = ok ? 1.f : 0.f;
    }
  }
  const float* in = (half ? cam_in : pam_in) + (size_t)b * 16 * HW;
  int obase = half * 16 + oq;
  float acc[4];
  #pragma unroll
  for (int o = 0; o < 4; o++) acc[o] = 0.f;
  float xa[9], xb[9];
  #pragma unroll
  for (int k = 0; k < 9; k++) xa[k] = in[off[k]] * msk[k];
  #pragma unroll
  for (int ic = 0; ic < 16; ic += 2){
    const float* xin1 = in + (size_t)(ic + 1) * HW;
    #pragma unroll
    for (int k = 0; k < 9; k++) xb[k] = xin1[off[k]] * msk[k];
    const float* wr0 = wt2 + ic * 288 + obase * 9;
    #pragma unroll
    for (int o = 0; o < 4; o++){
      float a = acc[o];
      #pragma unroll
      for (int k = 0; k < 9; k++) a += wr0[o * 9 + k] * xa[k];
      acc[o] = a;
    }
    if (ic + 2 < 16){
      const float* xin2 = in + (size_t)(ic + 2) * HW;
      #pragma unroll
      for (int k = 0; k < 9; k++) xa[k] = xin2[off[k]] * msk[k];
    }
    const float* wr1 = wt2 + (ic + 1) * 288 + obase * 9;
    #pragma unroll
    for (int o = 0; o < 4; o++){
      float a = acc[o];
      #pragma unroll
      for (int k = 0; k < 9; k++) a += wr1[o * 9 + k] * xb[k];
      acc[o] = a;
    }
  }
  #pragma unroll
  for (int o = 0; o < 4; o++){
    float v = acc[o];
    bdpre[(b * 32 + obase + o) * HW + pix] = v;
    float S = wredsum(v), Q = wredsum(v * v);
    if (tid == 0){
      bnpart[(obase + o) * 400 + (b * 100 + blockIdx.x) * 2]     = S;
      bnpart[(obase + o) * 400 + (b * 100 + blockIdx.x) * 2 + 1] = Q;
    }
  }
}

// ---------------- K13: inline BN-B + relu + sum + 1x1 conv 16->256 + relu -> out ----------
__global__ __launch_bounds__(256) void k_c6(
    const float* __restrict__ bdpre, const float* __restrict__ bnpart,
    const float* __restrict__ w1, const float* __restrict__ b1,
    const float* __restrict__ w2, const float* __restrict__ b2,
    const float* __restrict__ w6, const float* __restrict__ b6,
    float* __restrict__ out){
  __shared__ float lS[8][32], lQ[8][32], lsc[64];
  int tid = threadIdx.x; int og = blockIdx.y * 32, b = blockIdx.z;
  {
    int oc = tid & 31, sl = tid >> 5;
    float S = 0.f, Q = 0.f;
    for (int i = sl; i < 200; i += 8){
      S += bnpart[oc * 400 + i * 2];
      Q += bnpart[oc * 400 + i * 2 + 1];
    }
    lS[sl][oc] = S; lQ[sl][oc] = Q;
    __syncthreads();
    if (tid < 32){
      float SS = 0.f, QQ = 0.f;
      #pragma unroll
      for (int s = 0; s < 8; s++){ SS += lS[s][tid]; QQ += lQ[s][tid]; }
      float M = 2.f * HW;
      float mean = SS / M, var = QQ / M - mean * mean;
      float rstd = rsqrtf(var + 1e-3f);
      float w  = (tid < 16) ? w1[tid] : w2[tid - 16];
      float bb = (tid < 16) ? b1[tid] : b2[tid - 16];
      float sc = w * rstd;
      lsc[tid * 2] = sc; lsc[tid * 2 + 1] = bb - mean * sc;
    }
    __syncthreads();
  }
  int n = blockIdx.x * 256 + tid;
  float x[16];
  #pragma unroll
  for (int c = 0; c < 16; c++){
    float v1 = bdpre[(b * 32 + c) * HW + n] * lsc[c * 2] + lsc[c * 2 + 1];
    float v2 = bdpre[(b * 32 + 16 + c) * HW + n] * lsc[(16 + c) * 2] + lsc[(16 + c) * 2 + 1];
    x[c] = fmaxf(v1, 0.f) + fmaxf(v2, 0.f);
  }
  #pragma unroll
  for (int o = 0; o < 32; o++){
    float a = b6[og + o];
    #pragma unroll
    for (int c = 0; c < 16; c++) a += w6[(og + o) * 16 + c] * x[c];
    out[(b * 256 + og + o) * HW + n] = fmaxf(a, 0.f);
  }
}

extern "C" void kernel_launch(void* const* d_in, const int* in_sizes, int n_in,
                              void* d_out, int out_size, void* d_ws, size_t ws_size,
                              hipStream_t stream){
  const float* z      = (const float*)d_in[0];
  const float* w_at0  = (const float*)d_in[1];
  const float* b_at0  = (const float*)d_in[2];
  const float* w_at1  = (const float*)d_in[3];
  const float* b_at1  = (const float*)d_in[4];
  const float* w_at2  = (const float*)d_in[5];
  const float* b_at2  = (const float*)d_in[6];
  const float* w_at3  = (const float*)d_in[7];
  const float* b_at3  = (const float*)d_in[8];
  const float* gn_w   = (const float*)d_in[9];
  const float* gn_b   = (const float*)d_in[10];
  const float* conv_w = (const float*)d_in[11];
  const float* conv_b = (const float*)d_in[12];
  const float* c5a_w  = (const float*)d_in[13];
  const float* bn5a_w = (const float*)d_in[14];
  const float* bn5a_b = (const float*)d_in[15];
  const float* c5c_w  = (const float*)d_in[16];
  const float* bn5c_w = (const float*)d_in[17];
  const float* bn5c_b = (const float*)d_in[18];
  const float* pq_w   = (const float*)d_in[19];
  const float* pq_b   = (const float*)d_in[20];
  const float* pk_w   = (const float*)d_in[21];
  const float* pk_b   = (const float*)d_in[22];
  const float* pv_w   = (const float*)d_in[23];
  const float* pv_b   = (const float*)d_in[24];
  const float* pa_g   = (const float*)d_in[25];
  const float* ca_g   = (const float*)d_in[26];
  const float* c5b_w  = (const float*)d_in[27];
  const float* bn5b_w = (const float*)d_in[28];
  const float* bn5b_b = (const float*)d_in[29];
  const float* c5d_w  = (const float*)d_in[30];
  const float* bn5d_w = (const float*)d_in[31];
  const float* bn5d_b = (const float*)d_in[32];
  const float* c6_w   = (const float*)d_in[33];
  const float* c6_b   = (const float*)d_in[34];

  float* ws = (float*)d_ws;
  unsigned short* ZBF    = (unsigned short*)ws;                  // bf16 [0..1,638,400) f32
  unsigned short* ZC2BFT = (unsigned short*)(ws + 1638400);      // bf16 conv1 out
  unsigned short* CWBF   = (unsigned short*)(ws + 3276800);      // bf16 GN-folded conv1 w
  float* CBP     = ws + 3407872;
  float* FPRE    = ws + 3408384;
  float* FEAT    = FPRE + 409600;
  float* QKVT    = FEAT + 409600;
  float* PAM_IN  = QKVT + 256000;
  float* CAM_IN  = PAM_IN + 204800;
  float* BDPRE   = CAM_IN + 204800;
  float* ST      = BDPRE + 409600;
  float* GN_SC    = ST;                   // 1024
  float* CAM_E    = ST + 1024;            // 512
  float* GN_PART  = ST + 2176;            // 102,400
  float* BNA_PART = ST + 104576;          // 12,800
  float* BNB_PART = ST + 117376;          // 12,800
  float* WT2      = ST + 130176;          // 4,608
  unsigned short* WBBF = (unsigned short*)(ST + 134784);  // 73,728 bf16
  // PART (PAM partials, 8*18*2*HW = 1,843,200 f32) aliases [0..1,843,200):
  // ZBF + head of ZC2BFT, both dead before k_pam_a runs.
  float* PART = ws;

  k_dwt<<<dim3(100, 4, 2), 256, 0, stream>>>(z, w_at0, b_at0, w_at1, b_at1,
                                             w_at2, b_at2, w_at3, b_at3, ZBF, GN_PART);
  k_gnfin<<<8, 256, 0, stream>>>(GN_PART, gn_w, gn_b, GN_SC);
  k_prep<<<832, 256, 0, stream>>>(c5a_w, c5c_w, c5b_w, c5d_w, conv_w, GN_SC, conv_b,
                                  WT2, WBBF, CWBF, CBP);
  k_conv1_mfma<<<dim3(100, 4, 2), 256, 0, stream>>>(ZBF, CWBF, CBP, ZC2BFT);
  k_conv5ac2<<<dim3(100, 2, 2), 256, 0, stream>>>(ZC2BFT, WBBF, FPRE, BNA_PART);
  k_featqkv<<<dim3(25, 2), 256, 0, stream>>>(FPRE, BNA_PART, bn5a_w, bn5a_b,
                                             bn5c_w, bn5c_b, pq_w, pq_b, pk_w, pk_b,
                                             pv_w, pv_b, FEAT, QKVT);
  k_pam_a<<<dim3(100, 8, 2), 256, 0, stream>>>(QKVT, PART);
  k_cam_gram<<<dim3(16, 16, 2), 256, 0, stream>>>(FEAT, CAM_E);
  k_merge<<<dim3(25, 24, 2), 256, 0, stream>>>(PART, FEAT, CAM_E, pa_g, ca_g,
                                               PAM_IN, CAM_IN);
  k_conv5bd2<<<dim3(100, 8, 2), 64, 0, stream>>>(PAM_IN, CAM_IN, WT2, BDPRE, BNB_PART);
  k_c6<<<dim3(25, 8, 2), 256, 0, stream>>>(BDPRE, BNB_PART, bn5b_w, bn5b_b,
                                           bn5d_w, bn5d_b, c6_w, c6_b, (float*)d_out);
}